// Round 1
// baseline (12547.054 us; speedup 1.0000x reference)
//
#include <hip/hip_runtime.h>
#include <hip/hip_bf16.h>

#define TILE 64
#define BK 16

#define EPI_NONE 0
#define EPI_RESID 1
#define EPI_GELU 2

// ---------------------------------------------------------------------------
// Generic f32 GEMM: C = A(M,K) @ B(K,N) + bias[N]  (+ residual | gelu)
// 64x64 tile, BK=16, 256 threads, 4x4 per thread.
// ---------------------------------------------------------------------------
__global__ __launch_bounds__(256) void gemm_f32_kernel(
    const float* __restrict__ A, const float* __restrict__ B,
    const float* __restrict__ bias, const float* __restrict__ Rsd,
    float* __restrict__ C, int M, int N, int K, int epi)
{
    __shared__ float As[BK][TILE + 1];
    __shared__ float Bs[BK][TILE + 1];
    const int tid = threadIdx.x;
    const int tx = tid & 15, ty = tid >> 4;
    const int tm = blockIdx.y * TILE, tn = blockIdx.x * TILE;

    float acc[4][4] = {};
    for (int k0 = 0; k0 < K; k0 += BK) {
#pragma unroll
        for (int i = 0; i < 4; i++) {
            int idx = tid + i * 256;
            int m = idx >> 4, k = idx & 15;
            As[k][m] = A[(size_t)(tm + m) * K + k0 + k];
        }
#pragma unroll
        for (int i = 0; i < 4; i++) {
            int idx = tid + i * 256;
            int kb = idx >> 6, n = idx & 63;
            Bs[kb][n] = B[(size_t)(k0 + kb) * N + tn + n];
        }
        __syncthreads();
#pragma unroll
        for (int kk = 0; kk < BK; kk++) {
            float a[4], bv[4];
#pragma unroll
            for (int i = 0; i < 4; i++) a[i] = As[kk][ty * 4 + i];
#pragma unroll
            for (int j = 0; j < 4; j++) bv[j] = Bs[kk][tx * 4 + j];
#pragma unroll
            for (int i = 0; i < 4; i++)
#pragma unroll
                for (int j = 0; j < 4; j++) acc[i][j] += a[i] * bv[j];
        }
        __syncthreads();
    }

#pragma unroll
    for (int i = 0; i < 4; i++) {
        int r = tm + ty * 4 + i;
#pragma unroll
        for (int j = 0; j < 4; j++) {
            int c = tn + tx * 4 + j;
            float v = acc[i][j] + bias[c];
            if (epi == EPI_GELU) {
                v = 0.5f * v * (1.0f + erff(v * 0.70710678118654752f));
            } else if (epi == EPI_RESID) {
                v += Rsd[(size_t)r * N + c];
            }
            C[(size_t)r * N + c] = v;
        }
    }
}

// ---------------------------------------------------------------------------
// Batched scores: S[bz,q,k] = (Q_bh[q,:] . K_bh[k,:]) / 16  (+ mask)
// bz = b*8 + h; Q/K are (4096, 2048) with head columns h*256..+256.
// ---------------------------------------------------------------------------
__global__ __launch_bounds__(256) void score_kernel(
    const float* __restrict__ Q, const float* __restrict__ Kmat,
    const int* __restrict__ adj, float* __restrict__ S, int use_mask)
{
    __shared__ float Qs[BK][TILE + 1];
    __shared__ float Ks[BK][TILE + 1];
    const int bz = blockIdx.z;
    const int b = bz >> 3, hd = bz & 7;
    const float* Qb = Q + (size_t)b * 256 * 2048 + hd * 256;
    const float* Kb = Kmat + (size_t)b * 256 * 2048 + hd * 256;
    const int tid = threadIdx.x, tx = tid & 15, ty = tid >> 4;
    const int tm = blockIdx.y * TILE, tn = blockIdx.x * TILE;

    float acc[4][4] = {};
    for (int k0 = 0; k0 < 256; k0 += BK) {
#pragma unroll
        for (int i = 0; i < 4; i++) {
            int idx = tid + i * 256;
            int m = idx >> 4, k = idx & 15;
            Qs[k][m] = Qb[(size_t)(tm + m) * 2048 + k0 + k];
            Ks[k][m] = Kb[(size_t)(tn + m) * 2048 + k0 + k];
        }
        __syncthreads();
#pragma unroll
        for (int kk = 0; kk < BK; kk++) {
            float a[4], bv[4];
#pragma unroll
            for (int i = 0; i < 4; i++) a[i] = Qs[kk][ty * 4 + i];
#pragma unroll
            for (int j = 0; j < 4; j++) bv[j] = Ks[kk][tx * 4 + j];
#pragma unroll
            for (int i = 0; i < 4; i++)
#pragma unroll
                for (int j = 0; j < 4; j++) acc[i][j] += a[i] * bv[j];
        }
        __syncthreads();
    }

    const float scale = 0.0625f;  // 1/sqrt(256)
#pragma unroll
    for (int i = 0; i < 4; i++) {
        int r = tm + ty * 4 + i;
#pragma unroll
        for (int j = 0; j < 4; j++) {
            int c = tn + tx * 4 + j;
            float v = acc[i][j] * scale;
            if (use_mask) {
                int a_ = adj[((size_t)b * 256 + r) * 256 + c];
                v += (1.0f - (float)a_) * (-1.0e6f);
            }
            S[((size_t)bz * 256 + r) * 256 + c] = v;
        }
    }
}

// ---------------------------------------------------------------------------
// Softmax with +1 in denominator, row length 256. One wave per row.
// ---------------------------------------------------------------------------
__global__ __launch_bounds__(256) void softmax1_kernel(float* __restrict__ S)
{
    const int wave = threadIdx.x >> 6, lane = threadIdx.x & 63;
    const size_t row = (size_t)blockIdx.x * 4 + wave;
    float* r = S + row * 256 + lane * 4;
    float4 v = *reinterpret_cast<float4*>(r);
    float m = fmaxf(fmaxf(v.x, v.y), fmaxf(v.z, v.w));
#pragma unroll
    for (int off = 32; off; off >>= 1) m = fmaxf(m, __shfl_xor(m, off));
    float e0 = expf(v.x - m), e1 = expf(v.y - m), e2 = expf(v.z - m), e3 = expf(v.w - m);
    float s = e0 + e1 + e2 + e3;
#pragma unroll
    for (int off = 32; off; off >>= 1) s += __shfl_xor(s, off);
    float inv = 1.0f / (1.0f + s);
    v.x = e0 * inv; v.y = e1 * inv; v.z = e2 * inv; v.w = e3 * inv;
    *reinterpret_cast<float4*>(r) = v;
}

// ---------------------------------------------------------------------------
// Batched PV: O_bh[q,d] = sum_k P[bz][q,k] * V_bh[k,d]
// ---------------------------------------------------------------------------
__global__ __launch_bounds__(256) void pv_kernel(
    const float* __restrict__ P, const float* __restrict__ V, float* __restrict__ O)
{
    __shared__ float Ps[BK][TILE + 1];
    __shared__ float Vs[BK][TILE + 1];
    const int bz = blockIdx.z, b = bz >> 3, hd = bz & 7;
    const float* Pb = P + (size_t)bz * 256 * 256;
    const float* Vb = V + (size_t)b * 256 * 2048 + hd * 256;
    float* Ob = O + (size_t)b * 256 * 2048 + hd * 256;
    const int tid = threadIdx.x, tx = tid & 15, ty = tid >> 4;
    const int tm = blockIdx.y * TILE, tn = blockIdx.x * TILE;

    float acc[4][4] = {};
    for (int k0 = 0; k0 < 256; k0 += BK) {
#pragma unroll
        for (int i = 0; i < 4; i++) {
            int idx = tid + i * 256;
            int m = idx >> 4, k = idx & 15;
            Ps[k][m] = Pb[(size_t)(tm + m) * 256 + k0 + k];
        }
#pragma unroll
        for (int i = 0; i < 4; i++) {
            int idx = tid + i * 256;
            int kb = idx >> 6, n = idx & 63;
            Vs[kb][n] = Vb[(size_t)(k0 + kb) * 2048 + tn + n];
        }
        __syncthreads();
#pragma unroll
        for (int kk = 0; kk < BK; kk++) {
            float a[4], bv[4];
#pragma unroll
            for (int i = 0; i < 4; i++) a[i] = Ps[kk][ty * 4 + i];
#pragma unroll
            for (int j = 0; j < 4; j++) bv[j] = Vs[kk][tx * 4 + j];
#pragma unroll
            for (int i = 0; i < 4; i++)
#pragma unroll
                for (int j = 0; j < 4; j++) acc[i][j] += a[i] * bv[j];
        }
        __syncthreads();
    }

#pragma unroll
    for (int i = 0; i < 4; i++) {
        int r = tm + ty * 4 + i;
#pragma unroll
        for (int j = 0; j < 4; j++) {
            int c = tn + tx * 4 + j;
            Ob[(size_t)r * 2048 + c] = acc[i][j];
        }
    }
}

// ---------------------------------------------------------------------------
// LayerNorm, row length 512. One wave per row (8 elems/lane via 2x float4).
// ---------------------------------------------------------------------------
__global__ __launch_bounds__(256) void ln_kernel(
    const float* __restrict__ X, const float* __restrict__ g,
    const float* __restrict__ b, float* __restrict__ Y)
{
    const int wave = threadIdx.x >> 6, lane = threadIdx.x & 63;
    const size_t row = (size_t)blockIdx.x * 4 + wave;
    const float* xr = X + row * 512;
    float4 v0 = *reinterpret_cast<const float4*>(xr + lane * 4);
    float4 v1 = *reinterpret_cast<const float4*>(xr + 256 + lane * 4);
    float s = v0.x + v0.y + v0.z + v0.w + v1.x + v1.y + v1.z + v1.w;
    float ss = v0.x * v0.x + v0.y * v0.y + v0.z * v0.z + v0.w * v0.w +
               v1.x * v1.x + v1.y * v1.y + v1.z * v1.z + v1.w * v1.w;
#pragma unroll
    for (int off = 32; off; off >>= 1) {
        s += __shfl_xor(s, off);
        ss += __shfl_xor(ss, off);
    }
    float mu = s * (1.0f / 512.0f);
    float var = ss * (1.0f / 512.0f) - mu * mu;
    float rs = rsqrtf(var + 1e-5f);
    float4 g0 = *reinterpret_cast<const float4*>(g + lane * 4);
    float4 g1 = *reinterpret_cast<const float4*>(g + 256 + lane * 4);
    float4 b0 = *reinterpret_cast<const float4*>(b + lane * 4);
    float4 b1 = *reinterpret_cast<const float4*>(b + 256 + lane * 4);
    float* yr = Y + row * 512;
    float4 o0, o1;
    o0.x = (v0.x - mu) * rs * g0.x + b0.x;
    o0.y = (v0.y - mu) * rs * g0.y + b0.y;
    o0.z = (v0.z - mu) * rs * g0.z + b0.z;
    o0.w = (v0.w - mu) * rs * g0.w + b0.w;
    o1.x = (v1.x - mu) * rs * g1.x + b1.x;
    o1.y = (v1.y - mu) * rs * g1.y + b1.y;
    o1.z = (v1.z - mu) * rs * g1.z + b1.z;
    o1.w = (v1.w - mu) * rs * g1.w + b1.w;
    *reinterpret_cast<float4*>(yr + lane * 4) = o0;
    *reinterpret_cast<float4*>(yr + 256 + lane * 4) = o1;
}

// ---------------------------------------------------------------------------
// Embedding gather: Ag[t][j*300+e] = embed[program[t][j]][e]
// ---------------------------------------------------------------------------
__global__ __launch_bounds__(256) void gather_kernel(
    const int* __restrict__ program, const float* __restrict__ embed,
    float* __restrict__ Ag, int total)
{
    int idx = blockIdx.x * 256 + threadIdx.x;
    if (idx >= total) return;
    int t = idx / 2400;
    int c = idx - t * 2400;
    int j = c / 300;
    int e = c - j * 300;
    int tok = program[t * 8 + j];
    Ag[idx] = embed[(size_t)tok * 300 + e];
}

// ---------------------------------------------------------------------------

static inline void gemm(const float* A, const float* B, const float* bias,
                        const float* Rsd, float* C, int M, int N, int K, int epi,
                        hipStream_t s)
{
    dim3 grid(N / TILE, M / TILE);
    gemm_f32_kernel<<<grid, 256, 0, s>>>(A, B, bias, Rsd, C, M, N, K, epi);
}

extern "C" void kernel_launch(void* const* d_in, const int* in_sizes, int n_in,
                              void* d_out, int out_size, void* d_ws, size_t ws_size,
                              hipStream_t stream)
{
    const int*   program = (const int*)d_in[0];
    const int*   adj     = (const int*)d_in[1];
    const float* img     = (const float*)d_in[2];
    const float* embed   = (const float*)d_in[3];
    const float* W_in    = (const float*)d_in[4];
    const float* b_in    = (const float*)d_in[5];
    const float* ln1_g   = (const float*)d_in[6];
    const float* ln1_b   = (const float*)d_in[7];
    const float* ln2_g   = (const float*)d_in[8];
    const float* ln2_b   = (const float*)d_in[9];
    const float* Wq      = (const float*)d_in[10];
    const float* bq      = (const float*)d_in[11];
    const float* Wk      = (const float*)d_in[12];
    const float* bk      = (const float*)d_in[13];
    const float* Wv      = (const float*)d_in[14];
    const float* bv      = (const float*)d_in[15];
    const float* Wo      = (const float*)d_in[16];
    const float* bo      = (const float*)d_in[17];
    const float* fW1     = (const float*)d_in[18];
    const float* fb1     = (const float*)d_in[19];
    const float* fW2     = (const float*)d_in[20];
    const float* fb2     = (const float*)d_in[21];
    const float* cWq     = (const float*)d_in[22];
    const float* cbq     = (const float*)d_in[23];
    const float* cWk     = (const float*)d_in[24];
    const float* cbk     = (const float*)d_in[25];
    const float* cWv     = (const float*)d_in[26];
    const float* cbv     = (const float*)d_in[27];
    const float* cWo     = (const float*)d_in[28];
    const float* cbo     = (const float*)d_in[29];

    float* ws = (float*)d_ws;
    float* x  = ws;              // 4096 x 512
    float* h  = ws + 2097152;    // 4096 x 512
    float* Qb = ws + 4194304;    // 4096 x 2048
    float* Kb = ws + 12582912;   // 4096 x 2048
    float* Vb = ws + 20971520;   // 4096 x 2048
    float* Sb = ws + 29360128;   // 128 x 256 x 256
    float* Ob = ws + 37748736;   // 4096 x 2048
    float* Ag = Sb;              // 4096 x 2400 (aliases S+O, dead after embed)
    float* g  = Qb;              // 4096 x 512 FFN mid (aliases Q)

    // Embedding gather + input projection
    gather_kernel<<<38400, 256, 0, stream>>>(program, embed, Ag, 9830400);
    gemm(Ag, W_in, b_in, nullptr, x, 4096, 512, 2400, EPI_NONE, stream);

    for (int l = 0; l < 6; l++) {
        const float* Wq_l  = Wq  + (size_t)l * 512 * 2048;
        const float* Wk_l  = Wk  + (size_t)l * 512 * 2048;
        const float* Wv_l  = Wv  + (size_t)l * 512 * 2048;
        const float* Wo_l  = Wo  + (size_t)l * 2048 * 512;
        const float* fW1_l = fW1 + (size_t)l * 512 * 512;
        const float* fW2_l = fW2 + (size_t)l * 512 * 512;
        const float* cWq_l = cWq + (size_t)l * 512 * 2048;
        const float* cWk_l = cWk + (size_t)l * 512 * 2048;
        const float* cWv_l = cWv + (size_t)l * 512 * 2048;
        const float* cWo_l = cWo + (size_t)l * 2048 * 512;
        const float* bq_l = bq + l * 2048;
        const float* bk_l = bk + l * 2048;
        const float* bv_l = bv + l * 2048;
        const float* bo_l = bo + l * 512;
        const float* fb1_l = fb1 + l * 512;
        const float* fb2_l = fb2 + l * 512;
        const float* cbq_l = cbq + l * 2048;
        const float* cbk_l = cbk + l * 2048;
        const float* cbv_l = cbv + l * 2048;
        const float* cbo_l = cbo + l * 512;

        // --- self-attention (pre-LN) ---
        ln_kernel<<<1024, 256, 0, stream>>>(x, ln1_g + l * 512, ln1_b + l * 512, h);
        gemm(h, Wq_l, bq_l, nullptr, Qb, 4096, 2048, 512, EPI_NONE, stream);
        gemm(h, Wk_l, bk_l, nullptr, Kb, 4096, 2048, 512, EPI_NONE, stream);
        gemm(h, Wv_l, bv_l, nullptr, Vb, 4096, 2048, 512, EPI_NONE, stream);
        score_kernel<<<dim3(4, 4, 128), 256, 0, stream>>>(Qb, Kb, adj, Sb, 1);
        softmax1_kernel<<<8192, 256, 0, stream>>>(Sb);
        pv_kernel<<<dim3(4, 4, 128), 256, 0, stream>>>(Sb, Vb, Ob);
        gemm(Ob, Wo_l, bo_l, x, x, 4096, 512, 2048, EPI_RESID, stream);

        // --- FFN (pre-LN) ---
        ln_kernel<<<1024, 256, 0, stream>>>(x, ln2_g + l * 512, ln2_b + l * 512, h);
        gemm(h, fW1_l, fb1_l, nullptr, g, 4096, 512, 512, EPI_GELU, stream);
        gemm(g, fW2_l, fb2_l, x, x, 4096, 512, 512, EPI_RESID, stream);

        // --- cross-attention (no LN on query, no mask) ---
        gemm(x, cWq_l, cbq_l, nullptr, Qb, 4096, 2048, 512, EPI_NONE, stream);
        gemm(img, cWk_l, cbk_l, nullptr, Kb, 4096, 2048, 512, EPI_NONE, stream);
        gemm(img, cWv_l, cbv_l, nullptr, Vb, 4096, 2048, 512, EPI_NONE, stream);
        score_kernel<<<dim3(4, 4, 128), 256, 0, stream>>>(Qb, Kb, nullptr, Sb, 0);
        softmax1_kernel<<<8192, 256, 0, stream>>>(Sb);
        pv_kernel<<<dim3(4, 4, 128), 256, 0, stream>>>(Sb, Vb, Ob);
        gemm(Ob, cWo_l, cbo_l, x, x, 4096, 512, 2048, EPI_RESID, stream);
    }

    hipMemcpyAsync(d_out, x, (size_t)2097152 * sizeof(float),
                   hipMemcpyDeviceToDevice, stream);
}

// Round 2
// 6643.102 us; speedup vs baseline: 1.8887x; 1.8887x over previous
//
#include <hip/hip_runtime.h>
#include <hip/hip_bf16.h>

typedef __attribute__((ext_vector_type(8))) short short8;
typedef __attribute__((ext_vector_type(4))) float f32x4;
typedef unsigned short u16;

__device__ __forceinline__ u16 f2b(float f) {
    unsigned int u = __builtin_bit_cast(unsigned int, f);
    u = u + 0x7fffu + ((u >> 16) & 1u);
    return (u16)(u >> 16);
}

// epilogue modes
#define EPI_F32      0   // outF = acc + bias0
#define EPI_BF16     1   // outB = bf16(acc + bias0)
#define EPI_RESID    2   // outF = acc + bias0 + Rsd
#define EPI_RESID_XB 3   // EPI_RESID + outB = bf16(same)
#define EPI_GELU     4   // outB = bf16(gelu(acc + bias0))
#define EPI_SCORES   5   // outF[bz] = acc/16 (+ mask from adj)
#define EPI_QKV      6   // 3-way split: Q(outB), K(outB2), V-transposed(outV)
#define EPI_KV       7   // 2-way split: K(outB), V-transposed(outV)
#define EPI_PV       8   // outB[(b*256+r)*2048 + h*256 + c] = bf16(acc)

// ---------------------------------------------------------------------------
// bf16 MFMA GEMM: C = A(M,K) @ Bt(N,K)^T, f32 accumulate, fused epilogues.
// BM x 128 tile, BK=32, 256 threads (4 waves 2x2), 16x16x32 bf16 MFMA.
// A, Bt are bf16 [rows][K] with leading dims lda/ldb (elements).
// LDS slot-swizzled: slot = kg ^ ((row>>1)&3)  (2-way max -> free).
// ---------------------------------------------------------------------------
template<int BM>
__global__ __launch_bounds__(256) void gemm_bf16_kernel(
    const u16* __restrict__ A, long aStride, int lda,
    const u16* __restrict__ B, long bStride, int ldb,
    int M, int N, int K, int epi,
    const float* __restrict__ bias0, const float* __restrict__ bias1,
    const float* __restrict__ bias2,
    const float* __restrict__ Rsd, const int* __restrict__ adj,
    float* __restrict__ outF, u16* __restrict__ outB,
    u16* __restrict__ outB2, u16* __restrict__ outV,
    long cStride, int ldc)
{
    constexpr int BN = 128;
    constexpr int WM = BM / 2;   // wave tile rows
    constexpr int MF = WM / 16;  // A fragments per wave
    constexpr int NF = 4;        // B fragments per wave (64 cols)
    constexpr int AUNITS = BM * 4;          // 16B units in A tile
    constexpr int UPT = (BM + BN) / 64;     // units per thread

    __shared__ __align__(16) u16 smem[(BM + BN) * 32];
    u16* As = smem;
    u16* Bs = smem + BM * 32;

    const int tid = threadIdx.x;
    const int wave = tid >> 6, lane = tid & 63;
    const int wm = wave >> 1, wn = wave & 1;
    const int tm = blockIdx.y * BM, tn = blockIdx.x * BN;
    const int bz = blockIdx.z;

    size_t aOff, bOff;
    if (epi == EPI_SCORES) {  // per-(batch,head) view of Q/K [4096][2048]
        aOff = bOff = (size_t)(bz >> 3) * 524288 + (size_t)(bz & 7) * 256;
    } else {
        aOff = (size_t)bz * (size_t)aStride;
        bOff = (size_t)bz * (size_t)bStride;
    }

    const int lr = lane & 15, kg = lane >> 4;
    const int slotx = (lr >> 1) & 3;

    f32x4 acc[MF][NF];
#pragma unroll
    for (int m = 0; m < MF; m++)
#pragma unroll
        for (int n = 0; n < NF; n++) acc[m][n] = (f32x4)(0.f);

    for (int k0 = 0; k0 < K; k0 += 32) {
#pragma unroll
        for (int i = 0; i < UPT; i++) {
            int u = tid + i * 256;
            const u16* src;
            u16* dst;
            if (u < AUNITS) {
                int row = u >> 2, g = u & 3;
                src = A + aOff + (size_t)(tm + row) * lda + k0 + g * 8;
                dst = As + row * 32 + ((g ^ ((row >> 1) & 3)) * 8);
            } else {
                int v2 = u - AUNITS;
                int row = v2 >> 2, g = v2 & 3;
                src = B + bOff + (size_t)(tn + row) * ldb + k0 + g * 8;
                dst = Bs + row * 32 + ((g ^ ((row >> 1) & 3)) * 8);
            }
            *(uint4*)dst = *(const uint4*)src;
        }
        __syncthreads();

        short8 af[MF], bfr[NF];
#pragma unroll
        for (int m = 0; m < MF; m++) {
            int row = wm * WM + m * 16 + lr;
            af[m] = *(const short8*)&As[row * 32 + ((kg ^ slotx) * 8)];
        }
#pragma unroll
        for (int n = 0; n < NF; n++) {
            int row = wn * 64 + n * 16 + lr;
            bfr[n] = *(const short8*)&Bs[row * 32 + ((kg ^ slotx) * 8)];
        }
#pragma unroll
        for (int m = 0; m < MF; m++)
#pragma unroll
            for (int n = 0; n < NF; n++)
                acc[m][n] = __builtin_amdgcn_mfma_f32_16x16x32_bf16(
                    af[m], bfr[n], acc[m][n], 0, 0, 0);
        __syncthreads();
    }

    // epilogue: D row=(lane>>4)*4+e, col=lane&15
#pragma unroll
    for (int m = 0; m < MF; m++) {
#pragma unroll
        for (int n = 0; n < NF; n++) {
#pragma unroll
            for (int e = 0; e < 4; e++) {
                int r = tm + wm * WM + m * 16 + (lane >> 4) * 4 + e;
                int c = tn + wn * 64 + n * 16 + (lane & 15);
                float v = acc[m][n][e];
                switch (epi) {
                case EPI_F32:
                    outF[(size_t)r * ldc + c] = v + bias0[c];
                    break;
                case EPI_BF16: {
                    float t = v + (bias0 ? bias0[c] : 0.f);
                    outB[(size_t)r * ldc + c] = f2b(t);
                } break;
                case EPI_RESID:
                    outF[(size_t)r * ldc + c] = v + bias0[c] + Rsd[(size_t)r * ldc + c];
                    break;
                case EPI_RESID_XB: {
                    float t = v + bias0[c] + Rsd[(size_t)r * ldc + c];
                    outF[(size_t)r * ldc + c] = t;
                    outB[(size_t)r * ldc + c] = f2b(t);
                } break;
                case EPI_GELU: {
                    float t = v + bias0[c];
                    t = 0.5f * t * (1.f + erff(t * 0.70710678118654752f));
                    outB[(size_t)r * ldc + c] = f2b(t);
                } break;
                case EPI_SCORES: {
                    float t = v * 0.0625f;
                    if (adj) {
                        int a_ = adj[((size_t)(bz >> 3) * 256 + r) * 256 + c];
                        t += (1.f - (float)a_) * -1.0e6f;
                    }
                    outF[(size_t)bz * cStride + (size_t)r * ldc + c] = t;
                } break;
                case EPI_QKV: {
                    int sel = c >> 11, cc = c & 2047;
                    const float* bp = sel == 0 ? bias0 : (sel == 1 ? bias1 : bias2);
                    float t = v + bp[cc];
                    if (sel == 0)
                        outB[(size_t)r * 2048 + cc] = f2b(t);
                    else if (sel == 1)
                        outB2[(size_t)r * 2048 + cc] = f2b(t);
                    else
                        outV[(size_t)((r >> 8) * 8 + (cc >> 8)) * 65536 +
                             (size_t)(cc & 255) * 256 + (r & 255)] = f2b(t);
                } break;
                case EPI_KV: {
                    int sel = c >> 11, cc = c & 2047;
                    float t = v + (sel == 0 ? bias0 : bias1)[cc];
                    if (sel == 0)
                        outB[(size_t)r * 2048 + cc] = f2b(t);
                    else
                        outV[(size_t)((r >> 8) * 8 + (cc >> 8)) * 65536 +
                             (size_t)(cc & 255) * 256 + (r & 255)] = f2b(t);
                } break;
                case EPI_PV:
                    outB[((size_t)(bz >> 3) * 256 + r) * 2048 + (bz & 7) * 256 + c] = f2b(v);
                    break;
                }
            }
        }
    }
}

// ---------------------------------------------------------------------------
// Transpose+convert: W f32 [R][C] -> out bf16 [C][R]. blockIdx.z selects src.
// ---------------------------------------------------------------------------
__global__ __launch_bounds__(256) void transpose_kernel(
    const float* p0, const float* p1, const float* p2,
    const float* p3, const float* p4, const float* p5,
    int R, int C, u16* __restrict__ out, long outStride)
{
    const float* W;
    switch (blockIdx.z) {
    default: W = p0; break;
    case 1: W = p1; break;
    case 2: W = p2; break;
    case 3: W = p3; break;
    case 4: W = p4; break;
    case 5: W = p5; break;
    }
    u16* o = out + (size_t)blockIdx.z * outStride;
    __shared__ float t[64][65];
    const int tid = threadIdx.x;
    const int rBase = blockIdx.y * 64, cBase = blockIdx.x * 64;
#pragma unroll
    for (int i = 0; i < 16; i++) {
        int idx = tid + i * 256;
        int rr = idx >> 6, cc = idx & 63;
        float v = 0.f;
        if (rBase + rr < R) v = W[(size_t)(rBase + rr) * C + cBase + cc];
        t[rr][cc] = v;
    }
    __syncthreads();
#pragma unroll
    for (int i = 0; i < 16; i++) {
        int idx = tid + i * 256;
        int cc = idx >> 6, rr = idx & 63;
        if (rBase + rr < R)
            o[(size_t)(cBase + cc) * R + rBase + rr] = f2b(t[rr][cc]);
    }
}

// ---------------------------------------------------------------------------
// Softmax with +1 denominator, rows of 256 f32 -> bf16 P. One wave per row.
// ---------------------------------------------------------------------------
__global__ __launch_bounds__(256) void softmax1_kernel(
    const float* __restrict__ S, u16* __restrict__ P)
{
    const int wave = threadIdx.x >> 6, lane = threadIdx.x & 63;
    const size_t row = (size_t)blockIdx.x * 4 + wave;
    float4 v = *reinterpret_cast<const float4*>(S + row * 256 + lane * 4);
    float m = fmaxf(fmaxf(v.x, v.y), fmaxf(v.z, v.w));
#pragma unroll
    for (int off = 32; off; off >>= 1) m = fmaxf(m, __shfl_xor(m, off));
    float e0 = expf(v.x - m), e1 = expf(v.y - m), e2 = expf(v.z - m), e3 = expf(v.w - m);
    float s = e0 + e1 + e2 + e3;
#pragma unroll
    for (int off = 32; off; off >>= 1) s += __shfl_xor(s, off);
    float inv = 1.0f / (1.0f + s);
    uint2 pk;
    pk.x = (unsigned)f2b(e0 * inv) | ((unsigned)f2b(e1 * inv) << 16);
    pk.y = (unsigned)f2b(e2 * inv) | ((unsigned)f2b(e3 * inv) << 16);
    *reinterpret_cast<uint2*>(P + row * 256 + lane * 4) = pk;
}

// ---------------------------------------------------------------------------
// LayerNorm rows of 512, f32 in -> bf16 out. One wave per row.
// ---------------------------------------------------------------------------
__global__ __launch_bounds__(256) void ln_kernel(
    const float* __restrict__ X, const float* __restrict__ g,
    const float* __restrict__ b, u16* __restrict__ Y)
{
    const int wave = threadIdx.x >> 6, lane = threadIdx.x & 63;
    const size_t row = (size_t)blockIdx.x * 4 + wave;
    const float* xr = X + row * 512;
    float4 v0 = *reinterpret_cast<const float4*>(xr + lane * 8);
    float4 v1 = *reinterpret_cast<const float4*>(xr + lane * 8 + 4);
    float s = v0.x + v0.y + v0.z + v0.w + v1.x + v1.y + v1.z + v1.w;
    float ss = v0.x * v0.x + v0.y * v0.y + v0.z * v0.z + v0.w * v0.w +
               v1.x * v1.x + v1.y * v1.y + v1.z * v1.z + v1.w * v1.w;
#pragma unroll
    for (int off = 32; off; off >>= 1) {
        s += __shfl_xor(s, off);
        ss += __shfl_xor(ss, off);
    }
    float mu = s * (1.0f / 512.0f);
    float var = ss * (1.0f / 512.0f) - mu * mu;
    float rs = rsqrtf(var + 1e-5f);
    float4 g0 = *reinterpret_cast<const float4*>(g + lane * 8);
    float4 g1 = *reinterpret_cast<const float4*>(g + lane * 8 + 4);
    float4 b0 = *reinterpret_cast<const float4*>(b + lane * 8);
    float4 b1 = *reinterpret_cast<const float4*>(b + lane * 8 + 4);
    float o0 = (v0.x - mu) * rs * g0.x + b0.x;
    float o1 = (v0.y - mu) * rs * g0.y + b0.y;
    float o2 = (v0.z - mu) * rs * g0.z + b0.z;
    float o3 = (v0.w - mu) * rs * g0.w + b0.w;
    float o4 = (v1.x - mu) * rs * g1.x + b1.x;
    float o5 = (v1.y - mu) * rs * g1.y + b1.y;
    float o6 = (v1.z - mu) * rs * g1.z + b1.z;
    float o7 = (v1.w - mu) * rs * g1.w + b1.w;
    uint4 pk;
    pk.x = (unsigned)f2b(o0) | ((unsigned)f2b(o1) << 16);
    pk.y = (unsigned)f2b(o2) | ((unsigned)f2b(o3) << 16);
    pk.z = (unsigned)f2b(o4) | ((unsigned)f2b(o5) << 16);
    pk.w = (unsigned)f2b(o6) | ((unsigned)f2b(o7) << 16);
    *reinterpret_cast<uint4*>(Y + row * 512 + lane * 8) = pk;
}

// ---------------------------------------------------------------------------
// Embedding gather -> bf16: Ag[t][j*300+e] = embed[program[t][j]][e]
// ---------------------------------------------------------------------------
__global__ __launch_bounds__(256) void gather_kernel(
    const int* __restrict__ program, const float* __restrict__ embed,
    u16* __restrict__ Ag, int total)
{
    int idx = blockIdx.x * 256 + threadIdx.x;
    if (idx >= total) return;
    int t = idx / 2400;
    int c = idx - t * 2400;
    int j = c / 300;
    int e = c - j * 300;
    int tok = program[t * 8 + j];
    Ag[idx] = f2b(embed[(size_t)tok * 300 + e]);
}

// f32 -> bf16 convert, 4 elems/thread
__global__ __launch_bounds__(256) void cvt_kernel(
    const float* __restrict__ in, u16* __restrict__ out, int n4)
{
    int i = blockIdx.x * 256 + threadIdx.x;
    if (i >= n4) return;
    float4 v = reinterpret_cast<const float4*>(in)[i];
    uint2 pk;
    pk.x = (unsigned)f2b(v.x) | ((unsigned)f2b(v.y) << 16);
    pk.y = (unsigned)f2b(v.z) | ((unsigned)f2b(v.w) << 16);
    reinterpret_cast<uint2*>(out)[i] = pk;
}

// ---------------------------------------------------------------------------

extern "C" void kernel_launch(void* const* d_in, const int* in_sizes, int n_in,
                              void* d_out, int out_size, void* d_ws, size_t ws_size,
                              hipStream_t stream)
{
    const int*   program = (const int*)d_in[0];
    const int*   adj     = (const int*)d_in[1];
    const float* img     = (const float*)d_in[2];
    const float* embed   = (const float*)d_in[3];
    const float* W_in    = (const float*)d_in[4];
    const float* b_in    = (const float*)d_in[5];
    const float* ln1_g   = (const float*)d_in[6];
    const float* ln1_b   = (const float*)d_in[7];
    const float* ln2_g   = (const float*)d_in[8];
    const float* ln2_b   = (const float*)d_in[9];
    const float* Wq      = (const float*)d_in[10];
    const float* bq      = (const float*)d_in[11];
    const float* Wk      = (const float*)d_in[12];
    const float* bk      = (const float*)d_in[13];
    const float* Wv      = (const float*)d_in[14];
    const float* bv      = (const float*)d_in[15];
    const float* Wo      = (const float*)d_in[16];
    const float* bo      = (const float*)d_in[17];
    const float* fW1     = (const float*)d_in[18];
    const float* fb1     = (const float*)d_in[19];
    const float* fW2     = (const float*)d_in[20];
    const float* fb2     = (const float*)d_in[21];
    const float* cWq     = (const float*)d_in[22];
    const float* cbq     = (const float*)d_in[23];
    const float* cWk     = (const float*)d_in[24];
    const float* cbk     = (const float*)d_in[25];
    const float* cWv     = (const float*)d_in[26];
    const float* cbv     = (const float*)d_in[27];
    const float* cWo     = (const float*)d_in[28];
    const float* cbo     = (const float*)d_in[29];

    char* wsb = (char*)d_ws;
    const size_t MB = 1024 * 1024;
    float* x    = (float*)(wsb + 0);             // 4096x512 f32      (8 MB)
    float* S    = (float*)(wsb + 8 * MB);        // 128x256x256 f32   (32 MB)
    u16*   h    = (u16*)(wsb + 40 * MB);         // 4096x512 bf16     (4 MB)
    u16*   xb   = (u16*)(wsb + 44 * MB);         // 4096x512 bf16     (4 MB)
    u16*   Q    = (u16*)(wsb + 48 * MB);         // 4096x2048 bf16    (16 MB)
    u16*   Kb   = (u16*)(wsb + 64 * MB);         // 4096x2048 bf16    (16 MB)
    u16*   Vt   = (u16*)(wsb + 80 * MB);         // [128][256][256]   (16 MB)
    u16*   P    = (u16*)(wsb + 96 * MB);         // 128x256x256 bf16  (16 MB)
    u16*   O    = (u16*)(wsb + 112 * MB);        // 4096x2048 bf16    (16 MB)
    u16*   imgb = (u16*)(wsb + 128 * MB);        // 4096x512 bf16     (4 MB)
    u16*   Wt   = (u16*)(wsb + 132 * MB);        // per-layer weights (17 MB)
    u16*   WinT = (u16*)(wsb + 149 * MB);        // 512x2400 bf16     (2.4 MB)
    u16*   Ag   = Q;   // gather buffer aliases Q+K (dead before QKV)
    u16*   g    = Q;   // FFN mid aliases Q (dead during FFN)
    const long Mi = 1048576;

    // prologue
    gather_kernel<<<38400, 256, 0, stream>>>(program, embed, Ag, 9830400);
    transpose_kernel<<<dim3(8, 38, 1), 256, 0, stream>>>(
        W_in, nullptr, nullptr, nullptr, nullptr, nullptr, 2400, 512, WinT, 0);
    cvt_kernel<<<2048, 256, 0, stream>>>(img, imgb, 524288);
    gemm_bf16_kernel<64><<<dim3(4, 64, 1), 256, 0, stream>>>(
        Ag, 0, 2400, WinT, 0, 2400, 4096, 512, 2400, EPI_F32,
        b_in, nullptr, nullptr, nullptr, nullptr,
        x, nullptr, nullptr, nullptr, 0, 512);

    for (int l = 0; l < 6; l++) {
        const float* Wq_l  = Wq  + (size_t)l * 512 * 2048;
        const float* Wk_l  = Wk  + (size_t)l * 512 * 2048;
        const float* Wv_l  = Wv  + (size_t)l * 512 * 2048;
        const float* Wo_l  = Wo  + (size_t)l * 2048 * 512;
        const float* fW1_l = fW1 + (size_t)l * 512 * 512;
        const float* fW2_l = fW2 + (size_t)l * 512 * 512;
        const float* cWq_l = cWq + (size_t)l * 512 * 2048;
        const float* cWk_l = cWk + (size_t)l * 512 * 2048;
        const float* cWv_l = cWv + (size_t)l * 512 * 2048;
        const float* cWo_l = cWo + (size_t)l * 2048 * 512;

        // per-layer weight transpose+convert into Wt
        transpose_kernel<<<dim3(32, 8, 6), 256, 0, stream>>>(
            Wq_l, Wk_l, Wv_l, cWq_l, cWk_l, cWv_l, 512, 2048, Wt, Mi);
        transpose_kernel<<<dim3(8, 32, 2), 256, 0, stream>>>(
            Wo_l, cWo_l, nullptr, nullptr, nullptr, nullptr, 2048, 512, Wt + 6 * Mi, Mi);
        transpose_kernel<<<dim3(8, 8, 2), 256, 0, stream>>>(
            fW1_l, fW2_l, nullptr, nullptr, nullptr, nullptr, 512, 512, Wt + 8 * Mi, 262144);

        // --- self-attention ---
        ln_kernel<<<1024, 256, 0, stream>>>(x, ln1_g + l * 512, ln1_b + l * 512, h);
        gemm_bf16_kernel<128><<<dim3(48, 32, 1), 256, 0, stream>>>(
            h, 0, 512, Wt, 0, 512, 4096, 6144, 512, EPI_QKV,
            bq + l * 2048, bk + l * 2048, bv + l * 2048, nullptr, nullptr,
            nullptr, Q, Kb, Vt, 0, 2048);
        gemm_bf16_kernel<128><<<dim3(2, 2, 128), 256, 0, stream>>>(
            Q, 0, 2048, Kb, 0, 2048, 256, 256, 256, EPI_SCORES,
            nullptr, nullptr, nullptr, nullptr, adj,
            S, nullptr, nullptr, nullptr, 65536, 256);
        softmax1_kernel<<<8192, 256, 0, stream>>>(S, P);
        gemm_bf16_kernel<128><<<dim3(2, 2, 128), 256, 0, stream>>>(
            P, 65536, 256, Vt, 65536, 256, 256, 256, 256, EPI_PV,
            nullptr, nullptr, nullptr, nullptr, nullptr,
            nullptr, O, nullptr, nullptr, 0, 2048);
        gemm_bf16_kernel<64><<<dim3(4, 64, 1), 256, 0, stream>>>(
            O, 0, 2048, Wt + 6 * Mi, 0, 2048, 4096, 512, 2048, EPI_RESID,
            bo + l * 512, nullptr, nullptr, x, nullptr,
            x, nullptr, nullptr, nullptr, 0, 512);

        // --- FFN ---
        ln_kernel<<<1024, 256, 0, stream>>>(x, ln2_g + l * 512, ln2_b + l * 512, h);
        gemm_bf16_kernel<64><<<dim3(4, 64, 1), 256, 0, stream>>>(
            h, 0, 512, Wt + 8 * Mi, 0, 512, 4096, 512, 512, EPI_GELU,
            fb1 + l * 512, nullptr, nullptr, nullptr, nullptr,
            nullptr, g, nullptr, nullptr, 0, 512);
        gemm_bf16_kernel<64><<<dim3(4, 64, 1), 256, 0, stream>>>(
            g, 0, 512, Wt + 8 * Mi + 262144, 0, 512, 4096, 512, 512, EPI_RESID_XB,
            fb2 + l * 512, nullptr, nullptr, x, nullptr,
            x, xb, nullptr, nullptr, 0, 512);

        // --- cross-attention (query = x, no mask) ---
        gemm_bf16_kernel<128><<<dim3(16, 32, 1), 256, 0, stream>>>(
            xb, 0, 512, Wt + 3 * Mi, 0, 512, 4096, 2048, 512, EPI_BF16,
            cbq + l * 2048, nullptr, nullptr, nullptr, nullptr,
            nullptr, Q, nullptr, nullptr, 0, 2048);
        gemm_bf16_kernel<128><<<dim3(32, 32, 1), 256, 0, stream>>>(
            imgb, 0, 512, Wt + 4 * Mi, 0, 512, 4096, 4096, 512, EPI_KV,
            cbk + l * 2048, cbv + l * 2048, nullptr, nullptr, nullptr,
            nullptr, Kb, nullptr, Vt, 0, 2048);
        gemm_bf16_kernel<128><<<dim3(2, 2, 128), 256, 0, stream>>>(
            Q, 0, 2048, Kb, 0, 2048, 256, 256, 256, EPI_SCORES,
            nullptr, nullptr, nullptr, nullptr, nullptr,
            S, nullptr, nullptr, nullptr, 65536, 256);
        softmax1_kernel<<<8192, 256, 0, stream>>>(S, P);
        gemm_bf16_kernel<128><<<dim3(2, 2, 128), 256, 0, stream>>>(
            P, 65536, 256, Vt, 65536, 256, 256, 256, 256, EPI_PV,
            nullptr, nullptr, nullptr, nullptr, nullptr,
            nullptr, O, nullptr, nullptr, 0, 2048);
        gemm_bf16_kernel<64><<<dim3(4, 64, 1), 256, 0, stream>>>(
            O, 0, 2048, Wt + 7 * Mi, 0, 2048, 4096, 512, 2048, EPI_RESID,
            cbo + l * 512, nullptr, nullptr, x, nullptr,
            x, nullptr, nullptr, nullptr, 0, 512);
    }

    hipMemcpyAsync(d_out, x, (size_t)2097152 * sizeof(float),
                   hipMemcpyDeviceToDevice, stream);
}

// Round 3
// 2197.461 us; speedup vs baseline: 5.7098x; 3.0231x over previous
//
#include <hip/hip_runtime.h>
#include <hip/hip_bf16.h>

typedef __attribute__((ext_vector_type(8))) short short8;
typedef __attribute__((ext_vector_type(4))) float f32x4;
typedef unsigned short u16;

__device__ __forceinline__ u16 f2b(float f) {
    unsigned int u = __builtin_bit_cast(unsigned int, f);
    u = u + 0x7fffu + ((u >> 16) & 1u);
    return (u16)(u >> 16);
}

// epilogue modes (template parameter)
#define EPI_F32      0   // outF = acc + bias0
#define EPI_BF16     1   // outB = bf16(acc + bias0)
#define EPI_RESID    2   // outF = acc + bias0 + Rsd
#define EPI_RESID_XB 3   // EPI_RESID + outB = bf16(same)
#define EPI_GELU     4   // outB = bf16(gelu(acc + bias0))
#define EPI_SCORES   5   // outF[bz] = acc/16 (+ mask from adj)
#define EPI_QKV      6   // 3-way split: Q(outB), K(outB2), V-transposed(outV)
#define EPI_KV       7   // 2-way split: K(outB), V-transposed(outV)
#define EPI_PV       8   // outB[(b*256+r)*2048 + h*256 + c] = bf16(acc)

// ---------------------------------------------------------------------------
// bf16 MFMA GEMM: C = A(M,K) @ Bt(N,K)^T, f32 accumulate, fused epilogue EPI.
// BM x 128 tile, BK=32, 256 threads (4 waves 2x2), 16x16x32 bf16 MFMA.
// Staging: global_load_lds width=16; LDS linear, XOR-swizzle applied to the
// per-lane GLOBAL source k-group (involution), ds_read applies same XOR.
// ---------------------------------------------------------------------------
template<int BM, int EPI>
__global__ __launch_bounds__(256, 2) void gemm_bf16(
    const u16* __restrict__ A, long aStride, int lda,
    const u16* __restrict__ B, long bStride, int ldb,
    int M, int N, int K,
    const float* __restrict__ bias0, const float* __restrict__ bias1,
    const float* __restrict__ bias2,
    const float* __restrict__ Rsd, const int* __restrict__ adj,
    float* __restrict__ outF, u16* __restrict__ outB,
    u16* __restrict__ outB2, u16* __restrict__ outV,
    long cStride, int ldc)
{
    constexpr int BN = 128;
    constexpr int WM = BM / 2;   // wave tile rows
    constexpr int MF = WM / 16;  // A fragments per wave
    constexpr int NF = 4;        // B fragments per wave (64 cols)
    constexpr int AUNITS = BM * 4;          // 16B units in A tile
    constexpr int UPT = (BM + BN) / 64;     // 16B units per thread

    __shared__ __align__(16) u16 smem[(BM + BN) * 32];
    u16* As = smem;
    u16* Bs = smem + BM * 32;

    const int tid = threadIdx.x;
    const int wave = tid >> 6, lane = tid & 63;
    const int wm = wave >> 1, wn = wave & 1;
    const int tm = blockIdx.y * BM, tn = blockIdx.x * BN;
    const int bz = blockIdx.z;

    size_t aOff, bOff;
    if constexpr (EPI == EPI_SCORES) {  // per-(batch,head) view of [4096][2048]
        aOff = bOff = (size_t)(bz >> 3) * 524288 + (size_t)(bz & 7) * 256;
    } else {
        aOff = (size_t)bz * (size_t)aStride;
        bOff = (size_t)bz * (size_t)bStride;
    }

    const int lr = lane & 15, kg = lane >> 4;
    const int slotx = (lr >> 1) & 3;

    f32x4 acc[MF][NF];
#pragma unroll
    for (int m = 0; m < MF; m++)
#pragma unroll
        for (int n = 0; n < NF; n++) acc[m][n] = (f32x4)(0.f);

    for (int k0 = 0; k0 < K; k0 += 32) {
#pragma unroll
        for (int i = 0; i < UPT; i++) {
            int u = tid + i * 256;
            u16* dst = smem + u * 8;  // linear LDS: base + lane*16B per wave
            if (u < AUNITS) {
                int row = u >> 2, g = u & 3;
                int gs = g ^ ((row >> 1) & 3);
                const u16* src = A + aOff + (size_t)(tm + row) * lda + k0 + gs * 8;
                __builtin_amdgcn_global_load_lds(src, dst, 16, 0, 0);
            } else {
                int v2 = u - AUNITS;
                int row = v2 >> 2, g = v2 & 3;
                int gs = g ^ ((row >> 1) & 3);
                const u16* src = B + bOff + (size_t)(tn + row) * ldb + k0 + gs * 8;
                __builtin_amdgcn_global_load_lds(src, dst, 16, 0, 0);
            }
        }
        __syncthreads();

        short8 af[MF], bfr[NF];
#pragma unroll
        for (int m = 0; m < MF; m++) {
            int row = wm * WM + m * 16 + lr;
            af[m] = *(const short8*)&As[row * 32 + ((kg ^ slotx) * 8)];
        }
#pragma unroll
        for (int n = 0; n < NF; n++) {
            int row = wn * 64 + n * 16 + lr;
            bfr[n] = *(const short8*)&Bs[row * 32 + ((kg ^ slotx) * 8)];
        }
#pragma unroll
        for (int m = 0; m < MF; m++)
#pragma unroll
            for (int n = 0; n < NF; n++)
                acc[m][n] = __builtin_amdgcn_mfma_f32_16x16x32_bf16(
                    af[m], bfr[n], acc[m][n], 0, 0, 0);
        __syncthreads();
    }

    // epilogue: D row=(lane>>4)*4+e, col=lane&15
#pragma unroll
    for (int m = 0; m < MF; m++) {
#pragma unroll
        for (int n = 0; n < NF; n++) {
#pragma unroll
            for (int e = 0; e < 4; e++) {
                int r = tm + wm * WM + m * 16 + (lane >> 4) * 4 + e;
                int c = tn + wn * 64 + n * 16 + (lane & 15);
                float v = acc[m][n][e];
                if constexpr (EPI == EPI_F32) {
                    outF[(size_t)r * ldc + c] = v + bias0[c];
                } else if constexpr (EPI == EPI_BF16) {
                    outB[(size_t)r * ldc + c] = f2b(v + bias0[c]);
                } else if constexpr (EPI == EPI_RESID) {
                    outF[(size_t)r * ldc + c] = v + bias0[c] + Rsd[(size_t)r * ldc + c];
                } else if constexpr (EPI == EPI_RESID_XB) {
                    float t = v + bias0[c] + Rsd[(size_t)r * ldc + c];
                    outF[(size_t)r * ldc + c] = t;
                    outB[(size_t)r * ldc + c] = f2b(t);
                } else if constexpr (EPI == EPI_GELU) {
                    float t = v + bias0[c];
                    t = 0.5f * t * (1.f + erff(t * 0.70710678118654752f));
                    outB[(size_t)r * ldc + c] = f2b(t);
                } else if constexpr (EPI == EPI_SCORES) {
                    float t = v * 0.0625f;
                    if (adj) {
                        int a_ = adj[((size_t)(bz >> 3) * 256 + r) * 256 + c];
                        t += (1.f - (float)a_) * -1.0e6f;
                    }
                    outF[(size_t)bz * cStride + (size_t)r * ldc + c] = t;
                } else if constexpr (EPI == EPI_QKV) {
                    int sel = c >> 11, cc = c & 2047;
                    const float* bp = sel == 0 ? bias0 : (sel == 1 ? bias1 : bias2);
                    float t = v + bp[cc];
                    if (sel == 0)
                        outB[(size_t)r * 2048 + cc] = f2b(t);
                    else if (sel == 1)
                        outB2[(size_t)r * 2048 + cc] = f2b(t);
                    else
                        outV[(size_t)((r >> 8) * 8 + (cc >> 8)) * 65536 +
                             (size_t)(cc & 255) * 256 + (r & 255)] = f2b(t);
                } else if constexpr (EPI == EPI_KV) {
                    int sel = c >> 11, cc = c & 2047;
                    float t = v + (sel == 0 ? bias0 : bias1)[cc];
                    if (sel == 0)
                        outB[(size_t)r * 2048 + cc] = f2b(t);
                    else
                        outV[(size_t)((r >> 8) * 8 + (cc >> 8)) * 65536 +
                             (size_t)(cc & 255) * 256 + (r & 255)] = f2b(t);
                } else if constexpr (EPI == EPI_PV) {
                    outB[((size_t)(bz >> 3) * 256 + r) * 2048 + (bz & 7) * 256 + c] = f2b(v);
                }
            }
        }
    }
}

// ---------------------------------------------------------------------------
// Transpose+convert: W f32 [R][C] -> out bf16 [C][R]. blockIdx.z selects src.
// ---------------------------------------------------------------------------
__global__ __launch_bounds__(256) void transpose_kernel(
    const float* p0, const float* p1, const float* p2,
    const float* p3, const float* p4, const float* p5,
    int R, int C, u16* __restrict__ out, long outStride)
{
    const float* W;
    switch (blockIdx.z) {
    default: W = p0; break;
    case 1: W = p1; break;
    case 2: W = p2; break;
    case 3: W = p3; break;
    case 4: W = p4; break;
    case 5: W = p5; break;
    }
    u16* o = out + (size_t)blockIdx.z * outStride;
    __shared__ float t[64][65];
    const int tid = threadIdx.x;
    const int rBase = blockIdx.y * 64, cBase = blockIdx.x * 64;
#pragma unroll
    for (int i = 0; i < 16; i++) {
        int idx = tid + i * 256;
        int rr = idx >> 6, cc = idx & 63;
        float v = 0.f;
        if (rBase + rr < R) v = W[(size_t)(rBase + rr) * C + cBase + cc];
        t[rr][cc] = v;
    }
    __syncthreads();
#pragma unroll
    for (int i = 0; i < 16; i++) {
        int idx = tid + i * 256;
        int cc = idx >> 6, rr = idx & 63;
        if (rBase + rr < R)
            o[(size_t)(cBase + cc) * R + rBase + rr] = f2b(t[rr][cc]);
    }
}

// ---------------------------------------------------------------------------
// Softmax with +1 denominator, rows of 256 f32 -> bf16 P. One wave per row.
// ---------------------------------------------------------------------------
__global__ __launch_bounds__(256) void softmax1_kernel(
    const float* __restrict__ S, u16* __restrict__ P)
{
    const int wave = threadIdx.x >> 6, lane = threadIdx.x & 63;
    const size_t row = (size_t)blockIdx.x * 4 + wave;
    float4 v = *reinterpret_cast<const float4*>(S + row * 256 + lane * 4);
    float m = fmaxf(fmaxf(v.x, v.y), fmaxf(v.z, v.w));
#pragma unroll
    for (int off = 32; off; off >>= 1) m = fmaxf(m, __shfl_xor(m, off));
    float e0 = expf(v.x - m), e1 = expf(v.y - m), e2 = expf(v.z - m), e3 = expf(v.w - m);
    float s = e0 + e1 + e2 + e3;
#pragma unroll
    for (int off = 32; off; off >>= 1) s += __shfl_xor(s, off);
    float inv = 1.0f / (1.0f + s);
    uint2 pk;
    pk.x = (unsigned)f2b(e0 * inv) | ((unsigned)f2b(e1 * inv) << 16);
    pk.y = (unsigned)f2b(e2 * inv) | ((unsigned)f2b(e3 * inv) << 16);
    *reinterpret_cast<uint2*>(P + row * 256 + lane * 4) = pk;
}

// ---------------------------------------------------------------------------
// LayerNorm rows of 512, f32 in -> bf16 out. One wave per row.
// ---------------------------------------------------------------------------
__global__ __launch_bounds__(256) void ln_kernel(
    const float* __restrict__ X, const float* __restrict__ g,
    const float* __restrict__ b, u16* __restrict__ Y)
{
    const int wave = threadIdx.x >> 6, lane = threadIdx.x & 63;
    const size_t row = (size_t)blockIdx.x * 4 + wave;
    const float* xr = X + row * 512;
    float4 v0 = *reinterpret_cast<const float4*>(xr + lane * 8);
    float4 v1 = *reinterpret_cast<const float4*>(xr + lane * 8 + 4);
    float s = v0.x + v0.y + v0.z + v0.w + v1.x + v1.y + v1.z + v1.w;
    float ss = v0.x * v0.x + v0.y * v0.y + v0.z * v0.z + v0.w * v0.w +
               v1.x * v1.x + v1.y * v1.y + v1.z * v1.z + v1.w * v1.w;
#pragma unroll
    for (int off = 32; off; off >>= 1) {
        s += __shfl_xor(s, off);
        ss += __shfl_xor(ss, off);
    }
    float mu = s * (1.0f / 512.0f);
    float var = ss * (1.0f / 512.0f) - mu * mu;
    float rs = rsqrtf(var + 1e-5f);
    float4 g0 = *reinterpret_cast<const float4*>(g + lane * 8);
    float4 g1 = *reinterpret_cast<const float4*>(g + lane * 8 + 4);
    float4 b0 = *reinterpret_cast<const float4*>(b + lane * 8);
    float4 b1 = *reinterpret_cast<const float4*>(b + lane * 8 + 4);
    float o0 = (v0.x - mu) * rs * g0.x + b0.x;
    float o1 = (v0.y - mu) * rs * g0.y + b0.y;
    float o2 = (v0.z - mu) * rs * g0.z + b0.z;
    float o3 = (v0.w - mu) * rs * g0.w + b0.w;
    float o4 = (v1.x - mu) * rs * g1.x + b1.x;
    float o5 = (v1.y - mu) * rs * g1.y + b1.y;
    float o6 = (v1.z - mu) * rs * g1.z + b1.z;
    float o7 = (v1.w - mu) * rs * g1.w + b1.w;
    uint4 pk;
    pk.x = (unsigned)f2b(o0) | ((unsigned)f2b(o1) << 16);
    pk.y = (unsigned)f2b(o2) | ((unsigned)f2b(o3) << 16);
    pk.z = (unsigned)f2b(o4) | ((unsigned)f2b(o5) << 16);
    pk.w = (unsigned)f2b(o6) | ((unsigned)f2b(o7) << 16);
    *reinterpret_cast<uint4*>(Y + row * 512 + lane * 8) = pk;
}

// ---------------------------------------------------------------------------
// Embedding gather -> bf16: Ag[t][j*300+e] = embed[program[t][j]][e]
// ---------------------------------------------------------------------------
__global__ __launch_bounds__(256) void gather_kernel(
    const int* __restrict__ program, const float* __restrict__ embed,
    u16* __restrict__ Ag, int total)
{
    int idx = blockIdx.x * 256 + threadIdx.x;
    if (idx >= total) return;
    int t = idx / 2400;
    int c = idx - t * 2400;
    int j = c / 300;
    int e = c - j * 300;
    int tok = program[t * 8 + j];
    Ag[idx] = f2b(embed[(size_t)tok * 300 + e]);
}

// f32 -> bf16 convert, 4 elems/thread
__global__ __launch_bounds__(256) void cvt_kernel(
    const float* __restrict__ in, u16* __restrict__ out, int n4)
{
    int i = blockIdx.x * 256 + threadIdx.x;
    if (i >= n4) return;
    float4 v = reinterpret_cast<const float4*>(in)[i];
    uint2 pk;
    pk.x = (unsigned)f2b(v.x) | ((unsigned)f2b(v.y) << 16);
    pk.y = (unsigned)f2b(v.z) | ((unsigned)f2b(v.w) << 16);
    reinterpret_cast<uint2*>(out)[i] = pk;
}

// ---------------------------------------------------------------------------

extern "C" void kernel_launch(void* const* d_in, const int* in_sizes, int n_in,
                              void* d_out, int out_size, void* d_ws, size_t ws_size,
                              hipStream_t stream)
{
    const int*   program = (const int*)d_in[0];
    const int*   adj     = (const int*)d_in[1];
    const float* img     = (const float*)d_in[2];
    const float* embed   = (const float*)d_in[3];
    const float* W_in    = (const float*)d_in[4];
    const float* b_in    = (const float*)d_in[5];
    const float* ln1_g   = (const float*)d_in[6];
    const float* ln1_b   = (const float*)d_in[7];
    const float* ln2_g   = (const float*)d_in[8];
    const float* ln2_b   = (const float*)d_in[9];
    const float* Wq      = (const float*)d_in[10];
    const float* bq      = (const float*)d_in[11];
    const float* Wk      = (const float*)d_in[12];
    const float* bk      = (const float*)d_in[13];
    const float* Wv      = (const float*)d_in[14];
    const float* bv      = (const float*)d_in[15];
    const float* Wo      = (const float*)d_in[16];
    const float* bo      = (const float*)d_in[17];
    const float* fW1     = (const float*)d_in[18];
    const float* fb1     = (const float*)d_in[19];
    const float* fW2     = (const float*)d_in[20];
    const float* fb2     = (const float*)d_in[21];
    const float* cWq     = (const float*)d_in[22];
    const float* cbq     = (const float*)d_in[23];
    const float* cWk     = (const float*)d_in[24];
    const float* cbk     = (const float*)d_in[25];
    const float* cWv     = (const float*)d_in[26];
    const float* cbv     = (const float*)d_in[27];
    const float* cWo     = (const float*)d_in[28];
    const float* cbo     = (const float*)d_in[29];

    char* wsb = (char*)d_ws;
    const size_t MB = 1024 * 1024;
    float* x    = (float*)(wsb + 0);             // 4096x512 f32      (8 MB)
    float* S    = (float*)(wsb + 8 * MB);        // 128x256x256 f32   (32 MB)
    u16*   h    = (u16*)(wsb + 40 * MB);         // 4096x512 bf16     (4 MB)
    u16*   xb   = (u16*)(wsb + 44 * MB);         // 4096x512 bf16     (4 MB)
    u16*   Q    = (u16*)(wsb + 48 * MB);         // 4096x2048 bf16    (16 MB)
    u16*   Kb   = (u16*)(wsb + 64 * MB);         // 4096x2048 bf16    (16 MB)
    u16*   Vt   = (u16*)(wsb + 80 * MB);         // [128][256][256]   (16 MB)
    u16*   P    = (u16*)(wsb + 96 * MB);         // 128x256x256 bf16  (16 MB)
    u16*   O    = (u16*)(wsb + 112 * MB);        // 4096x2048 bf16    (16 MB)
    u16*   imgb = (u16*)(wsb + 128 * MB);        // 4096x512 bf16     (4 MB)
    u16*   Wt   = (u16*)(wsb + 132 * MB);        // per-layer weights (17 MB)
    u16*   WinT = (u16*)(wsb + 149 * MB);        // 512x2400 bf16     (2.4 MB)
    u16*   Ag   = Q;   // gather buffer aliases Q+K (dead before QKV)
    u16*   g    = Q;   // FFN mid aliases Q (dead during FFN)
    const long Mi = 1048576;

    // prologue
    gather_kernel<<<38400, 256, 0, stream>>>(program, embed, Ag, 9830400);
    transpose_kernel<<<dim3(8, 38, 1), 256, 0, stream>>>(
        W_in, nullptr, nullptr, nullptr, nullptr, nullptr, 2400, 512, WinT, 0);
    cvt_kernel<<<2048, 256, 0, stream>>>(img, imgb, 524288);
    gemm_bf16<64, EPI_F32><<<dim3(4, 64, 1), 256, 0, stream>>>(
        Ag, 0, 2400, WinT, 0, 2400, 4096, 512, 2400,
        b_in, nullptr, nullptr, nullptr, nullptr,
        x, nullptr, nullptr, nullptr, 0, 512);

    for (int l = 0; l < 6; l++) {
        const float* Wq_l  = Wq  + (size_t)l * 512 * 2048;
        const float* Wk_l  = Wk  + (size_t)l * 512 * 2048;
        const float* Wv_l  = Wv  + (size_t)l * 512 * 2048;
        const float* Wo_l  = Wo  + (size_t)l * 2048 * 512;
        const float* fW1_l = fW1 + (size_t)l * 512 * 512;
        const float* fW2_l = fW2 + (size_t)l * 512 * 512;
        const float* cWq_l = cWq + (size_t)l * 512 * 2048;
        const float* cWk_l = cWk + (size_t)l * 512 * 2048;
        const float* cWv_l = cWv + (size_t)l * 512 * 2048;
        const float* cWo_l = cWo + (size_t)l * 2048 * 512;

        // per-layer weight transpose+convert into Wt
        transpose_kernel<<<dim3(32, 8, 6), 256, 0, stream>>>(
            Wq_l, Wk_l, Wv_l, cWq_l, cWk_l, cWv_l, 512, 2048, Wt, Mi);
        transpose_kernel<<<dim3(8, 32, 2), 256, 0, stream>>>(
            Wo_l, cWo_l, nullptr, nullptr, nullptr, nullptr, 2048, 512, Wt + 6 * Mi, Mi);
        transpose_kernel<<<dim3(8, 8, 2), 256, 0, stream>>>(
            fW1_l, fW2_l, nullptr, nullptr, nullptr, nullptr, 512, 512, Wt + 8 * Mi, 262144);

        // --- self-attention ---
        ln_kernel<<<1024, 256, 0, stream>>>(x, ln1_g + l * 512, ln1_b + l * 512, h);
        gemm_bf16<128, EPI_QKV><<<dim3(48, 32, 1), 256, 0, stream>>>(
            h, 0, 512, Wt, 0, 512, 4096, 6144, 512,
            bq + l * 2048, bk + l * 2048, bv + l * 2048, nullptr, nullptr,
            nullptr, Q, Kb, Vt, 0, 2048);
        gemm_bf16<128, EPI_SCORES><<<dim3(2, 2, 128), 256, 0, stream>>>(
            Q, 0, 2048, Kb, 0, 2048, 256, 256, 256,
            nullptr, nullptr, nullptr, nullptr, adj,
            S, nullptr, nullptr, nullptr, 65536, 256);
        softmax1_kernel<<<8192, 256, 0, stream>>>(S, P);
        gemm_bf16<128, EPI_PV><<<dim3(2, 2, 128), 256, 0, stream>>>(
            P, 65536, 256, Vt, 65536, 256, 256, 256, 256,
            nullptr, nullptr, nullptr, nullptr, nullptr,
            nullptr, O, nullptr, nullptr, 0, 2048);
        gemm_bf16<64, EPI_RESID><<<dim3(4, 64, 1), 256, 0, stream>>>(
            O, 0, 2048, Wt + 6 * Mi, 0, 2048, 4096, 512, 2048,
            bo + l * 512, nullptr, nullptr, x, nullptr,
            x, nullptr, nullptr, nullptr, 0, 512);

        // --- FFN ---
        ln_kernel<<<1024, 256, 0, stream>>>(x, ln2_g + l * 512, ln2_b + l * 512, h);
        gemm_bf16<64, EPI_GELU><<<dim3(4, 64, 1), 256, 0, stream>>>(
            h, 0, 512, Wt + 8 * Mi, 0, 512, 4096, 512, 512,
            fb1 + l * 512, nullptr, nullptr, nullptr, nullptr,
            nullptr, g, nullptr, nullptr, 0, 512);
        gemm_bf16<64, EPI_RESID_XB><<<dim3(4, 64, 1), 256, 0, stream>>>(
            g, 0, 512, Wt + 8 * Mi + 262144, 0, 512, 4096, 512, 512,
            fb2 + l * 512, nullptr, nullptr, x, nullptr,
            x, xb, nullptr, nullptr, 0, 512);

        // --- cross-attention (query = x, no mask) ---
        gemm_bf16<128, EPI_BF16><<<dim3(16, 32, 1), 256, 0, stream>>>(
            xb, 0, 512, Wt + 3 * Mi, 0, 512, 4096, 2048, 512,
            cbq + l * 2048, nullptr, nullptr, nullptr, nullptr,
            nullptr, Q, nullptr, nullptr, 0, 2048);
        gemm_bf16<128, EPI_KV><<<dim3(32, 32, 1), 256, 0, stream>>>(
            imgb, 0, 512, Wt + 4 * Mi, 0, 512, 4096, 4096, 512,
            cbk + l * 2048, cbv + l * 2048, nullptr, nullptr, nullptr,
            nullptr, Kb, nullptr, Vt, 0, 2048);
        gemm_bf16<128, EPI_SCORES><<<dim3(2, 2, 128), 256, 0, stream>>>(
            Q, 0, 2048, Kb, 0, 2048, 256, 256, 256,
            nullptr, nullptr, nullptr, nullptr, nullptr,
            S, nullptr, nullptr, nullptr, 65536, 256);
        softmax1_kernel<<<8192, 256, 0, stream>>>(S, P);
        gemm_bf16<128, EPI_PV><<<dim3(2, 2, 128), 256, 0, stream>>>(
            P, 65536, 256, Vt, 65536, 256, 256, 256, 256,
            nullptr, nullptr, nullptr, nullptr, nullptr,
            nullptr, O, nullptr, nullptr, 0, 2048);
        gemm_bf16<64, EPI_RESID><<<dim3(4, 64, 1), 256, 0, stream>>>(
            O, 0, 2048, Wt + 7 * Mi, 0, 2048, 4096, 512, 2048,
            cbo + l * 512, nullptr, nullptr, x, nullptr,
            x, nullptr, nullptr, nullptr, 0, 512);
    }

    hipMemcpyAsync(d_out, x, (size_t)2097152 * sizeof(float),
                   hipMemcpyDeviceToDevice, stream);
}

// Round 4
// 2123.273 us; speedup vs baseline: 5.9093x; 1.0349x over previous
//
#include <hip/hip_runtime.h>
#include <hip/hip_bf16.h>

typedef __attribute__((ext_vector_type(8))) short short8;
typedef __attribute__((ext_vector_type(4))) float f32x4;
typedef unsigned short u16;

__device__ __forceinline__ u16 f2b(float f) {
    unsigned int u = __builtin_bit_cast(unsigned int, f);
    u = u + 0x7fffu + ((u >> 16) & 1u);
    return (u16)(u >> 16);
}

// epilogue modes (template parameter)
#define EPI_F32      0   // outF = acc + bias0
#define EPI_BF16     1   // outB = bf16(acc + bias0)
#define EPI_RESID    2   // outF = acc + bias0 + Rsd
#define EPI_RESID_XB 3   // EPI_RESID + outB = bf16(same)
#define EPI_GELU     4   // outB = bf16(gelu(acc + bias0))
#define EPI_QKV      6   // 3-way split: Q(outB), K(outB2), V-transposed(outV)
#define EPI_KV       7   // 2-way split: K(outB), V-transposed(outV)
#define EPI_ATOMIC   9   // atomicAdd(outF, acc) (+bias0 when bz==0), split-K

// ---------------------------------------------------------------------------
// bf16 MFMA GEMM: C = A(M,K) @ Bt(N,K)^T, f32 accumulate, fused epilogue EPI.
// BM x 128 tile, BK=32, 256 threads (4 waves 2x2), 16x16x32 bf16 MFMA.
// Staging: global_load_lds width=16; LDS linear, XOR-swizzle applied to the
// per-lane GLOBAL source k-group (involution), ds_read applies same XOR.
// For EPI_ATOMIC, blockIdx.z is the K-slice (offset bz*aStride into K).
// ---------------------------------------------------------------------------
template<int BM, int EPI>
__global__ __launch_bounds__(256, 2) void gemm_bf16(
    const u16* __restrict__ A, long aStride, int lda,
    const u16* __restrict__ B, long bStride, int ldb,
    int M, int N, int K,
    const float* __restrict__ bias0, const float* __restrict__ bias1,
    const float* __restrict__ bias2,
    const float* __restrict__ Rsd,
    float* __restrict__ outF, u16* __restrict__ outB,
    u16* __restrict__ outB2, u16* __restrict__ outV,
    long cStride, int ldc)
{
    constexpr int BN = 128;
    constexpr int WM = BM / 2;   // wave tile rows
    constexpr int MF = WM / 16;  // A fragments per wave
    constexpr int NF = 4;        // B fragments per wave (64 cols)
    constexpr int AUNITS = BM * 4;          // 16B units in A tile
    constexpr int UPT = (BM + BN) / 64;     // 16B units per thread

    __shared__ __align__(16) u16 smem[(BM + BN) * 32];
    u16* As = smem;
    u16* Bs = smem + BM * 32;

    const int tid = threadIdx.x;
    const int wave = tid >> 6, lane = tid & 63;
    const int wm = wave >> 1, wn = wave & 1;
    const int tm = blockIdx.y * BM, tn = blockIdx.x * BN;
    const int bz = blockIdx.z;

    const size_t aOff = (size_t)bz * (size_t)aStride;
    const size_t bOff = (size_t)bz * (size_t)bStride;

    const int lr = lane & 15, kg = lane >> 4;
    const int slotx = (lr >> 1) & 3;

    f32x4 acc[MF][NF];
#pragma unroll
    for (int m = 0; m < MF; m++)
#pragma unroll
        for (int n = 0; n < NF; n++) acc[m][n] = (f32x4)(0.f);

    for (int k0 = 0; k0 < K; k0 += 32) {
#pragma unroll
        for (int i = 0; i < UPT; i++) {
            int u = tid + i * 256;
            u16* dst = smem + u * 8;  // linear LDS: base + lane*16B per wave
            if (u < AUNITS) {
                int row = u >> 2, g = u & 3;
                int gs = g ^ ((row >> 1) & 3);
                const u16* src = A + aOff + (size_t)(tm + row) * lda + k0 + gs * 8;
                __builtin_amdgcn_global_load_lds(src, dst, 16, 0, 0);
            } else {
                int v2 = u - AUNITS;
                int row = v2 >> 2, g = v2 & 3;
                int gs = g ^ ((row >> 1) & 3);
                const u16* src = B + bOff + (size_t)(tn + row) * ldb + k0 + gs * 8;
                __builtin_amdgcn_global_load_lds(src, dst, 16, 0, 0);
            }
        }
        __syncthreads();

        short8 af[MF], bfr[NF];
#pragma unroll
        for (int m = 0; m < MF; m++) {
            int row = wm * WM + m * 16 + lr;
            af[m] = *(const short8*)&As[row * 32 + ((kg ^ slotx) * 8)];
        }
#pragma unroll
        for (int n = 0; n < NF; n++) {
            int row = wn * 64 + n * 16 + lr;
            bfr[n] = *(const short8*)&Bs[row * 32 + ((kg ^ slotx) * 8)];
        }
#pragma unroll
        for (int m = 0; m < MF; m++)
#pragma unroll
            for (int n = 0; n < NF; n++)
                acc[m][n] = __builtin_amdgcn_mfma_f32_16x16x32_bf16(
                    af[m], bfr[n], acc[m][n], 0, 0, 0);
        __syncthreads();
    }

    // epilogue: D row=(lane>>4)*4+e, col=lane&15
#pragma unroll
    for (int m = 0; m < MF; m++) {
#pragma unroll
        for (int n = 0; n < NF; n++) {
#pragma unroll
            for (int e = 0; e < 4; e++) {
                int r = tm + wm * WM + m * 16 + (lane >> 4) * 4 + e;
                int c = tn + wn * 64 + n * 16 + (lane & 15);
                float v = acc[m][n][e];
                if constexpr (EPI == EPI_F32) {
                    outF[(size_t)r * ldc + c] = v + bias0[c];
                } else if constexpr (EPI == EPI_BF16) {
                    outB[(size_t)r * ldc + c] = f2b(v + bias0[c]);
                } else if constexpr (EPI == EPI_RESID) {
                    outF[(size_t)r * ldc + c] = v + bias0[c] + Rsd[(size_t)r * ldc + c];
                } else if constexpr (EPI == EPI_RESID_XB) {
                    float t = v + bias0[c] + Rsd[(size_t)r * ldc + c];
                    outF[(size_t)r * ldc + c] = t;
                    outB[(size_t)r * ldc + c] = f2b(t);
                } else if constexpr (EPI == EPI_GELU) {
                    float t = v + bias0[c];
                    t = 0.5f * t * (1.f + erff(t * 0.70710678118654752f));
                    outB[(size_t)r * ldc + c] = f2b(t);
                } else if constexpr (EPI == EPI_QKV) {
                    int sel = c >> 11, cc = c & 2047;
                    const float* bp = sel == 0 ? bias0 : (sel == 1 ? bias1 : bias2);
                    float t = v + bp[cc];
                    if (sel == 0)
                        outB[(size_t)r * 2048 + cc] = f2b(t);
                    else if (sel == 1)
                        outB2[(size_t)r * 2048 + cc] = f2b(t);
                    else
                        outV[(size_t)((r >> 8) * 8 + (cc >> 8)) * 65536 +
                             (size_t)(cc & 255) * 256 + (r & 255)] = f2b(t);
                } else if constexpr (EPI == EPI_KV) {
                    int sel = c >> 11, cc = c & 2047;
                    float t = v + (sel == 0 ? bias0 : bias1)[cc];
                    if (sel == 0)
                        outB[(size_t)r * 2048 + cc] = f2b(t);
                    else
                        outV[(size_t)((r >> 8) * 8 + (cc >> 8)) * 65536 +
                             (size_t)(cc & 255) * 256 + (r & 255)] = f2b(t);
                } else if constexpr (EPI == EPI_ATOMIC) {
                    float t = v;
                    if (bz == 0) t += bias0[c];
                    atomicAdd(&outF[(size_t)r * ldc + c], t);
                }
            }
        }
    }
}

// ---------------------------------------------------------------------------
// Fused attention: per (b,h) and 64-row q-tile, computes
// O = softmax1(Q K^T / 16 + mask) V  over 256 keys, D=256.
// Q,K: [4096][2048] bf16 (head cols h*256..). Vt: [bh][256 d][256 tok] bf16.
// 4 waves: phase1 wave w owns k-slice w*64; phase2 wave w owns d-slice w*64.
// S held in registers (16 x f32x4 / thread). Softmax+1 wave-parallel with
// LDS cross-wave reduce. P staged to LDS (aliases Q tile) for PV A-operand.
// ---------------------------------------------------------------------------
template<bool MASKED>
__global__ __launch_bounds__(256, 2) void attn_kernel(
    const u16* __restrict__ Q, const u16* __restrict__ K,
    const u16* __restrict__ Vt, const int* __restrict__ adj,
    u16* __restrict__ O)
{
    __shared__ __align__(16) u16 Ps[64 * 256];   // Q tile, then P tile (32 KB)
    __shared__ __align__(16) u16 Ks[256 * 32];   // K tile / V tile (16 KB)
    __shared__ float red1[64 * 4];
    __shared__ float red2[64 * 4];

    const int tid = threadIdx.x;
    const int w = tid >> 6, lane = tid & 63;
    const int lr = lane & 15, kg = lane >> 4;
    const int qt = blockIdx.x, bh = blockIdx.y;
    const int b = bh >> 3, h = bh & 7;
    const size_t qkBase = (size_t)b * 256 * 2048 + h * 256;

    // stage Q tile 64x256 (16B-group swizzle: LDS slot s holds group s^(row&7))
#pragma unroll
    for (int i = 0; i < 8; i++) {
        int u = tid + i * 256;
        int row = u >> 5, g = u & 31;
        int gs = g ^ (row & 7);
        const u16* src = Q + qkBase + (size_t)(qt * 64 + row) * 2048 + gs * 8;
        __builtin_amdgcn_global_load_lds(src, Ps + u * 8, 16, 0, 0);
    }

    f32x4 sacc[4][4];
#pragma unroll
    for (int m = 0; m < 4; m++)
#pragma unroll
        for (int n = 0; n < 4; n++) sacc[m][n] = (f32x4)(0.f);

    // ---- phase 1: S = Q K^T (contraction over d, 8 steps of 32) ----
    for (int dk = 0; dk < 8; dk++) {
#pragma unroll
        for (int i = 0; i < 4; i++) {
            int u = tid + i * 256;
            int row = u >> 2, g = u & 3;
            int gs = g ^ ((row >> 1) & 3);
            const u16* src = K + qkBase + (size_t)row * 2048 + dk * 32 + gs * 8;
            __builtin_amdgcn_global_load_lds(src, Ks + u * 8, 16, 0, 0);
        }
        __syncthreads();
        short8 af[4], bfr[4];
#pragma unroll
        for (int m = 0; m < 4; m++) {
            int row = m * 16 + lr;
            af[m] = *(const short8*)&Ps[row * 256 + (((dk * 4 + kg) ^ (row & 7)) * 8)];
        }
#pragma unroll
        for (int n = 0; n < 4; n++) {
            int row = w * 64 + n * 16 + lr;
            bfr[n] = *(const short8*)&Ks[row * 32 + ((kg ^ ((row >> 1) & 3)) * 8)];
        }
#pragma unroll
        for (int m = 0; m < 4; m++)
#pragma unroll
            for (int n = 0; n < 4; n++)
                sacc[m][n] = __builtin_amdgcn_mfma_f32_16x16x32_bf16(
                    af[m], bfr[n], sacc[m][n], 0, 0, 0);
        __syncthreads();
    }

    // ---- phase 2: scale + mask + softmax(+1 denom) ----
#pragma unroll
    for (int m = 0; m < 4; m++)
#pragma unroll
        for (int n = 0; n < 4; n++)
#pragma unroll
            for (int e = 0; e < 4; e++) {
                float t = sacc[m][n][e] * 0.0625f;
                if (MASKED) {
                    int q = qt * 64 + m * 16 + kg * 4 + e;
                    int k = w * 64 + n * 16 + lr;
                    int a_ = adj[((size_t)b * 256 + q) * 256 + k];
                    t += (1.f - (float)a_) * -1.0e6f;
                }
                sacc[m][n][e] = t;
            }

    float mx[4][4];
#pragma unroll
    for (int m = 0; m < 4; m++)
#pragma unroll
        for (int e = 0; e < 4; e++) {
            float v = sacc[m][0][e];
#pragma unroll
            for (int n = 1; n < 4; n++) v = fmaxf(v, sacc[m][n][e]);
#pragma unroll
            for (int off = 1; off < 16; off <<= 1) v = fmaxf(v, __shfl_xor(v, off));
            mx[m][e] = v;
        }
    if (lr == 0) {
#pragma unroll
        for (int m = 0; m < 4; m++)
#pragma unroll
            for (int e = 0; e < 4; e++)
                red1[(m * 16 + kg * 4 + e) * 4 + w] = mx[m][e];
    }
    __syncthreads();

    float inv[4][4];
    float sum[4][4];
#pragma unroll
    for (int m = 0; m < 4; m++)
#pragma unroll
        for (int e = 0; e < 4; e++) {
            int r = m * 16 + kg * 4 + e;
            float gm = fmaxf(fmaxf(red1[r * 4 + 0], red1[r * 4 + 1]),
                             fmaxf(red1[r * 4 + 2], red1[r * 4 + 3]));
            inv[m][e] = gm;  // stash gm
            float s = 0.f;
#pragma unroll
            for (int n = 0; n < 4; n++) {
                float ev = __expf(sacc[m][n][e] - gm);
                sacc[m][n][e] = ev;
                s += ev;
            }
            sum[m][e] = s;
        }
#pragma unroll
    for (int m = 0; m < 4; m++)
#pragma unroll
        for (int e = 0; e < 4; e++) {
            float s = sum[m][e];
#pragma unroll
            for (int off = 1; off < 16; off <<= 1) s += __shfl_xor(s, off);
            sum[m][e] = s;
        }
    if (lr == 0) {
#pragma unroll
        for (int m = 0; m < 4; m++)
#pragma unroll
            for (int e = 0; e < 4; e++)
                red2[(m * 16 + kg * 4 + e) * 4 + w] = sum[m][e];
    }
    __syncthreads();
#pragma unroll
    for (int m = 0; m < 4; m++)
#pragma unroll
        for (int e = 0; e < 4; e++) {
            int r = m * 16 + kg * 4 + e;
            float gs = red2[r * 4 + 0] + red2[r * 4 + 1] +
                       red2[r * 4 + 2] + red2[r * 4 + 3];
            inv[m][e] = 1.f / (1.f + gs);
        }

    // ---- phase 3: P -> LDS (bf16, aliases Q tile; all Q reads are done) ----
#pragma unroll
    for (int m = 0; m < 4; m++)
#pragma unroll
        for (int n = 0; n < 4; n++)
#pragma unroll
            for (int e = 0; e < 4; e++) {
                int q = m * 16 + kg * 4 + e;
                int k = w * 64 + n * 16 + lr;
                float pv = sacc[m][n][e] * inv[m][e];
                Ps[q * 256 + (((k >> 3) ^ (q & 7)) * 8) + (k & 7)] = f2b(pv);
            }

    // ---- phase 4: O = P V (contraction over k, 8 steps of 32) ----
    f32x4 oacc[4][4];
#pragma unroll
    for (int m = 0; m < 4; m++)
#pragma unroll
        for (int n = 0; n < 4; n++) oacc[m][n] = (f32x4)(0.f);

    for (int kt = 0; kt < 8; kt++) {
#pragma unroll
        for (int i = 0; i < 4; i++) {
            int u = tid + i * 256;
            int row = u >> 2, g = u & 3;   // row = d
            int gs = g ^ ((row >> 1) & 3);
            const u16* src = Vt + (size_t)bh * 65536 + (size_t)row * 256 + kt * 32 + gs * 8;
            __builtin_amdgcn_global_load_lds(src, Ks + u * 8, 16, 0, 0);
        }
        __syncthreads();   // also guards Ps writes on kt==0
        short8 af[4], bfr[4];
#pragma unroll
        for (int m = 0; m < 4; m++) {
            int q = m * 16 + lr;
            af[m] = *(const short8*)&Ps[q * 256 + (((kt * 4 + kg) ^ (q & 7)) * 8)];
        }
#pragma unroll
        for (int n = 0; n < 4; n++) {
            int row = w * 64 + n * 16 + lr;
            bfr[n] = *(const short8*)&Ks[row * 32 + ((kg ^ ((row >> 1) & 3)) * 8)];
        }
#pragma unroll
        for (int m = 0; m < 4; m++)
#pragma unroll
            for (int n = 0; n < 4; n++)
                oacc[m][n] = __builtin_amdgcn_mfma_f32_16x16x32_bf16(
                    af[m], bfr[n], oacc[m][n], 0, 0, 0);
        __syncthreads();
    }

    // ---- epilogue: O[tok][h*256+d] ----
#pragma unroll
    for (int m = 0; m < 4; m++)
#pragma unroll
        for (int n = 0; n < 4; n++)
#pragma unroll
            for (int e = 0; e < 4; e++) {
                int q = qt * 64 + m * 16 + kg * 4 + e;
                int d = w * 64 + n * 16 + lr;
                O[(size_t)(b * 256 + q) * 2048 + h * 256 + d] = f2b(oacc[m][n][e]);
            }
}

// ---------------------------------------------------------------------------
// Transpose+convert: W f32 [R][C] -> out bf16 [C][R]. blockIdx.z selects src.
// ---------------------------------------------------------------------------
__global__ __launch_bounds__(256) void transpose_kernel(
    const float* p0, const float* p1, const float* p2,
    const float* p3, const float* p4, const float* p5,
    int R, int C, u16* __restrict__ out, long outStride)
{
    const float* W;
    switch (blockIdx.z) {
    default: W = p0; break;
    case 1: W = p1; break;
    case 2: W = p2; break;
    case 3: W = p3; break;
    case 4: W = p4; break;
    case 5: W = p5; break;
    }
    u16* o = out + (size_t)blockIdx.z * outStride;
    __shared__ float t[64][65];
    const int tid = threadIdx.x;
    const int rBase = blockIdx.y * 64, cBase = blockIdx.x * 64;
#pragma unroll
    for (int i = 0; i < 16; i++) {
        int idx = tid + i * 256;
        int rr = idx >> 6, cc = idx & 63;
        float v = 0.f;
        if (rBase + rr < R) v = W[(size_t)(rBase + rr) * C + cBase + cc];
        t[rr][cc] = v;
    }
    __syncthreads();
#pragma unroll
    for (int i = 0; i < 16; i++) {
        int idx = tid + i * 256;
        int cc = idx >> 6, rr = idx & 63;
        if (rBase + rr < R)
            o[(size_t)(cBase + cc) * R + rBase + rr] = f2b(t[rr][cc]);
    }
}

// ---------------------------------------------------------------------------
// LayerNorm rows of 512, f32 in -> bf16 out. One wave per row.
// ---------------------------------------------------------------------------
__global__ __launch_bounds__(256) void ln_kernel(
    const float* __restrict__ X, const float* __restrict__ g,
    const float* __restrict__ b, u16* __restrict__ Y)
{
    const int wave = threadIdx.x >> 6, lane = threadIdx.x & 63;
    const size_t row = (size_t)blockIdx.x * 4 + wave;
    const float* xr = X + row * 512;
    float4 v0 = *reinterpret_cast<const float4*>(xr + lane * 8);
    float4 v1 = *reinterpret_cast<const float4*>(xr + lane * 8 + 4);
    float s = v0.x + v0.y + v0.z + v0.w + v1.x + v1.y + v1.z + v1.w;
    float ss = v0.x * v0.x + v0.y * v0.y + v0.z * v0.z + v0.w * v0.w +
               v1.x * v1.x + v1.y * v1.y + v1.z * v1.z + v1.w * v1.w;
#pragma unroll
    for (int off = 32; off; off >>= 1) {
        s += __shfl_xor(s, off);
        ss += __shfl_xor(ss, off);
    }
    float mu = s * (1.0f / 512.0f);
    float var = ss * (1.0f / 512.0f) - mu * mu;
    float rs = rsqrtf(var + 1e-5f);
    float4 g0 = *reinterpret_cast<const float4*>(g + lane * 8);
    float4 g1 = *reinterpret_cast<const float4*>(g + lane * 8 + 4);
    float4 b0 = *reinterpret_cast<const float4*>(b + lane * 8);
    float4 b1 = *reinterpret_cast<const float4*>(b + lane * 8 + 4);
    float o0 = (v0.x - mu) * rs * g0.x + b0.x;
    float o1 = (v0.y - mu) * rs * g0.y + b0.y;
    float o2 = (v0.z - mu) * rs * g0.z + b0.z;
    float o3 = (v0.w - mu) * rs * g0.w + b0.w;
    float o4 = (v1.x - mu) * rs * g1.x + b1.x;
    float o5 = (v1.y - mu) * rs * g1.y + b1.y;
    float o6 = (v1.z - mu) * rs * g1.z + b1.z;
    float o7 = (v1.w - mu) * rs * g1.w + b1.w;
    uint4 pk;
    pk.x = (unsigned)f2b(o0) | ((unsigned)f2b(o1) << 16);
    pk.y = (unsigned)f2b(o2) | ((unsigned)f2b(o3) << 16);
    pk.z = (unsigned)f2b(o4) | ((unsigned)f2b(o5) << 16);
    pk.w = (unsigned)f2b(o6) | ((unsigned)f2b(o7) << 16);
    *reinterpret_cast<uint4*>(Y + row * 512 + lane * 8) = pk;
}

// ---------------------------------------------------------------------------
// Embedding gather -> bf16: Ag[t][j*300+e] = embed[program[t][j]][e]
// ---------------------------------------------------------------------------
__global__ __launch_bounds__(256) void gather_kernel(
    const int* __restrict__ program, const float* __restrict__ embed,
    u16* __restrict__ Ag, int total)
{
    int idx = blockIdx.x * 256 + threadIdx.x;
    if (idx >= total) return;
    int t = idx / 2400;
    int c = idx - t * 2400;
    int j = c / 300;
    int e = c - j * 300;
    int tok = program[t * 8 + j];
    Ag[idx] = f2b(embed[(size_t)tok * 300 + e]);
}

// f32 -> bf16 convert, 4 elems/thread
__global__ __launch_bounds__(256) void cvt_kernel(
    const float* __restrict__ in, u16* __restrict__ out, int n4)
{
    int i = blockIdx.x * 256 + threadIdx.x;
    if (i >= n4) return;
    float4 v = reinterpret_cast<const float4*>(in)[i];
    uint2 pk;
    pk.x = (unsigned)f2b(v.x) | ((unsigned)f2b(v.y) << 16);
    pk.y = (unsigned)f2b(v.z) | ((unsigned)f2b(v.w) << 16);
    reinterpret_cast<uint2*>(out)[i] = pk;
}

// ---------------------------------------------------------------------------

extern "C" void kernel_launch(void* const* d_in, const int* in_sizes, int n_in,
                              void* d_out, int out_size, void* d_ws, size_t ws_size,
                              hipStream_t stream)
{
    const int*   program = (const int*)d_in[0];
    const int*   adj     = (const int*)d_in[1];
    const float* img     = (const float*)d_in[2];
    const float* embed   = (const float*)d_in[3];
    const float* W_in    = (const float*)d_in[4];
    const float* b_in    = (const float*)d_in[5];
    const float* ln1_g   = (const float*)d_in[6];
    const float* ln1_b   = (const float*)d_in[7];
    const float* ln2_g   = (const float*)d_in[8];
    const float* ln2_b   = (const float*)d_in[9];
    const float* Wq      = (const float*)d_in[10];
    const float* bq      = (const float*)d_in[11];
    const float* Wk      = (const float*)d_in[12];
    const float* bk      = (const float*)d_in[13];
    const float* Wv      = (const float*)d_in[14];
    const float* bv      = (const float*)d_in[15];
    const float* Wo      = (const float*)d_in[16];
    const float* bo      = (const float*)d_in[17];
    const float* fW1     = (const float*)d_in[18];
    const float* fb1     = (const float*)d_in[19];
    const float* fW2     = (const float*)d_in[20];
    const float* fb2     = (const float*)d_in[21];
    const float* cWq     = (const float*)d_in[22];
    const float* cbq     = (const float*)d_in[23];
    const float* cWk     = (const float*)d_in[24];
    const float* cbk     = (const float*)d_in[25];
    const float* cWv     = (const float*)d_in[26];
    const float* cbv     = (const float*)d_in[27];
    const float* cWo     = (const float*)d_in[28];
    const float* cbo     = (const float*)d_in[29];

    char* wsb = (char*)d_ws;
    const size_t MB = 1024 * 1024;
    float* x    = (float*)(wsb + 0);             // 4096x512 f32      (8 MB)
    u16*   h    = (u16*)(wsb + 40 * MB);         // 4096x512 bf16     (4 MB)
    u16*   xb   = (u16*)(wsb + 44 * MB);         // 4096x512 bf16     (4 MB)
    u16*   Q    = (u16*)(wsb + 48 * MB);         // 4096x2048 bf16    (16 MB)
    u16*   Kb   = (u16*)(wsb + 64 * MB);         // 4096x2048 bf16    (16 MB)
    u16*   Vt   = (u16*)(wsb + 80 * MB);         // [128][256][256]   (16 MB)
    u16*   O    = (u16*)(wsb + 112 * MB);        // 4096x2048 bf16    (16 MB)
    u16*   imgb = (u16*)(wsb + 128 * MB);        // 4096x512 bf16     (4 MB)
    u16*   Wt   = (u16*)(wsb + 132 * MB);        // per-layer weights (17 MB)
    u16*   WinT = (u16*)(wsb + 149 * MB);        // 512x2400 bf16     (2.4 MB)
    u16*   Ag   = Q;   // gather buffer aliases Q+K (dead before QKV)
    u16*   g    = Q;   // FFN mid aliases Q (dead during FFN)
    const long Mi = 1048576;

    // prologue
    gather_kernel<<<38400, 256, 0, stream>>>(program, embed, Ag, 9830400);
    transpose_kernel<<<dim3(8, 38, 1), 256, 0, stream>>>(
        W_in, nullptr, nullptr, nullptr, nullptr, nullptr, 2400, 512, WinT, 0);
    cvt_kernel<<<2048, 256, 0, stream>>>(img, imgb, 524288);
    gemm_bf16<64, EPI_F32><<<dim3(4, 64, 1), 256, 0, stream>>>(
        Ag, 0, 2400, WinT, 0, 2400, 4096, 512, 2400,
        b_in, nullptr, nullptr, nullptr,
        x, nullptr, nullptr, nullptr, 0, 512);

    for (int l = 0; l < 6; l++) {
        const float* Wq_l  = Wq  + (size_t)l * 512 * 2048;
        const float* Wk_l  = Wk  + (size_t)l * 512 * 2048;
        const float* Wv_l  = Wv  + (size_t)l * 512 * 2048;
        const float* Wo_l  = Wo  + (size_t)l * 2048 * 512;
        const float* fW1_l = fW1 + (size_t)l * 512 * 512;
        const float* fW2_l = fW2 + (size_t)l * 512 * 512;
        const float* cWq_l = cWq + (size_t)l * 512 * 2048;
        const float* cWk_l = cWk + (size_t)l * 512 * 2048;
        const float* cWv_l = cWv + (size_t)l * 512 * 2048;
        const float* cWo_l = cWo + (size_t)l * 2048 * 512;

        // per-layer weight transpose+convert into Wt
        transpose_kernel<<<dim3(32, 8, 6), 256, 0, stream>>>(
            Wq_l, Wk_l, Wv_l, cWq_l, cWk_l, cWv_l, 512, 2048, Wt, Mi);
        transpose_kernel<<<dim3(8, 32, 2), 256, 0, stream>>>(
            Wo_l, cWo_l, nullptr, nullptr, nullptr, nullptr, 2048, 512, Wt + 6 * Mi, Mi);
        transpose_kernel<<<dim3(8, 8, 2), 256, 0, stream>>>(
            fW1_l, fW2_l, nullptr, nullptr, nullptr, nullptr, 512, 512, Wt + 8 * Mi, 262144);

        // --- self-attention ---
        ln_kernel<<<1024, 256, 0, stream>>>(x, ln1_g + l * 512, ln1_b + l * 512, h);
        gemm_bf16<128, EPI_QKV><<<dim3(48, 32, 1), 256, 0, stream>>>(
            h, 0, 512, Wt, 0, 512, 4096, 6144, 512,
            bq + l * 2048, bk + l * 2048, bv + l * 2048, nullptr,
            nullptr, Q, Kb, Vt, 0, 2048);
        attn_kernel<true><<<dim3(4, 128), 256, 0, stream>>>(Q, Kb, Vt, adj, O);
        gemm_bf16<64, EPI_ATOMIC><<<dim3(4, 64, 4), 256, 0, stream>>>(
            O, 512, 2048, Wt + 6 * Mi, 512, 2048, 4096, 512, 512,
            bo + l * 512, nullptr, nullptr, nullptr,
            x, nullptr, nullptr, nullptr, 0, 512);

        // --- FFN ---
        ln_kernel<<<1024, 256, 0, stream>>>(x, ln2_g + l * 512, ln2_b + l * 512, h);
        gemm_bf16<64, EPI_GELU><<<dim3(4, 64, 1), 256, 0, stream>>>(
            h, 0, 512, Wt + 8 * Mi, 0, 512, 4096, 512, 512,
            fb1 + l * 512, nullptr, nullptr, nullptr,
            nullptr, g, nullptr, nullptr, 0, 512);
        gemm_bf16<64, EPI_RESID_XB><<<dim3(4, 64, 1), 256, 0, stream>>>(
            g, 0, 512, Wt + 8 * Mi + 262144, 0, 512, 4096, 512, 512,
            fb2 + l * 512, nullptr, nullptr, x,
            x, xb, nullptr, nullptr, 0, 512);

        // --- cross-attention (query = x, no mask) ---
        gemm_bf16<128, EPI_BF16><<<dim3(16, 32, 1), 256, 0, stream>>>(
            xb, 0, 512, Wt + 3 * Mi, 0, 512, 4096, 2048, 512,
            cbq + l * 2048, nullptr, nullptr, nullptr,
            nullptr, Q, nullptr, nullptr, 0, 2048);
        gemm_bf16<128, EPI_KV><<<dim3(32, 32, 1), 256, 0, stream>>>(
            imgb, 0, 512, Wt + 4 * Mi, 0, 512, 4096, 4096, 512,
            cbk + l * 2048, cbv + l * 2048, nullptr, nullptr,
            nullptr, Kb, nullptr, Vt, 0, 2048);
        attn_kernel<false><<<dim3(4, 128), 256, 0, stream>>>(Q, Kb, Vt, nullptr, O);
        gemm_bf16<64, EPI_ATOMIC><<<dim3(4, 64, 4), 256, 0, stream>>>(
            O, 512, 2048, Wt + 7 * Mi, 512, 2048, 4096, 512, 512,
            cbo + l * 512, nullptr, nullptr, nullptr,
            x, nullptr, nullptr, nullptr, 0, 512);
    }

    hipMemcpyAsync(d_out, x, (size_t)2097152 * sizeof(float),
                   hipMemcpyDeviceToDevice, stream);
}

// Round 5
// 2028.367 us; speedup vs baseline: 6.1858x; 1.0468x over previous
//
#include <hip/hip_runtime.h>
#include <hip/hip_bf16.h>

typedef __attribute__((ext_vector_type(8))) short short8;
typedef __attribute__((ext_vector_type(4))) float f32x4;
typedef unsigned short u16;

__device__ __forceinline__ u16 f2b(float f) {
    unsigned int u = __builtin_bit_cast(unsigned int, f);
    u = u + 0x7fffu + ((u >> 16) & 1u);
    return (u16)(u >> 16);
}

// epilogue modes (template parameter)
#define EPI_F32      0   // outF = acc + bias0
#define EPI_BF16     1   // outB = bf16(acc + bias0)
#define EPI_RESID    2   // outF = acc + bias0 + Rsd
#define EPI_RESID_XB 3   // EPI_RESID + outB = bf16(same)
#define EPI_GELU     4   // outB = bf16(gelu(acc + bias0))
#define EPI_QKV      6   // 3-way split: Q(outB), K(outB2), V-transposed(outV)
#define EPI_KV       7   // 2-way split: K(outB), V-transposed(outV)
#define EPI_ATOMIC   9   // atomicAdd(outF, acc) (+bias0 when bz==0), split-K

// ---------------------------------------------------------------------------
// bf16 MFMA GEMM: C = A(M,K) @ Bt(N,K)^T, f32 accumulate, fused epilogue EPI.
// BM x 128 tile, BK=32, 256 threads (4 waves 2x2), 16x16x32 bf16 MFMA.
// 2-phase double-buffered K-loop: prefetch tile t+1 via global_load_lds while
// computing tile t; one __syncthreads (vmcnt drain) per K-step.
// LDS linear; XOR-swizzle applied to per-lane GLOBAL source k-group
// (involution), ds_read applies the same XOR.
// ---------------------------------------------------------------------------
template<int BM, int EPI>
__global__ __launch_bounds__(256, 2) void gemm_bf16(
    const u16* __restrict__ A, long aStride, int lda,
    const u16* __restrict__ B, long bStride, int ldb,
    int M, int N, int K,
    const float* __restrict__ bias0, const float* __restrict__ bias1,
    const float* __restrict__ bias2,
    const float* __restrict__ Rsd,
    float* __restrict__ outF, u16* __restrict__ outB,
    u16* __restrict__ outB2, u16* __restrict__ outV,
    long cStride, int ldc)
{
    constexpr int BN = 128;
    constexpr int WM = BM / 2;   // wave tile rows
    constexpr int MF = WM / 16;  // A fragments per wave
    constexpr int NF = 4;        // B fragments per wave (64 cols)
    constexpr int AUNITS = BM * 4;          // 16B units in A tile
    constexpr int UPT = (BM + BN) / 64;     // 16B units per thread
    constexpr int BUFE = (BM + BN) * 32;    // u16 elements per LDS buffer

    __shared__ __align__(16) u16 smem[2 * BUFE];

    const int tid = threadIdx.x;
    const int wave = tid >> 6, lane = tid & 63;
    const int wm = wave >> 1, wn = wave & 1;
    const int tm = blockIdx.y * BM, tn = blockIdx.x * BN;
    const int bz = blockIdx.z;

    const size_t aOff = (size_t)bz * (size_t)aStride;
    const size_t bOff = (size_t)bz * (size_t)bStride;

    const int lr = lane & 15, kg = lane >> 4;
    const int slotx = (lr >> 1) & 3;

    auto stage = [&](int buf, int k0) {
#pragma unroll
        for (int i = 0; i < UPT; i++) {
            int u = tid + i * 256;
            u16* dst = smem + buf * BUFE + u * 8;
            if (u < AUNITS) {
                int row = u >> 2, g = u & 3;
                int gs = g ^ ((row >> 1) & 3);
                const u16* src = A + aOff + (size_t)(tm + row) * lda + k0 + gs * 8;
                __builtin_amdgcn_global_load_lds(src, dst, 16, 0, 0);
            } else {
                int v2 = u - AUNITS;
                int row = v2 >> 2, g = v2 & 3;
                int gs = g ^ ((row >> 1) & 3);
                const u16* src = B + bOff + (size_t)(tn + row) * ldb + k0 + gs * 8;
                __builtin_amdgcn_global_load_lds(src, dst, 16, 0, 0);
            }
        }
    };

    f32x4 acc[MF][NF];
#pragma unroll
    for (int m = 0; m < MF; m++)
#pragma unroll
        for (int n = 0; n < NF; n++) acc[m][n] = (f32x4)(0.f);

    const int NT = K >> 5;
    stage(0, 0);
    __syncthreads();

    for (int t = 0; t < NT; t++) {
        const int cur = t & 1;
        if (t + 1 < NT) stage(cur ^ 1, (t + 1) * 32);

        const u16* As = smem + cur * BUFE;
        const u16* Bs = As + BM * 32;
        short8 af[MF], bfr[NF];
#pragma unroll
        for (int m = 0; m < MF; m++) {
            int row = wm * WM + m * 16 + lr;
            af[m] = *(const short8*)&As[row * 32 + ((kg ^ slotx) * 8)];
        }
#pragma unroll
        for (int n = 0; n < NF; n++) {
            int row = wn * 64 + n * 16 + lr;
            bfr[n] = *(const short8*)&Bs[row * 32 + ((kg ^ slotx) * 8)];
        }
#pragma unroll
        for (int m = 0; m < MF; m++)
#pragma unroll
            for (int n = 0; n < NF; n++)
                acc[m][n] = __builtin_amdgcn_mfma_f32_16x16x32_bf16(
                    af[m], bfr[n], acc[m][n], 0, 0, 0);
        __syncthreads();   // drains prefetch (vmcnt 0) + joins waves
    }

    // epilogue: D row=(lane>>4)*4+e, col=lane&15
#pragma unroll
    for (int m = 0; m < MF; m++) {
#pragma unroll
        for (int n = 0; n < NF; n++) {
#pragma unroll
            for (int e = 0; e < 4; e++) {
                int r = tm + wm * WM + m * 16 + (lane >> 4) * 4 + e;
                int c = tn + wn * 64 + n * 16 + (lane & 15);
                float v = acc[m][n][e];
                if constexpr (EPI == EPI_F32) {
                    outF[(size_t)r * ldc + c] = v + bias0[c];
                } else if constexpr (EPI == EPI_BF16) {
                    outB[(size_t)r * ldc + c] = f2b(v + bias0[c]);
                } else if constexpr (EPI == EPI_RESID) {
                    outF[(size_t)r * ldc + c] = v + bias0[c] + Rsd[(size_t)r * ldc + c];
                } else if constexpr (EPI == EPI_RESID_XB) {
                    float t = v + bias0[c] + Rsd[(size_t)r * ldc + c];
                    outF[(size_t)r * ldc + c] = t;
                    outB[(size_t)r * ldc + c] = f2b(t);
                } else if constexpr (EPI == EPI_GELU) {
                    float t = v + bias0[c];
                    t = 0.5f * t * (1.f + erff(t * 0.70710678118654752f));
                    outB[(size_t)r * ldc + c] = f2b(t);
                } else if constexpr (EPI == EPI_QKV) {
                    int sel = c >> 11, cc = c & 2047;
                    const float* bp = sel == 0 ? bias0 : (sel == 1 ? bias1 : bias2);
                    float t = v + bp[cc];
                    if (sel == 0)
                        outB[(size_t)r * 2048 + cc] = f2b(t);
                    else if (sel == 1)
                        outB2[(size_t)r * 2048 + cc] = f2b(t);
                    else
                        outV[(size_t)((r >> 8) * 8 + (cc >> 8)) * 65536 +
                             (size_t)(cc & 255) * 256 + (r & 255)] = f2b(t);
                } else if constexpr (EPI == EPI_KV) {
                    int sel = c >> 11, cc = c & 2047;
                    float t = v + (sel == 0 ? bias0 : bias1)[cc];
                    if (sel == 0)
                        outB[(size_t)r * 2048 + cc] = f2b(t);
                    else
                        outV[(size_t)((r >> 8) * 8 + (cc >> 8)) * 65536 +
                             (size_t)(cc & 255) * 256 + (r & 255)] = f2b(t);
                } else if constexpr (EPI == EPI_ATOMIC) {
                    float t = v;
                    if (bz == 0) t += bias0[c];
                    atomicAdd(&outF[(size_t)r * ldc + c], t);
                }
            }
        }
    }
}

// ---------------------------------------------------------------------------
// Fused attention: per (b,h) and 64-row q-tile:
// O = softmax1(Q K^T / 16 + mask) V over 256 keys, D=256.
// 2-phase double-buffered K and V streaming; V tile 0 prefetched during
// softmax. S in registers; P staged to LDS (aliases Q tile).
// ---------------------------------------------------------------------------
template<bool MASKED>
__global__ __launch_bounds__(256, 2) void attn_kernel(
    const u16* __restrict__ Q, const u16* __restrict__ K,
    const u16* __restrict__ Vt, const int* __restrict__ adj,
    u16* __restrict__ O)
{
    __shared__ __align__(16) u16 Ps[64 * 256];       // Q tile then P tile (32 KB)
    __shared__ __align__(16) u16 Ks[2 * 256 * 32];   // K/V double buffer (32 KB)
    __shared__ float red1[64 * 4];
    __shared__ float red2[64 * 4];

    const int tid = threadIdx.x;
    const int w = tid >> 6, lane = tid & 63;
    const int lr = lane & 15, kg = lane >> 4;
    const int qt = blockIdx.x, bh = blockIdx.y;
    const int b = bh >> 3, h = bh & 7;
    const size_t qkBase = (size_t)b * 256 * 2048 + h * 256;

    auto stageK = [&](int buf, int dk) {
#pragma unroll
        for (int i = 0; i < 4; i++) {
            int u = tid + i * 256;
            int row = u >> 2, g = u & 3;
            int gs = g ^ ((row >> 1) & 3);
            const u16* src = K + qkBase + (size_t)row * 2048 + dk * 32 + gs * 8;
            __builtin_amdgcn_global_load_lds(src, Ks + buf * 8192 + u * 8, 16, 0, 0);
        }
    };
    auto stageV = [&](int buf, int kt) {
#pragma unroll
        for (int i = 0; i < 4; i++) {
            int u = tid + i * 256;
            int row = u >> 2, g = u & 3;   // row = d
            int gs = g ^ ((row >> 1) & 3);
            const u16* src = Vt + (size_t)bh * 65536 + (size_t)row * 256 + kt * 32 + gs * 8;
            __builtin_amdgcn_global_load_lds(src, Ks + buf * 8192 + u * 8, 16, 0, 0);
        }
    };

    // stage Q tile 64x256 (16B-group swizzle: LDS slot s holds group s^(row&7))
#pragma unroll
    for (int i = 0; i < 8; i++) {
        int u = tid + i * 256;
        int row = u >> 5, g = u & 31;
        int gs = g ^ (row & 7);
        const u16* src = Q + qkBase + (size_t)(qt * 64 + row) * 2048 + gs * 8;
        __builtin_amdgcn_global_load_lds(src, Ps + u * 8, 16, 0, 0);
    }

    f32x4 sacc[4][4];
#pragma unroll
    for (int m = 0; m < 4; m++)
#pragma unroll
        for (int n = 0; n < 4; n++) sacc[m][n] = (f32x4)(0.f);

    // ---- phase 1: S = Q K^T (contraction over d, 8 steps of 32) ----
    stageK(0, 0);
    __syncthreads();
    for (int dk = 0; dk < 8; dk++) {
        const int cur = dk & 1;
        if (dk < 7) stageK(cur ^ 1, dk + 1);
        short8 af[4], bfr[4];
#pragma unroll
        for (int m = 0; m < 4; m++) {
            int row = m * 16 + lr;
            af[m] = *(const short8*)&Ps[row * 256 + (((dk * 4 + kg) ^ (row & 7)) * 8)];
        }
#pragma unroll
        for (int n = 0; n < 4; n++) {
            int row = w * 64 + n * 16 + lr;
            bfr[n] = *(const short8*)&Ks[cur * 8192 + row * 32 + ((kg ^ ((row >> 1) & 3)) * 8)];
        }
#pragma unroll
        for (int m = 0; m < 4; m++)
#pragma unroll
            for (int n = 0; n < 4; n++)
                sacc[m][n] = __builtin_amdgcn_mfma_f32_16x16x32_bf16(
                    af[m], bfr[n], sacc[m][n], 0, 0, 0);
        __syncthreads();
    }

    // prefetch V tile 0 into Ks buf0 (overlaps softmax)
    stageV(0, 0);

    // ---- phase 2: scale + mask + softmax(+1 denom) ----
#pragma unroll
    for (int m = 0; m < 4; m++)
#pragma unroll
        for (int n = 0; n < 4; n++)
#pragma unroll
            for (int e = 0; e < 4; e++) {
                float t = sacc[m][n][e] * 0.0625f;
                if (MASKED) {
                    int q = qt * 64 + m * 16 + kg * 4 + e;
                    int k = w * 64 + n * 16 + lr;
                    int a_ = adj[((size_t)b * 256 + q) * 256 + k];
                    t += (1.f - (float)a_) * -1.0e6f;
                }
                sacc[m][n][e] = t;
            }

    float mx[4][4];
#pragma unroll
    for (int m = 0; m < 4; m++)
#pragma unroll
        for (int e = 0; e < 4; e++) {
            float v = sacc[m][0][e];
#pragma unroll
            for (int n = 1; n < 4; n++) v = fmaxf(v, sacc[m][n][e]);
#pragma unroll
            for (int off = 1; off < 16; off <<= 1) v = fmaxf(v, __shfl_xor(v, off));
            mx[m][e] = v;
        }
    if (lr == 0) {
#pragma unroll
        for (int m = 0; m < 4; m++)
#pragma unroll
            for (int e = 0; e < 4; e++)
                red1[(m * 16 + kg * 4 + e) * 4 + w] = mx[m][e];
    }
    __syncthreads();

    float inv[4][4];
    float sum[4][4];
#pragma unroll
    for (int m = 0; m < 4; m++)
#pragma unroll
        for (int e = 0; e < 4; e++) {
            int r = m * 16 + kg * 4 + e;
            float gm = fmaxf(fmaxf(red1[r * 4 + 0], red1[r * 4 + 1]),
                             fmaxf(red1[r * 4 + 2], red1[r * 4 + 3]));
            float s = 0.f;
#pragma unroll
            for (int n = 0; n < 4; n++) {
                float ev = __expf(sacc[m][n][e] - gm);
                sacc[m][n][e] = ev;
                s += ev;
            }
            sum[m][e] = s;
        }
#pragma unroll
    for (int m = 0; m < 4; m++)
#pragma unroll
        for (int e = 0; e < 4; e++) {
            float s = sum[m][e];
#pragma unroll
            for (int off = 1; off < 16; off <<= 1) s += __shfl_xor(s, off);
            sum[m][e] = s;
        }
    if (lr == 0) {
#pragma unroll
        for (int m = 0; m < 4; m++)
#pragma unroll
            for (int e = 0; e < 4; e++)
                red2[(m * 16 + kg * 4 + e) * 4 + w] = sum[m][e];
    }
    __syncthreads();
#pragma unroll
    for (int m = 0; m < 4; m++)
#pragma unroll
        for (int e = 0; e < 4; e++) {
            int r = m * 16 + kg * 4 + e;
            float gs = red2[r * 4 + 0] + red2[r * 4 + 1] +
                       red2[r * 4 + 2] + red2[r * 4 + 3];
            inv[m][e] = 1.f / (1.f + gs);
        }

    // ---- phase 3: P -> LDS (bf16, aliases Q tile; all Q reads are done) ----
#pragma unroll
    for (int m = 0; m < 4; m++)
#pragma unroll
        for (int n = 0; n < 4; n++)
#pragma unroll
            for (int e = 0; e < 4; e++) {
                int q = m * 16 + kg * 4 + e;
                int k = w * 64 + n * 16 + lr;
                float pv = sacc[m][n][e] * inv[m][e];
                Ps[q * 256 + (((k >> 3) ^ (q & 7)) * 8) + (k & 7)] = f2b(pv);
            }
    __syncthreads();   // P visible to all; V tile 0 drained

    // ---- phase 4: O = P V (contraction over k, 8 steps of 32) ----
    f32x4 oacc[4][4];
#pragma unroll
    for (int m = 0; m < 4; m++)
#pragma unroll
        for (int n = 0; n < 4; n++) oacc[m][n] = (f32x4)(0.f);

    for (int kt = 0; kt < 8; kt++) {
        const int cur = kt & 1;
        if (kt < 7) stageV(cur ^ 1, kt + 1);
        short8 af[4], bfr[4];
#pragma unroll
        for (int m = 0; m < 4; m++) {
            int q = m * 16 + lr;
            af[m] = *(const short8*)&Ps[q * 256 + (((kt * 4 + kg) ^ (q & 7)) * 8)];
        }
#pragma unroll
        for (int n = 0; n < 4; n++) {
            int row = w * 64 + n * 16 + lr;
            bfr[n] = *(const short8*)&Ks[cur * 8192 + row * 32 + ((kg ^ ((row >> 1) & 3)) * 8)];
        }
#pragma unroll
        for (int m = 0; m < 4; m++)
#pragma unroll
            for (int n = 0; n < 4; n++)
                oacc[m][n] = __builtin_amdgcn_mfma_f32_16x16x32_bf16(
                    af[m], bfr[n], oacc[m][n], 0, 0, 0);
        __syncthreads();
    }

    // ---- epilogue: O[tok][h*256+d] ----
#pragma unroll
    for (int m = 0; m < 4; m++)
#pragma unroll
        for (int n = 0; n < 4; n++)
#pragma unroll
            for (int e = 0; e < 4; e++) {
                int q = qt * 64 + m * 16 + kg * 4 + e;
                int d = w * 64 + n * 16 + lr;
                O[(size_t)(b * 256 + q) * 2048 + h * 256 + d] = f2b(oacc[m][n][e]);
            }
}

// ---------------------------------------------------------------------------
// Transpose+convert: src f32 [R][C] -> dst bf16 [C][R].
// blockIdx.z = layer*nsrc + mat; src = p[mat] + layer*srcLayerStride;
// dst = out + layer*dstLayerStride + mat*dstMatStride.
// ---------------------------------------------------------------------------
__global__ __launch_bounds__(256) void transpose_kernel(
    const float* p0, const float* p1, const float* p2,
    const float* p3, const float* p4, const float* p5,
    int nsrc, long srcLayerStride, int R, int C,
    u16* __restrict__ out, long dstMatStride, long dstLayerStride)
{
    const int mat = blockIdx.z % nsrc, layer = blockIdx.z / nsrc;
    const float* W;
    switch (mat) {
    default: W = p0; break;
    case 1: W = p1; break;
    case 2: W = p2; break;
    case 3: W = p3; break;
    case 4: W = p4; break;
    case 5: W = p5; break;
    }
    W += (size_t)layer * srcLayerStride;
    u16* o = out + (size_t)layer * dstLayerStride + (size_t)mat * dstMatStride;
    __shared__ float t[64][65];
    const int tid = threadIdx.x;
    const int rBase = blockIdx.y * 64, cBase = blockIdx.x * 64;
#pragma unroll
    for (int i = 0; i < 16; i++) {
        int idx = tid + i * 256;
        int rr = idx >> 6, cc = idx & 63;
        float v = 0.f;
        if (rBase + rr < R) v = W[(size_t)(rBase + rr) * C + cBase + cc];
        t[rr][cc] = v;
    }
    __syncthreads();
#pragma unroll
    for (int i = 0; i < 16; i++) {
        int idx = tid + i * 256;
        int cc = idx >> 6, rr = idx & 63;
        if (rBase + rr < R)
            o[(size_t)(cBase + cc) * R + rBase + rr] = f2b(t[rr][cc]);
    }
}

// ---------------------------------------------------------------------------
// LayerNorm rows of 512, f32 in -> bf16 out. One wave per row.
// ---------------------------------------------------------------------------
__global__ __launch_bounds__(256) void ln_kernel(
    const float* __restrict__ X, const float* __restrict__ g,
    const float* __restrict__ b, u16* __restrict__ Y)
{
    const int wave = threadIdx.x >> 6, lane = threadIdx.x & 63;
    const size_t row = (size_t)blockIdx.x * 4 + wave;
    const float* xr = X + row * 512;
    float4 v0 = *reinterpret_cast<const float4*>(xr + lane * 8);
    float4 v1 = *reinterpret_cast<const float4*>(xr + lane * 8 + 4);
    float s = v0.x + v0.y + v0.z + v0.w + v1.x + v1.y + v1.z + v1.w;
    float ss = v0.x * v0.x + v0.y * v0.y + v0.z * v0.z + v0.w * v0.w +
               v1.x * v1.x + v1.y * v1.y + v1.z * v1.z + v1.w * v1.w;
#pragma unroll
    for (int off = 32; off; off >>= 1) {
        s += __shfl_xor(s, off);
        ss += __shfl_xor(ss, off);
    }
    float mu = s * (1.0f / 512.0f);
    float var = ss * (1.0f / 512.0f) - mu * mu;
    float rs = rsqrtf(var + 1e-5f);
    float4 g0 = *reinterpret_cast<const float4*>(g + lane * 8);
    float4 g1 = *reinterpret_cast<const float4*>(g + lane * 8 + 4);
    float4 b0 = *reinterpret_cast<const float4*>(b + lane * 8);
    float4 b1 = *reinterpret_cast<const float4*>(b + lane * 8 + 4);
    float o0 = (v0.x - mu) * rs * g0.x + b0.x;
    float o1 = (v0.y - mu) * rs * g0.y + b0.y;
    float o2 = (v0.z - mu) * rs * g0.z + b0.z;
    float o3 = (v0.w - mu) * rs * g0.w + b0.w;
    float o4 = (v1.x - mu) * rs * g1.x + b1.x;
    float o5 = (v1.y - mu) * rs * g1.y + b1.y;
    float o6 = (v1.z - mu) * rs * g1.z + b1.z;
    float o7 = (v1.w - mu) * rs * g1.w + b1.w;
    uint4 pk;
    pk.x = (unsigned)f2b(o0) | ((unsigned)f2b(o1) << 16);
    pk.y = (unsigned)f2b(o2) | ((unsigned)f2b(o3) << 16);
    pk.z = (unsigned)f2b(o4) | ((unsigned)f2b(o5) << 16);
    pk.w = (unsigned)f2b(o6) | ((unsigned)f2b(o7) << 16);
    *reinterpret_cast<uint4*>(Y + row * 512 + lane * 8) = pk;
}

// ---------------------------------------------------------------------------
// Embedding gather -> bf16: Ag[t][j*300+e] = embed[program[t][j]][e]
// ---------------------------------------------------------------------------
__global__ __launch_bounds__(256) void gather_kernel(
    const int* __restrict__ program, const float* __restrict__ embed,
    u16* __restrict__ Ag, int total)
{
    int idx = blockIdx.x * 256 + threadIdx.x;
    if (idx >= total) return;
    int t = idx / 2400;
    int c = idx - t * 2400;
    int j = c / 300;
    int e = c - j * 300;
    int tok = program[t * 8 + j];
    Ag[idx] = f2b(embed[(size_t)tok * 300 + e]);
}

// f32 -> bf16 convert, 4 elems/thread
__global__ __launch_bounds__(256) void cvt_kernel(
    const float* __restrict__ in, u16* __restrict__ out, int n4)
{
    int i = blockIdx.x * 256 + threadIdx.x;
    if (i >= n4) return;
    float4 v = reinterpret_cast<const float4*>(in)[i];
    uint2 pk;
    pk.x = (unsigned)f2b(v.x) | ((unsigned)f2b(v.y) << 16);
    pk.y = (unsigned)f2b(v.z) | ((unsigned)f2b(v.w) << 16);
    reinterpret_cast<uint2*>(out)[i] = pk;
}

// ---------------------------------------------------------------------------

extern "C" void kernel_launch(void* const* d_in, const int* in_sizes, int n_in,
                              void* d_out, int out_size, void* d_ws, size_t ws_size,
                              hipStream_t stream)
{
    const int*   program = (const int*)d_in[0];
    const int*   adj     = (const int*)d_in[1];
    const float* img     = (const float*)d_in[2];
    const float* embed   = (const float*)d_in[3];
    const float* W_in    = (const float*)d_in[4];
    const float* b_in    = (const float*)d_in[5];
    const float* ln1_g   = (const float*)d_in[6];
    const float* ln1_b   = (const float*)d_in[7];
    const float* ln2_g   = (const float*)d_in[8];
    const float* ln2_b   = (const float*)d_in[9];
    const float* Wq      = (const float*)d_in[10];
    const float* bq      = (const float*)d_in[11];
    const float* Wk      = (const float*)d_in[12];
    const float* bk      = (const float*)d_in[13];
    const float* Wv      = (const float*)d_in[14];
    const float* bv      = (const float*)d_in[15];
    const float* Wo      = (const float*)d_in[16];
    const float* bo      = (const float*)d_in[17];
    const float* fW1     = (const float*)d_in[18];
    const float* fb1     = (const float*)d_in[19];
    const float* fW2     = (const float*)d_in[20];
    const float* fb2     = (const float*)d_in[21];
    const float* cWq     = (const float*)d_in[22];
    const float* cbq     = (const float*)d_in[23];
    const float* cWk     = (const float*)d_in[24];
    const float* cbk     = (const float*)d_in[25];
    const float* cWv     = (const float*)d_in[26];
    const float* cbv     = (const float*)d_in[27];
    const float* cWo     = (const float*)d_in[28];
    const float* cbo     = (const float*)d_in[29];

    char* wsb = (char*)d_ws;
    const size_t MB = 1024 * 1024;
    const long Mi = 1048576;
    const long LSTR = 8 * Mi + Mi / 2;           // 8.5 Mi elements per layer block

    float* x    = (float*)(wsb + 0);             // 4096x512 f32      (8 MB)
    u16*   h    = (u16*)(wsb + 8 * MB);          // 4096x512 bf16     (4 MB)
    u16*   xb   = (u16*)(wsb + 12 * MB);         // 4096x512 bf16     (4 MB)
    u16*   imgb = (u16*)(wsb + 16 * MB);         // 4096x512 bf16     (4 MB)
    u16*   WinT = (u16*)(wsb + 20 * MB);         // 512x2400 bf16     (2.4 MB)
    u16*   Q    = (u16*)(wsb + 24 * MB);         // 4096x2048 bf16    (16 MB)
    u16*   Kb   = (u16*)(wsb + 40 * MB);         // 4096x2048 bf16    (16 MB)
    u16*   Vt   = (u16*)(wsb + 56 * MB);         // [128][256][256]   (16 MB)
    u16*   O    = (u16*)(wsb + 72 * MB);         // 4096x2048 bf16    (16 MB)
    u16*   Wall = (u16*)(wsb + 88 * MB);         // transposed weights
    u16*   Ag   = Q;   // gather buffer (19.7 MB: Q + start of Kb, both dead)
    u16*   g    = Q;   // FFN mid aliases Q (dead during FFN)

    // big ws: all 6 layers' weights transposed upfront (102 MB); else per-layer
    const bool bigws = ws_size >= (size_t)191 * MB;

    // prologue
    gather_kernel<<<38400, 256, 0, stream>>>(program, embed, Ag, 9830400);
    transpose_kernel<<<dim3(8, 38, 1), 256, 0, stream>>>(
        W_in, nullptr, nullptr, nullptr, nullptr, nullptr,
        1, 0, 2400, 512, WinT, 0, 0);
    cvt_kernel<<<2048, 256, 0, stream>>>(img, imgb, 524288);
    if (bigws) {
        transpose_kernel<<<dim3(32, 8, 36), 256, 0, stream>>>(
            Wq, Wk, Wv, cWq, cWk, cWv, 6, Mi, 512, 2048, Wall, Mi, LSTR);
        transpose_kernel<<<dim3(8, 32, 12), 256, 0, stream>>>(
            Wo, cWo, nullptr, nullptr, nullptr, nullptr,
            2, Mi, 2048, 512, Wall + 6 * Mi, Mi, LSTR);
        transpose_kernel<<<dim3(8, 8, 12), 256, 0, stream>>>(
            fW1, fW2, nullptr, nullptr, nullptr, nullptr,
            2, 262144, 512, 512, Wall + 8 * Mi, 262144, LSTR);
    }
    gemm_bf16<64, EPI_F32><<<dim3(4, 64, 1), 256, 0, stream>>>(
        Ag, 0, 2400, WinT, 0, 2400, 4096, 512, 2400,
        b_in, nullptr, nullptr, nullptr,
        x, nullptr, nullptr, nullptr, 0, 512);

    for (int l = 0; l < 6; l++) {
        u16* Wl = Wall + (bigws ? (size_t)l * LSTR : 0);
        if (!bigws) {
            transpose_kernel<<<dim3(32, 8, 6), 256, 0, stream>>>(
                Wq + (size_t)l * Mi, Wk + (size_t)l * Mi, Wv + (size_t)l * Mi,
                cWq + (size_t)l * Mi, cWk + (size_t)l * Mi, cWv + (size_t)l * Mi,
                6, 0, 512, 2048, Wl, Mi, 0);
            transpose_kernel<<<dim3(8, 32, 2), 256, 0, stream>>>(
                Wo + (size_t)l * Mi, cWo + (size_t)l * Mi,
                nullptr, nullptr, nullptr, nullptr,
                2, 0, 2048, 512, Wl + 6 * Mi, Mi, 0);
            transpose_kernel<<<dim3(8, 8, 2), 256, 0, stream>>>(
                fW1 + (size_t)l * 262144, fW2 + (size_t)l * 262144,
                nullptr, nullptr, nullptr, nullptr,
                2, 0, 512, 512, Wl + 8 * Mi, 262144, 0);
        }

        // --- self-attention ---
        ln_kernel<<<1024, 256, 0, stream>>>(x, ln1_g + l * 512, ln1_b + l * 512, h);
        gemm_bf16<128, EPI_QKV><<<dim3(48, 32, 1), 256, 0, stream>>>(
            h, 0, 512, Wl, 0, 512, 4096, 6144, 512,
            bq + l * 2048, bk + l * 2048, bv + l * 2048, nullptr,
            nullptr, Q, Kb, Vt, 0, 2048);
        attn_kernel<true><<<dim3(4, 128), 256, 0, stream>>>(Q, Kb, Vt, adj, O);
        gemm_bf16<64, EPI_ATOMIC><<<dim3(4, 64, 4), 256, 0, stream>>>(
            O, 512, 2048, Wl + 6 * Mi, 512, 2048, 4096, 512, 512,
            bo + l * 512, nullptr, nullptr, nullptr,
            x, nullptr, nullptr, nullptr, 0, 512);

        // --- FFN ---
        ln_kernel<<<1024, 256, 0, stream>>>(x, ln2_g + l * 512, ln2_b + l * 512, h);
        gemm_bf16<64, EPI_GELU><<<dim3(4, 64, 1), 256, 0, stream>>>(
            h, 0, 512, Wl + 8 * Mi, 0, 512, 4096, 512, 512,
            fb1 + l * 512, nullptr, nullptr, nullptr,
            nullptr, g, nullptr, nullptr, 0, 512);
        gemm_bf16<64, EPI_RESID_XB><<<dim3(4, 64, 1), 256, 0, stream>>>(
            g, 0, 512, Wl + 8 * Mi + 262144, 0, 512, 4096, 512, 512,
            fb2 + l * 512, nullptr, nullptr, x,
            x, xb, nullptr, nullptr, 0, 512);

        // --- cross-attention (query = x, no mask) ---
        gemm_bf16<128, EPI_BF16><<<dim3(16, 32, 1), 256, 0, stream>>>(
            xb, 0, 512, Wl + 3 * Mi, 0, 512, 4096, 2048, 512,
            cbq + l * 2048, nullptr, nullptr, nullptr,
            nullptr, Q, nullptr, nullptr, 0, 2048);
        gemm_bf16<128, EPI_KV><<<dim3(32, 32, 1), 256, 0, stream>>>(
            imgb, 0, 512, Wl + 4 * Mi, 0, 512, 4096, 4096, 512,
            cbk + l * 2048, cbv + l * 2048, nullptr, nullptr,
            nullptr, Kb, nullptr, Vt, 0, 2048);
        attn_kernel<false><<<dim3(4, 128), 256, 0, stream>>>(Q, Kb, Vt, nullptr, O);
        gemm_bf16<64, EPI_ATOMIC><<<dim3(4, 64, 4), 256, 0, stream>>>(
            O, 512, 2048, Wl + 7 * Mi, 512, 2048, 4096, 512, 512,
            cbo + l * 512, nullptr, nullptr, nullptr,
            x, nullptr, nullptr, nullptr, 0, 512);
    }

    hipMemcpyAsync(d_out, x, (size_t)2097152 * sizeof(float),
                   hipMemcpyDeviceToDevice, stream);
}

// Round 6
// 1902.643 us; speedup vs baseline: 6.5945x; 1.0661x over previous
//
#include <hip/hip_runtime.h>
#include <hip/hip_bf16.h>

typedef __attribute__((ext_vector_type(8))) short short8;
typedef __attribute__((ext_vector_type(4))) float f32x4;
typedef unsigned short u16;

__device__ __forceinline__ u16 f2b(float f) {
    unsigned int u = __builtin_bit_cast(unsigned int, f);
    u = u + 0x7fffu + ((u >> 16) & 1u);
    return (u16)(u >> 16);
}

// epilogue modes (template parameter)
#define EPI_F32      0   // outF = acc + bias0
#define EPI_RESID_XB 3   // outF = acc+bias0+Rsd, outB = bf16(same)
#define EPI_GELU     4   // outB = bf16(gelu(acc + bias0))
#define EPI_KV       7   // 2-way split: K(outB), V-transposed(outV)
#define EPI_ATOMIC   9   // atomicAdd(outF, acc) (+bias0 when bz==0), split-K

// ---------------------------------------------------------------------------
// bf16 MFMA GEMM: C = A(M,K) @ Bt(N,K)^T, f32 accumulate, fused epilogue EPI.
// BM x BN tile (BN 64 or 128), BK=32, 256 threads, 16x16x32 bf16 MFMA.
// 2-phase double-buffered K-loop with global_load_lds width=16.
// LDS linear; XOR-swizzle applied to per-lane GLOBAL source k-group.
// For EPI_ATOMIC, blockIdx.z is the K-slice (offset bz*aStride / bz*bStride).
// ---------------------------------------------------------------------------
template<int BM, int BN, int EPI>
__global__ __launch_bounds__(256, 2) void gemm_bf16(
    const u16* __restrict__ A, long aStride, int lda,
    const u16* __restrict__ B, long bStride, int ldb,
    int M, int N, int K,
    const float* __restrict__ bias0, const float* __restrict__ bias1,
    const float* __restrict__ Rsd,
    float* __restrict__ outF, u16* __restrict__ outB,
    u16* __restrict__ outV, int ldc)
{
    constexpr int WCOLS = BN / 64;           // waves along N
    constexpr int WROWS = 4 / WCOLS;         // waves along M
    constexpr int WM = BM / WROWS;           // rows per wave
    constexpr int MF = WM / 16;
    constexpr int NF = 4;                    // 64 cols per wave
    constexpr int AUNITS = BM * 4;           // 16B units in A tile
    constexpr int UPT = (BM + BN) / 64;      // 16B units per thread
    constexpr int BUFE = (BM + BN) * 32;     // u16 per LDS buffer

    __shared__ __align__(16) u16 smem[2 * BUFE];

    const int tid = threadIdx.x;
    const int wave = tid >> 6, lane = tid & 63;
    const int wm = wave / WCOLS, wn = wave % WCOLS;
    const int tm = blockIdx.y * BM, tn = blockIdx.x * BN;
    const int bz = blockIdx.z;

    const size_t aOff = (size_t)bz * (size_t)aStride;
    const size_t bOff = (size_t)bz * (size_t)bStride;

    const int lr = lane & 15, kg = lane >> 4;

    auto stage = [&](int buf, int k0) {
#pragma unroll
        for (int i = 0; i < UPT; i++) {
            int u = tid + i * 256;
            u16* dst = smem + buf * BUFE + u * 8;
            if (u < AUNITS) {
                int row = u >> 2, g = u & 3;
                int gs = g ^ ((row >> 1) & 3);
                const u16* src = A + aOff + (size_t)(tm + row) * lda + k0 + gs * 8;
                __builtin_amdgcn_global_load_lds(src, dst, 16, 0, 0);
            } else {
                int v2 = u - AUNITS;
                int row = v2 >> 2, g = v2 & 3;
                int gs = g ^ ((row >> 1) & 3);
                const u16* src = B + bOff + (size_t)(tn + row) * ldb + k0 + gs * 8;
                __builtin_amdgcn_global_load_lds(src, dst, 16, 0, 0);
            }
        }
    };

    f32x4 acc[MF][NF];
#pragma unroll
    for (int m = 0; m < MF; m++)
#pragma unroll
        for (int n = 0; n < NF; n++) acc[m][n] = (f32x4)(0.f);

    const int NT = K >> 5;
    stage(0, 0);
    __syncthreads();

    for (int t = 0; t < NT; t++) {
        const int cur = t & 1;
        if (t + 1 < NT) stage(cur ^ 1, (t + 1) * 32);

        const u16* As = smem + cur * BUFE;
        const u16* Bs = As + BM * 32;
        short8 af[MF], bfr[NF];
#pragma unroll
        for (int m = 0; m < MF; m++) {
            int row = wm * WM + m * 16 + lr;
            af[m] = *(const short8*)&As[row * 32 + ((kg ^ ((row >> 1) & 3)) * 8)];
        }
#pragma unroll
        for (int n = 0; n < NF; n++) {
            int row = wn * 64 + n * 16 + lr;
            bfr[n] = *(const short8*)&Bs[row * 32 + ((kg ^ ((row >> 1) & 3)) * 8)];
        }
#pragma unroll
        for (int m = 0; m < MF; m++)
#pragma unroll
            for (int n = 0; n < NF; n++)
                acc[m][n] = __builtin_amdgcn_mfma_f32_16x16x32_bf16(
                    af[m], bfr[n], acc[m][n], 0, 0, 0);
        __syncthreads();
    }

    // epilogue: D row=(lane>>4)*4+e, col=lane&15
#pragma unroll
    for (int m = 0; m < MF; m++) {
#pragma unroll
        for (int n = 0; n < NF; n++) {
#pragma unroll
            for (int e = 0; e < 4; e++) {
                int r = tm + wm * WM + m * 16 + (lane >> 4) * 4 + e;
                int c = tn + wn * 64 + n * 16 + (lane & 15);
                float v = acc[m][n][e];
                if constexpr (EPI == EPI_F32) {
                    outF[(size_t)r * ldc + c] = v + bias0[c];
                } else if constexpr (EPI == EPI_RESID_XB) {
                    float t = v + bias0[c] + Rsd[(size_t)r * ldc + c];
                    outF[(size_t)r * ldc + c] = t;
                    outB[(size_t)r * ldc + c] = f2b(t);
                } else if constexpr (EPI == EPI_GELU) {
                    float t = v + bias0[c];
                    t = 0.5f * t * (1.f + erff(t * 0.70710678118654752f));
                    outB[(size_t)r * ldc + c] = f2b(t);
                } else if constexpr (EPI == EPI_KV) {
                    int sel = c >> 11, cc = c & 2047;
                    float t = v + (sel == 0 ? bias0 : bias1)[cc];
                    if (sel == 0)
                        outB[(size_t)r * 2048 + cc] = f2b(t);
                    else
                        outV[(size_t)((r >> 8) * 8 + (cc >> 8)) * 65536 +
                             (size_t)(cc & 255) * 256 + (r & 255)] = f2b(t);
                } else if constexpr (EPI == EPI_ATOMIC) {
                    float t = v;
                    if (bz == 0) t += bias0[c];
                    atomicAdd(&outF[(size_t)r * ldc + c], t);
                }
            }
        }
    }
}

// ---------------------------------------------------------------------------
// Fused attention with Q-projection:
// per (b,h) and 64-row q-tile:
//   Q = Aq[rows][512] @ WqT[h*256..+256][512]^T + bq_h     (phase 0)
//   O = softmax1(Q K^T / 16 + mask) V                      (phases 1-4)
// Aq: bf16 [4096][512] (LN output h, or xb). K: [4096][2048].
// Vt: [bh][256 d][256 tok]. All streamed double-buffered via global_load_lds.
// ---------------------------------------------------------------------------
template<bool MASKED>
__global__ __launch_bounds__(256, 2) void attn_kernel(
    const u16* __restrict__ Aq, const u16* __restrict__ WqT,
    const float* __restrict__ bq,
    const u16* __restrict__ K, const u16* __restrict__ Vt,
    const int* __restrict__ adj, u16* __restrict__ O)
{
    __shared__ __align__(16) u16 Ps[64 * 256];       // Q tile then P tile (32 KB)
    __shared__ __align__(16) u16 Ks[2 * 256 * 32];   // B double buffer (32 KB)
    __shared__ __align__(16) u16 Aql[2 * 64 * 32];   // phase-0 A dbuf (8 KB)
    __shared__ float red1[64 * 4];
    __shared__ float red2[64 * 4];

    const int tid = threadIdx.x;
    const int w = tid >> 6, lane = tid & 63;
    const int lr = lane & 15, kg = lane >> 4;
    const int qt = blockIdx.x, bh = blockIdx.y;
    const int b = bh >> 3, h = bh & 7;
    const size_t qkBase = (size_t)b * 256 * 2048 + h * 256;

    auto stageA0 = [&](int buf, int k0) {
        int u = tid;                       // 256 units exactly
        int row = u >> 2, g = u & 3;
        int gs = g ^ ((row >> 1) & 3);
        const u16* src = Aq + (size_t)(b * 256 + qt * 64 + row) * 512 + k0 + gs * 8;
        __builtin_amdgcn_global_load_lds(src, Aql + buf * 2048 + u * 8, 16, 0, 0);
    };
    auto stageB0 = [&](int buf, int k0) {
#pragma unroll
        for (int i = 0; i < 4; i++) {
            int u = tid + i * 256;
            int row = u >> 2, g = u & 3;
            int gs = g ^ ((row >> 1) & 3);
            const u16* src = WqT + (size_t)(h * 256 + row) * 512 + k0 + gs * 8;
            __builtin_amdgcn_global_load_lds(src, Ks + buf * 8192 + u * 8, 16, 0, 0);
        }
    };
    auto stageK = [&](int buf, int dk) {
#pragma unroll
        for (int i = 0; i < 4; i++) {
            int u = tid + i * 256;
            int row = u >> 2, g = u & 3;
            int gs = g ^ ((row >> 1) & 3);
            const u16* src = K + qkBase + (size_t)row * 2048 + dk * 32 + gs * 8;
            __builtin_amdgcn_global_load_lds(src, Ks + buf * 8192 + u * 8, 16, 0, 0);
        }
    };
    auto stageV = [&](int buf, int kt) {
#pragma unroll
        for (int i = 0; i < 4; i++) {
            int u = tid + i * 256;
            int row = u >> 2, g = u & 3;   // row = d
            int gs = g ^ ((row >> 1) & 3);
            const u16* src = Vt + (size_t)bh * 65536 + (size_t)row * 256 + kt * 32 + gs * 8;
            __builtin_amdgcn_global_load_lds(src, Ks + buf * 8192 + u * 8, 16, 0, 0);
        }
    };

    // ---- phase 0: Q = Aq @ WqT_head + bq  (K=512, 16 steps of 32) ----
    {
        f32x4 qacc[4][4];
#pragma unroll
        for (int m = 0; m < 4; m++)
#pragma unroll
            for (int n = 0; n < 4; n++) qacc[m][n] = (f32x4)(0.f);

        stageA0(0, 0);
        stageB0(0, 0);
        __syncthreads();
        for (int t = 0; t < 16; t++) {
            const int cur = t & 1;
            if (t < 15) { stageA0(cur ^ 1, (t + 1) * 32); stageB0(cur ^ 1, (t + 1) * 32); }
            short8 af[4], bfr[4];
#pragma unroll
            for (int m = 0; m < 4; m++) {
                int row = m * 16 + lr;
                af[m] = *(const short8*)&Aql[cur * 2048 + row * 32 + ((kg ^ ((row >> 1) & 3)) * 8)];
            }
#pragma unroll
            for (int n = 0; n < 4; n++) {
                int row = w * 64 + n * 16 + lr;
                bfr[n] = *(const short8*)&Ks[cur * 8192 + row * 32 + ((kg ^ ((row >> 1) & 3)) * 8)];
            }
#pragma unroll
            for (int m = 0; m < 4; m++)
#pragma unroll
                for (int n = 0; n < 4; n++)
                    qacc[m][n] = __builtin_amdgcn_mfma_f32_16x16x32_bf16(
                        af[m], bfr[n], qacc[m][n], 0, 0, 0);
            __syncthreads();
        }
        // write Q tile to Ps (bf16, swizzled for phase-1 A reads)
#pragma unroll
        for (int m = 0; m < 4; m++)
#pragma unroll
            for (int n = 0; n < 4; n++)
#pragma unroll
                for (int e = 0; e < 4; e++) {
                    int q = m * 16 + kg * 4 + e;
                    int d = w * 64 + n * 16 + lr;
                    float t = qacc[m][n][e] + bq[h * 256 + d];
                    Ps[q * 256 + (((d >> 3) ^ (q & 7)) * 8) + (d & 7)] = f2b(t);
                }
    }
    __syncthreads();

    f32x4 sacc[4][4];
#pragma unroll
    for (int m = 0; m < 4; m++)
#pragma unroll
        for (int n = 0; n < 4; n++) sacc[m][n] = (f32x4)(0.f);

    // ---- phase 1: S = Q K^T (contraction over d, 8 steps of 32) ----
    stageK(0, 0);
    __syncthreads();
    for (int dk = 0; dk < 8; dk++) {
        const int cur = dk & 1;
        if (dk < 7) stageK(cur ^ 1, dk + 1);
        short8 af[4], bfr[4];
#pragma unroll
        for (int m = 0; m < 4; m++) {
            int row = m * 16 + lr;
            af[m] = *(const short8*)&Ps[row * 256 + (((dk * 4 + kg) ^ (row & 7)) * 8)];
        }
#pragma unroll
        for (int n = 0; n < 4; n++) {
            int row = w * 64 + n * 16 + lr;
            bfr[n] = *(const short8*)&Ks[cur * 8192 + row * 32 + ((kg ^ ((row >> 1) & 3)) * 8)];
        }
#pragma unroll
        for (int m = 0; m < 4; m++)
#pragma unroll
            for (int n = 0; n < 4; n++)
                sacc[m][n] = __builtin_amdgcn_mfma_f32_16x16x32_bf16(
                    af[m], bfr[n], sacc[m][n], 0, 0, 0);
        __syncthreads();
    }

    // prefetch V tile 0 into Ks buf0 (overlaps softmax)
    stageV(0, 0);

    // ---- phase 2: scale + mask + softmax(+1 denom) ----
#pragma unroll
    for (int m = 0; m < 4; m++)
#pragma unroll
        for (int n = 0; n < 4; n++)
#pragma unroll
            for (int e = 0; e < 4; e++) {
                float t = sacc[m][n][e] * 0.0625f;
                if (MASKED) {
                    int q = qt * 64 + m * 16 + kg * 4 + e;
                    int k = w * 64 + n * 16 + lr;
                    int a_ = adj[((size_t)b * 256 + q) * 256 + k];
                    t += (1.f - (float)a_) * -1.0e6f;
                }
                sacc[m][n][e] = t;
            }

    float mx[4][4];
#pragma unroll
    for (int m = 0; m < 4; m++)
#pragma unroll
        for (int e = 0; e < 4; e++) {
            float v = sacc[m][0][e];
#pragma unroll
            for (int n = 1; n < 4; n++) v = fmaxf(v, sacc[m][n][e]);
#pragma unroll
            for (int off = 1; off < 16; off <<= 1) v = fmaxf(v, __shfl_xor(v, off));
            mx[m][e] = v;
        }
    if (lr == 0) {
#pragma unroll
        for (int m = 0; m < 4; m++)
#pragma unroll
            for (int e = 0; e < 4; e++)
                red1[(m * 16 + kg * 4 + e) * 4 + w] = mx[m][e];
    }
    __syncthreads();

    float inv[4][4];
    float sum[4][4];
#pragma unroll
    for (int m = 0; m < 4; m++)
#pragma unroll
        for (int e = 0; e < 4; e++) {
            int r = m * 16 + kg * 4 + e;
            float gm = fmaxf(fmaxf(red1[r * 4 + 0], red1[r * 4 + 1]),
                             fmaxf(red1[r * 4 + 2], red1[r * 4 + 3]));
            float s = 0.f;
#pragma unroll
            for (int n = 0; n < 4; n++) {
                float ev = __expf(sacc[m][n][e] - gm);
                sacc[m][n][e] = ev;
                s += ev;
            }
            sum[m][e] = s;
        }
#pragma unroll
    for (int m = 0; m < 4; m++)
#pragma unroll
        for (int e = 0; e < 4; e++) {
            float s = sum[m][e];
#pragma unroll
            for (int off = 1; off < 16; off <<= 1) s += __shfl_xor(s, off);
            sum[m][e] = s;
        }
    if (lr == 0) {
#pragma unroll
        for (int m = 0; m < 4; m++)
#pragma unroll
            for (int e = 0; e < 4; e++)
                red2[(m * 16 + kg * 4 + e) * 4 + w] = sum[m][e];
    }
    __syncthreads();
#pragma unroll
    for (int m = 0; m < 4; m++)
#pragma unroll
        for (int e = 0; e < 4; e++) {
            int r = m * 16 + kg * 4 + e;
            float gs = red2[r * 4 + 0] + red2[r * 4 + 1] +
                       red2[r * 4 + 2] + red2[r * 4 + 3];
            inv[m][e] = 1.f / (1.f + gs);
        }

    // ---- phase 3: P -> LDS (bf16, overwrites Q tile) ----
#pragma unroll
    for (int m = 0; m < 4; m++)
#pragma unroll
        for (int n = 0; n < 4; n++)
#pragma unroll
            for (int e = 0; e < 4; e++) {
                int q = m * 16 + kg * 4 + e;
                int k = w * 64 + n * 16 + lr;
                float pv = sacc[m][n][e] * inv[m][e];
                Ps[q * 256 + (((k >> 3) ^ (q & 7)) * 8) + (k & 7)] = f2b(pv);
            }
    __syncthreads();   // P visible; V tile 0 drained

    // ---- phase 4: O = P V (contraction over k, 8 steps of 32) ----
    f32x4 oacc[4][4];
#pragma unroll
    for (int m = 0; m < 4; m++)
#pragma unroll
        for (int n = 0; n < 4; n++) oacc[m][n] = (f32x4)(0.f);

    for (int kt = 0; kt < 8; kt++) {
        const int cur = kt & 1;
        if (kt < 7) stageV(cur ^ 1, kt + 1);
        short8 af[4], bfr[4];
#pragma unroll
        for (int m = 0; m < 4; m++) {
            int q = m * 16 + lr;
            af[m] = *(const short8*)&Ps[q * 256 + (((kt * 4 + kg) ^ (q & 7)) * 8)];
        }
#pragma unroll
        for (int n = 0; n < 4; n++) {
            int row = w * 64 + n * 16 + lr;
            bfr[n] = *(const short8*)&Ks[cur * 8192 + row * 32 + ((kg ^ ((row >> 1) & 3)) * 8)];
        }
#pragma unroll
        for (int m = 0; m < 4; m++)
#pragma unroll
            for (int n = 0; n < 4; n++)
                oacc[m][n] = __builtin_amdgcn_mfma_f32_16x16x32_bf16(
                    af[m], bfr[n], oacc[m][n], 0, 0, 0);
        __syncthreads();
    }

    // ---- epilogue: O[tok][h*256+d] ----
#pragma unroll
    for (int m = 0; m < 4; m++)
#pragma unroll
        for (int n = 0; n < 4; n++)
#pragma unroll
            for (int e = 0; e < 4; e++) {
                int q = qt * 64 + m * 16 + kg * 4 + e;
                int d = w * 64 + n * 16 + lr;
                O[(size_t)(b * 256 + q) * 2048 + h * 256 + d] = f2b(oacc[m][n][e]);
            }
}

// ---------------------------------------------------------------------------
// Transpose+convert (vectorized): src f32 [R][C] -> dst bf16 [C][R].
// blockIdx.z = layer*nsrc + mat. R multiple of 4, C multiple of 64.
// ---------------------------------------------------------------------------
__global__ __launch_bounds__(256) void transpose_kernel(
    const float* p0, const float* p1, const float* p2,
    const float* p3, const float* p4, const float* p5,
    int nsrc, long srcLayerStride, int R, int C,
    u16* __restrict__ out, long dstMatStride, long dstLayerStride)
{
    const int mat = blockIdx.z % nsrc, layer = blockIdx.z / nsrc;
    const float* W;
    switch (mat) {
    default: W = p0; break;
    case 1: W = p1; break;
    case 2: W = p2; break;
    case 3: W = p3; break;
    case 4: W = p4; break;
    case 5: W = p5; break;
    }
    W += (size_t)layer * srcLayerStride;
    u16* o = out + (size_t)layer * dstLayerStride + (size_t)mat * dstMatStride;
    __shared__ float t[64][68];
    const int tid = threadIdx.x;
    const int rBase = blockIdx.y * 64, cBase = blockIdx.x * 64;
#pragma unroll
    for (int i = 0; i < 4; i++) {
        int idx = tid + i * 256;
        int rr = idx >> 4, cc4 = (idx & 15) * 4;
        if (rBase + rr < R) {
            float4 v = *(const float4*)&W[(size_t)(rBase + rr) * C + cBase + cc4];
            t[rr][cc4] = v.x; t[rr][cc4 + 1] = v.y;
            t[rr][cc4 + 2] = v.z; t[rr][cc4 + 3] = v.w;
        }
    }
    __syncthreads();
#pragma unroll
    for (int i = 0; i < 4; i++) {
        int idx = tid + i * 256;
        int cc = idx >> 4, rr4 = (idx & 15) * 4;
        if (rBase + rr4 < R) {
            uint2 pk;
            pk.x = (unsigned)f2b(t[rr4][cc]) | ((unsigned)f2b(t[rr4 + 1][cc]) << 16);
            pk.y = (unsigned)f2b(t[rr4 + 2][cc]) | ((unsigned)f2b(t[rr4 + 3][cc]) << 16);
            *(uint2*)&o[(size_t)(cBase + cc) * R + rBase + rr4] = pk;
        }
    }
}

// ---------------------------------------------------------------------------
// LayerNorm rows of 512, f32 in -> bf16 out. One wave per row.
// ---------------------------------------------------------------------------
__global__ __launch_bounds__(256) void ln_kernel(
    const float* __restrict__ X, const float* __restrict__ g,
    const float* __restrict__ b, u16* __restrict__ Y)
{
    const int wave = threadIdx.x >> 6, lane = threadIdx.x & 63;
    const size_t row = (size_t)blockIdx.x * 4 + wave;
    const float* xr = X + row * 512;
    float4 v0 = *reinterpret_cast<const float4*>(xr + lane * 8);
    float4 v1 = *reinterpret_cast<const float4*>(xr + lane * 8 + 4);
    float s = v0.x + v0.y + v0.z + v0.w + v1.x + v1.y + v1.z + v1.w;
    float ss = v0.x * v0.x + v0.y * v0.y + v0.z * v0.z + v0.w * v0.w +
               v1.x * v1.x + v1.y * v1.y + v1.z * v1.z + v1.w * v1.w;
#pragma unroll
    for (int off = 32; off; off >>= 1) {
        s += __shfl_xor(s, off);
        ss += __shfl_xor(ss, off);
    }
    float mu = s * (1.0f / 512.0f);
    float var = ss * (1.0f / 512.0f) - mu * mu;
    float rs = rsqrtf(var + 1e-5f);
    float4 g0 = *reinterpret_cast<const float4*>(g + lane * 8);
    float4 g1 = *reinterpret_cast<const float4*>(g + lane * 8 + 4);
    float4 b0 = *reinterpret_cast<const float4*>(b + lane * 8);
    float4 b1 = *reinterpret_cast<const float4*>(b + lane * 8 + 4);
    float o0 = (v0.x - mu) * rs * g0.x + b0.x;
    float o1 = (v0.y - mu) * rs * g0.y + b0.y;
    float o2 = (v0.z - mu) * rs * g0.z + b0.z;
    float o3 = (v0.w - mu) * rs * g0.w + b0.w;
    float o4 = (v1.x - mu) * rs * g1.x + b1.x;
    float o5 = (v1.y - mu) * rs * g1.y + b1.y;
    float o6 = (v1.z - mu) * rs * g1.z + b1.z;
    float o7 = (v1.w - mu) * rs * g1.w + b1.w;
    uint4 pk;
    pk.x = (unsigned)f2b(o0) | ((unsigned)f2b(o1) << 16);
    pk.y = (unsigned)f2b(o2) | ((unsigned)f2b(o3) << 16);
    pk.z = (unsigned)f2b(o4) | ((unsigned)f2b(o5) << 16);
    pk.w = (unsigned)f2b(o6) | ((unsigned)f2b(o7) << 16);
    *reinterpret_cast<uint4*>(Y + row * 512 + lane * 8) = pk;
}

// ---------------------------------------------------------------------------
// Embedding gather -> bf16 (2 elems/thread): Ag[t][j*300+e] = embed[tok][e]
// ---------------------------------------------------------------------------
__global__ __launch_bounds__(256) void gather_kernel(
    const int* __restrict__ program, const float* __restrict__ embed,
    unsigned* __restrict__ Ag2, int total2)
{
    int idx = blockIdx.x * 256 + threadIdx.x;
    if (idx >= total2) return;
    int t = idx / 1200;
    int rem = idx - t * 1200;
    int j = rem / 150;
    int e2 = rem - j * 150;
    int tok = program[t * 8 + j];
    float2 v = *reinterpret_cast<const float2*>(&embed[(size_t)tok * 300 + e2 * 2]);
    Ag2[idx] = (unsigned)f2b(v.x) | ((unsigned)f2b(v.y) << 16);
}

// f32 -> bf16 convert, 4 elems/thread
__global__ __launch_bounds__(256) void cvt_kernel(
    const float* __restrict__ in, u16* __restrict__ out, int n4)
{
    int i = blockIdx.x * 256 + threadIdx.x;
    if (i >= n4) return;
    float4 v = reinterpret_cast<const float4*>(in)[i];
    uint2 pk;
    pk.x = (unsigned)f2b(v.x) | ((unsigned)f2b(v.y) << 16);
    pk.y = (unsigned)f2b(v.z) | ((unsigned)f2b(v.w) << 16);
    reinterpret_cast<uint2*>(out)[i] = pk;
}

// ---------------------------------------------------------------------------

extern "C" void kernel_launch(void* const* d_in, const int* in_sizes, int n_in,
                              void* d_out, int out_size, void* d_ws, size_t ws_size,
                              hipStream_t stream)
{
    const int*   program = (const int*)d_in[0];
    const int*   adj     = (const int*)d_in[1];
    const float* img     = (const float*)d_in[2];
    const float* embed   = (const float*)d_in[3];
    const float* W_in    = (const float*)d_in[4];
    const float* b_in    = (const float*)d_in[5];
    const float* ln1_g   = (const float*)d_in[6];
    const float* ln1_b   = (const float*)d_in[7];
    const float* ln2_g   = (const float*)d_in[8];
    const float* ln2_b   = (const float*)d_in[9];
    const float* Wq      = (const float*)d_in[10];
    const float* bq      = (const float*)d_in[11];
    const float* Wk      = (const float*)d_in[12];
    const float* bk      = (const float*)d_in[13];
    const float* Wv      = (const float*)d_in[14];
    const float* bv      = (const float*)d_in[15];
    const float* Wo      = (const float*)d_in[16];
    const float* bo      = (const float*)d_in[17];
    const float* fW1     = (const float*)d_in[18];
    const float* fb1     = (const float*)d_in[19];
    const float* fW2     = (const float*)d_in[20];
    const float* fb2     = (const float*)d_in[21];
    const float* cWq     = (const float*)d_in[22];
    const float* cbq     = (const float*)d_in[23];
    const float* cWk     = (const float*)d_in[24];
    const float* cbk     = (const float*)d_in[25];
    const float* cWv     = (const float*)d_in[26];
    const float* cbv     = (const float*)d_in[27];
    const float* cWo     = (const float*)d_in[28];
    const float* cbo     = (const float*)d_in[29];

    char* wsb = (char*)d_ws;
    const size_t MB = 1024 * 1024;
    const long Mi = 1048576;
    const long LSTR = 8 * Mi + Mi / 2;           // 8.5 Mi elements per layer

    float* x    = (float*)(wsb + 0);             // 4096x512 f32      (8 MB)
    u16*   h    = (u16*)(wsb + 8 * MB);          // 4096x512 bf16     (4 MB)
    u16*   xb   = (u16*)(wsb + 12 * MB);         // 4096x512 bf16     (4 MB)
    u16*   imgb = (u16*)(wsb + 16 * MB);         // 4096x512 bf16     (4 MB)
    u16*   WinT = (u16*)(wsb + 20 * MB);         // 512x2400 bf16     (2.4 MB)
    u16*   Kb   = (u16*)(wsb + 24 * MB);         // 4096x2048 bf16    (16 MB)
    u16*   Vt   = (u16*)(wsb + 40 * MB);         // [128][256][256]   (16 MB)
    u16*   O    = (u16*)(wsb + 56 * MB);         // 4096x2048 bf16    (16 MB)
    u16*   Wall = (u16*)(wsb + 72 * MB);         // transposed weights
    u16*   Ag   = Kb;  // gather buffer 19.7 MB (Kb+Vt head, both dead)
    u16*   g    = Kb;  // FFN mid aliases Kb (dead during FFN)

    // big ws: all 6 layers' weights transposed upfront (102 MB at +72)
    const bool bigws = ws_size >= (size_t)175 * MB;

    // prologue
    gather_kernel<<<19200, 256, 0, stream>>>(program, embed, (unsigned*)Ag, 4915200);
    transpose_kernel<<<dim3(8, 38, 1), 256, 0, stream>>>(
        W_in, nullptr, nullptr, nullptr, nullptr, nullptr,
        1, 0, 2400, 512, WinT, 0, 0);
    cvt_kernel<<<2048, 256, 0, stream>>>(img, imgb, 524288);
    if (bigws) {
        transpose_kernel<<<dim3(32, 8, 36), 256, 0, stream>>>(
            Wq, Wk, Wv, cWq, cWk, cWv, 6, Mi, 512, 2048, Wall, Mi, LSTR);
        transpose_kernel<<<dim3(8, 32, 12), 256, 0, stream>>>(
            Wo, cWo, nullptr, nullptr, nullptr, nullptr,
            2, Mi, 2048, 512, Wall + 6 * Mi, Mi, LSTR);
        transpose_kernel<<<dim3(8, 8, 12), 256, 0, stream>>>(
            fW1, fW2, nullptr, nullptr, nullptr, nullptr,
            2, 262144, 512, 512, Wall + 8 * Mi, 262144, LSTR);
    }
    gemm_bf16<64, 64, EPI_F32><<<dim3(8, 64, 1), 256, 0, stream>>>(
        Ag, 0, 2400, WinT, 0, 2400, 4096, 512, 2400,
        b_in, nullptr, nullptr,
        x, nullptr, nullptr, 512);

    for (int l = 0; l < 6; l++) {
        u16* Wl = Wall + (bigws ? (size_t)l * LSTR : 0);
        if (!bigws) {
            transpose_kernel<<<dim3(32, 8, 6), 256, 0, stream>>>(
                Wq + (size_t)l * Mi, Wk + (size_t)l * Mi, Wv + (size_t)l * Mi,
                cWq + (size_t)l * Mi, cWk + (size_t)l * Mi, cWv + (size_t)l * Mi,
                6, 0, 512, 2048, Wl, Mi, 0);
            transpose_kernel<<<dim3(8, 32, 2), 256, 0, stream>>>(
                Wo + (size_t)l * Mi, cWo + (size_t)l * Mi,
                nullptr, nullptr, nullptr, nullptr,
                2, 0, 2048, 512, Wl + 6 * Mi, Mi, 0);
            transpose_kernel<<<dim3(8, 8, 2), 256, 0, stream>>>(
                fW1 + (size_t)l * 262144, fW2 + (size_t)l * 262144,
                nullptr, nullptr, nullptr, nullptr,
                2, 0, 512, 512, Wl + 8 * Mi, 262144, 0);
        }

        // --- self-attention (Q fused into attn; KV-only GEMM) ---
        ln_kernel<<<1024, 256, 0, stream>>>(x, ln1_g + l * 512, ln1_b + l * 512, h);
        gemm_bf16<128, 128, EPI_KV><<<dim3(32, 32, 1), 256, 0, stream>>>(
            h, 0, 512, Wl + 1 * Mi, 0, 512, 4096, 4096, 512,
            bk + l * 2048, bv + l * 2048, nullptr,
            nullptr, Kb, Vt, 2048);
        attn_kernel<true><<<dim3(4, 128), 256, 0, stream>>>(
            h, Wl, bq + l * 2048, Kb, Vt, adj, O);
        gemm_bf16<64, 64, EPI_ATOMIC><<<dim3(8, 64, 4), 256, 0, stream>>>(
            O, 512, 2048, Wl + 6 * Mi, 512, 2048, 4096, 512, 512,
            bo + l * 512, nullptr, nullptr,
            x, nullptr, nullptr, 512);

        // --- FFN ---
        ln_kernel<<<1024, 256, 0, stream>>>(x, ln2_g + l * 512, ln2_b + l * 512, h);
        gemm_bf16<64, 64, EPI_GELU><<<dim3(8, 64, 1), 256, 0, stream>>>(
            h, 0, 512, Wl + 8 * Mi, 0, 512, 4096, 512, 512,
            fb1 + l * 512, nullptr, nullptr,
            nullptr, g, nullptr, 512);
        gemm_bf16<64, 64, EPI_RESID_XB><<<dim3(8, 64, 1), 256, 0, stream>>>(
            g, 0, 512, Wl + 8 * Mi + 262144, 0, 512, 4096, 512, 512,
            fb2 + l * 512, nullptr, x,
            x, xb, nullptr, 512);

        // --- cross-attention (Q fused; query source = xb, no mask) ---
        gemm_bf16<128, 128, EPI_KV><<<dim3(32, 32, 1), 256, 0, stream>>>(
            imgb, 0, 512, Wl + 4 * Mi, 0, 512, 4096, 4096, 512,
            cbk + l * 2048, cbv + l * 2048, nullptr,
            nullptr, Kb, Vt, 2048);
        attn_kernel<false><<<dim3(4, 128), 256, 0, stream>>>(
            xb, Wl + 3 * Mi, cbq + l * 2048, Kb, Vt, nullptr, O);
        gemm_bf16<64, 64, EPI_ATOMIC><<<dim3(8, 64, 4), 256, 0, stream>>>(
            O, 512, 2048, Wl + 7 * Mi, 512, 2048, 4096, 512, 512,
            cbo + l * 512, nullptr, nullptr,
            x, nullptr, nullptr, 512);
    }

    hipMemcpyAsync(d_out, x, (size_t)2097152 * sizeof(float),
                   hipMemcpyDeviceToDevice, stream);
}

// Round 7
// 1789.763 us; speedup vs baseline: 7.0105x; 1.0631x over previous
//
#include <hip/hip_runtime.h>
#include <hip/hip_bf16.h>

typedef __attribute__((ext_vector_type(8))) short short8;
typedef __attribute__((ext_vector_type(4))) float f32x4;
typedef unsigned short u16;

__device__ __forceinline__ u16 f2b(float f) {
    unsigned int u = __builtin_bit_cast(unsigned int, f);
    u = u + 0x7fffu + ((u >> 16) & 1u);
    return (u16)(u >> 16);
}

// epilogue modes (template parameter)
#define EPI_F32      0   // outF = acc + bias0
#define EPI_RESID_XB 3   // outF = acc+bias0+Rsd, outB = bf16(same)
#define EPI_GELU     4   // outB = bf16(gelu(acc + bias0))
#define EPI_KV       7   // 2-way split: K(outB), V-transposed(outV)
#define EPI_ATOMIC   9   // atomicAdd(outF, acc) (+bias0 when bz==0), split-K

// ---------------------------------------------------------------------------
// bf16 MFMA GEMM: C = A(M,K) @ Bt(N,K)^T, f32 accumulate, fused epilogue EPI.
// BM x BN tile, BK in {32,64}, 256 threads, 16x16x32 bf16 MFMA.
// 2-phase double-buffered K-loop with global_load_lds width=16.
// LDS linear; XOR-swizzle applied to per-lane GLOBAL source:
//   BK=32: 16B-group g ^ ((row>>1)&3)
//   BK=64: additionally k-half hh ^ (row&1)  (keeps ds_read banks = BK=32 case)
// For EPI_ATOMIC, blockIdx.z is the K-slice (offset bz*aStride / bz*bStride).
// ---------------------------------------------------------------------------
template<int BM, int BN, int BK, int EPI>
__global__ __launch_bounds__(256, 2) void gemm_bf16(
    const u16* __restrict__ A, long aStride, int lda,
    const u16* __restrict__ B, long bStride, int ldb,
    int M, int N, int K,
    const float* __restrict__ bias0, const float* __restrict__ bias1,
    const float* __restrict__ Rsd,
    float* __restrict__ outF, u16* __restrict__ outB,
    u16* __restrict__ outV, int ldc)
{
    constexpr int WCOLS = BN / 64;           // waves along N
    constexpr int WROWS = 4 / WCOLS;         // waves along M
    constexpr int WM = BM / WROWS;           // rows per wave
    constexpr int MF = WM / 16;
    constexpr int NF = 4;                    // 64 cols per wave
    constexpr int GR = BK / 8;               // 16B units per row
    constexpr int AUNITS = BM * GR;
    constexpr int UPT = (BM + BN) * GR / 256;
    constexpr int BUFE = (BM + BN) * BK;     // u16 per LDS buffer

    __shared__ __align__(16) u16 smem[2 * BUFE];

    const int tid = threadIdx.x;
    const int wave = tid >> 6, lane = tid & 63;
    const int wm = wave / WCOLS, wn = wave % WCOLS;
    const int tm = blockIdx.y * BM, tn = blockIdx.x * BN;
    const int bz = blockIdx.z;

    const size_t aOff = (size_t)bz * (size_t)aStride;
    const size_t bOff = (size_t)bz * (size_t)bStride;

    const int lr = lane & 15, kg = lane >> 4;

    auto stage = [&](int buf, int k0) {
#pragma unroll
        for (int i = 0; i < UPT; i++) {
            int u = tid + i * 256;
            u16* dst = smem + buf * BUFE + u * 8;
            bool isA = u < AUNITS;
            int v = isA ? u : u - AUNITS;
            int row, kloc;
            if constexpr (BK == 64) {
                row = v >> 3;
                int hh = (v >> 2) & 1, g = v & 3;
                kloc = ((hh ^ (row & 1)) << 5) + ((g ^ ((row >> 1) & 3)) << 3);
            } else {
                row = v >> 2;
                int g = v & 3;
                kloc = (g ^ ((row >> 1) & 3)) << 3;
            }
            const u16* src = isA
                ? A + aOff + (size_t)(tm + row) * lda + k0 + kloc
                : B + bOff + (size_t)(tn + row) * ldb + k0 + kloc;
            __builtin_amdgcn_global_load_lds(src, dst, 16, 0, 0);
        }
    };

    auto ldsOff = [&](int row, int kk) -> int {
        if constexpr (BK == 64)
            return row * 64 + (((kk ^ (row & 1)) * 4 + (kg ^ ((row >> 1) & 3))) * 8);
        else
            return row * 32 + ((kg ^ ((row >> 1) & 3)) * 8);
    };

    f32x4 acc[MF][NF];
#pragma unroll
    for (int m = 0; m < MF; m++)
#pragma unroll
        for (int n = 0; n < NF; n++) acc[m][n] = (f32x4)(0.f);

    const int NT = K / BK;
    stage(0, 0);
    __syncthreads();

    for (int t = 0; t < NT; t++) {
        const int cur = t & 1;
        if (t + 1 < NT) stage(cur ^ 1, (t + 1) * BK);

        const u16* As = smem + cur * BUFE;
        const u16* Bs = As + BM * BK;
#pragma unroll
        for (int kk = 0; kk < BK / 32; kk++) {
            short8 af[MF], bfr[NF];
#pragma unroll
            for (int m = 0; m < MF; m++) {
                int row = wm * WM + m * 16 + lr;
                af[m] = *(const short8*)&As[ldsOff(row, kk)];
            }
#pragma unroll
            for (int n = 0; n < NF; n++) {
                int row = wn * 64 + n * 16 + lr;
                bfr[n] = *(const short8*)&Bs[ldsOff(row, kk)];
            }
#pragma unroll
            for (int m = 0; m < MF; m++)
#pragma unroll
                for (int n = 0; n < NF; n++)
                    acc[m][n] = __builtin_amdgcn_mfma_f32_16x16x32_bf16(
                        af[m], bfr[n], acc[m][n], 0, 0, 0);
        }
        __syncthreads();   // drains prefetch (vmcnt 0) + joins waves
    }

    // epilogue: D row=(lane>>4)*4+e, col=lane&15
#pragma unroll
    for (int m = 0; m < MF; m++) {
#pragma unroll
        for (int n = 0; n < NF; n++) {
#pragma unroll
            for (int e = 0; e < 4; e++) {
                int r = tm + wm * WM + m * 16 + (lane >> 4) * 4 + e;
                int c = tn + wn * 64 + n * 16 + (lane & 15);
                float v = acc[m][n][e];
                if constexpr (EPI == EPI_F32) {
                    outF[(size_t)r * ldc + c] = v + bias0[c];
                } else if constexpr (EPI == EPI_RESID_XB) {
                    float t = v + bias0[c] + Rsd[(size_t)r * ldc + c];
                    outF[(size_t)r * ldc + c] = t;
                    outB[(size_t)r * ldc + c] = f2b(t);
                } else if constexpr (EPI == EPI_GELU) {
                    float t = v + bias0[c];
                    t = 0.5f * t * (1.f + erff(t * 0.70710678118654752f));
                    outB[(size_t)r * ldc + c] = f2b(t);
                } else if constexpr (EPI == EPI_KV) {
                    int sel = c >> 11, cc = c & 2047;
                    float t = v + (sel == 0 ? bias0 : bias1)[cc];
                    if (sel == 0)
                        outB[(size_t)r * 2048 + cc] = f2b(t);
                    else
                        outV[(size_t)((r >> 8) * 8 + (cc >> 8)) * 65536 +
                             (size_t)(cc & 255) * 256 + (r & 255)] = f2b(t);
                } else if constexpr (EPI == EPI_ATOMIC) {
                    float t = v;
                    if (bz == 0) t += bias0[c];
                    atomicAdd(&outF[(size_t)r * ldc + c], t);
                }
            }
        }
    }
}

// ---------------------------------------------------------------------------
// Fused attention with Q-projection:
// per (b,h) and 64-row q-tile:
//   Q = Aq[rows][512] @ WqT[h*256..+256][512]^T + bq_h     (phase 0)
//   O = softmax1(Q K^T / 16 + mask) V                      (phases 1-4)
// Aq: bf16 [4096][512]. K: [4096][2048]. Vt: [bh][256 d][256 tok].
// All streamed double-buffered via global_load_lds.
// ---------------------------------------------------------------------------
template<bool MASKED>
__global__ __launch_bounds__(256, 2) void attn_kernel(
    const u16* __restrict__ Aq, const u16* __restrict__ WqT,
    const float* __restrict__ bq,
    const u16* __restrict__ K, const u16* __restrict__ Vt,
    const int* __restrict__ adj, u16* __restrict__ O)
{
    __shared__ __align__(16) u16 Ps[64 * 256];       // Q tile then P tile (32 KB)
    __shared__ __align__(16) u16 Ks[2 * 256 * 32];   // B double buffer (32 KB)
    __shared__ __align__(16) u16 Aql[2 * 64 * 32];   // phase-0 A dbuf (8 KB)
    __shared__ float red1[64 * 4];
    __shared__ float red2[64 * 4];

    const int tid = threadIdx.x;
    const int w = tid >> 6, lane = tid & 63;
    const int lr = lane & 15, kg = lane >> 4;
    const int qt = blockIdx.x, bh = blockIdx.y;
    const int b = bh >> 3, h = bh & 7;
    const size_t qkBase = (size_t)b * 256 * 2048 + h * 256;

    auto stageA0 = [&](int buf, int k0) {
        int u = tid;                       // 256 units exactly
        int row = u >> 2, g = u & 3;
        int gs = g ^ ((row >> 1) & 3);
        const u16* src = Aq + (size_t)(b * 256 + qt * 64 + row) * 512 + k0 + gs * 8;
        __builtin_amdgcn_global_load_lds(src, Aql + buf * 2048 + u * 8, 16, 0, 0);
    };
    auto stageB0 = [&](int buf, int k0) {
#pragma unroll
        for (int i = 0; i < 4; i++) {
            int u = tid + i * 256;
            int row = u >> 2, g = u & 3;
            int gs = g ^ ((row >> 1) & 3);
            const u16* src = WqT + (size_t)(h * 256 + row) * 512 + k0 + gs * 8;
            __builtin_amdgcn_global_load_lds(src, Ks + buf * 8192 + u * 8, 16, 0, 0);
        }
    };
    auto stageK = [&](int buf, int dk) {
#pragma unroll
        for (int i = 0; i < 4; i++) {
            int u = tid + i * 256;
            int row = u >> 2, g = u & 3;
            int gs = g ^ ((row >> 1) & 3);
            const u16* src = K + qkBase + (size_t)row * 2048 + dk * 32 + gs * 8;
            __builtin_amdgcn_global_load_lds(src, Ks + buf * 8192 + u * 8, 16, 0, 0);
        }
    };
    auto stageV = [&](int buf, int kt) {
#pragma unroll
        for (int i = 0; i < 4; i++) {
            int u = tid + i * 256;
            int row = u >> 2, g = u & 3;   // row = d
            int gs = g ^ ((row >> 1) & 3);
            const u16* src = Vt + (size_t)bh * 65536 + (size_t)row * 256 + kt * 32 + gs * 8;
            __builtin_amdgcn_global_load_lds(src, Ks + buf * 8192 + u * 8, 16, 0, 0);
        }
    };

    // ---- phase 0: Q = Aq @ WqT_head + bq  (K=512, 16 steps of 32) ----
    {
        f32x4 qacc[4][4];
#pragma unroll
        for (int m = 0; m < 4; m++)
#pragma unroll
            for (int n = 0; n < 4; n++) qacc[m][n] = (f32x4)(0.f);

        stageA0(0, 0);
        stageB0(0, 0);
        __syncthreads();
        for (int t = 0; t < 16; t++) {
            const int cur = t & 1;
            if (t < 15) { stageA0(cur ^ 1, (t + 1) * 32); stageB0(cur ^ 1, (t + 1) * 32); }
            short8 af[4], bfr[4];
#pragma unroll
            for (int m = 0; m < 4; m++) {
                int row = m * 16 + lr;
                af[m] = *(const short8*)&Aql[cur * 2048 + row * 32 + ((kg ^ ((row >> 1) & 3)) * 8)];
            }
#pragma unroll
            for (int n = 0; n < 4; n++) {
                int row = w * 64 + n * 16 + lr;
                bfr[n] = *(const short8*)&Ks[cur * 8192 + row * 32 + ((kg ^ ((row >> 1) & 3)) * 8)];
            }
#pragma unroll
            for (int m = 0; m < 4; m++)
#pragma unroll
                for (int n = 0; n < 4; n++)
                    qacc[m][n] = __builtin_amdgcn_mfma_f32_16x16x32_bf16(
                        af[m], bfr[n], qacc[m][n], 0, 0, 0);
            __syncthreads();
        }
        // write Q tile to Ps (bf16, swizzled for phase-1 A reads)
#pragma unroll
        for (int m = 0; m < 4; m++)
#pragma unroll
            for (int n = 0; n < 4; n++)
#pragma unroll
                for (int e = 0; e < 4; e++) {
                    int q = m * 16 + kg * 4 + e;
                    int d = w * 64 + n * 16 + lr;
                    float t = qacc[m][n][e] + bq[h * 256 + d];
                    Ps[q * 256 + (((d >> 3) ^ (q & 7)) * 8) + (d & 7)] = f2b(t);
                }
    }
    __syncthreads();

    f32x4 sacc[4][4];
#pragma unroll
    for (int m = 0; m < 4; m++)
#pragma unroll
        for (int n = 0; n < 4; n++) sacc[m][n] = (f32x4)(0.f);

    // ---- phase 1: S = Q K^T (contraction over d, 8 steps of 32) ----
    stageK(0, 0);
    __syncthreads();
    for (int dk = 0; dk < 8; dk++) {
        const int cur = dk & 1;
        if (dk < 7) stageK(cur ^ 1, dk + 1);
        short8 af[4], bfr[4];
#pragma unroll
        for (int m = 0; m < 4; m++) {
            int row = m * 16 + lr;
            af[m] = *(const short8*)&Ps[row * 256 + (((dk * 4 + kg) ^ (row & 7)) * 8)];
        }
#pragma unroll
        for (int n = 0; n < 4; n++) {
            int row = w * 64 + n * 16 + lr;
            bfr[n] = *(const short8*)&Ks[cur * 8192 + row * 32 + ((kg ^ ((row >> 1) & 3)) * 8)];
        }
#pragma unroll
        for (int m = 0; m < 4; m++)
#pragma unroll
            for (int n = 0; n < 4; n++)
                sacc[m][n] = __builtin_amdgcn_mfma_f32_16x16x32_bf16(
                    af[m], bfr[n], sacc[m][n], 0, 0, 0);
        __syncthreads();
    }

    // prefetch V tile 0 into Ks buf0 (overlaps softmax)
    stageV(0, 0);

    // ---- phase 2: scale + mask + softmax(+1 denom) ----
#pragma unroll
    for (int m = 0; m < 4; m++)
#pragma unroll
        for (int n = 0; n < 4; n++)
#pragma unroll
            for (int e = 0; e < 4; e++) {
                float t = sacc[m][n][e] * 0.0625f;
                if (MASKED) {
                    int q = qt * 64 + m * 16 + kg * 4 + e;
                    int k = w * 64 + n * 16 + lr;
                    int a_ = adj[((size_t)b * 256 + q) * 256 + k];
                    t += (1.f - (float)a_) * -1.0e6f;
                }
                sacc[m][n][e] = t;
            }

    float mx[4][4];
#pragma unroll
    for (int m = 0; m < 4; m++)
#pragma unroll
        for (int e = 0; e < 4; e++) {
            float v = sacc[m][0][e];
#pragma unroll
            for (int n = 1; n < 4; n++) v = fmaxf(v, sacc[m][n][e]);
#pragma unroll
            for (int off = 1; off < 16; off <<= 1) v = fmaxf(v, __shfl_xor(v, off));
            mx[m][e] = v;
        }
    if (lr == 0) {
#pragma unroll
        for (int m = 0; m < 4; m++)
#pragma unroll
            for (int e = 0; e < 4; e++)
                red1[(m * 16 + kg * 4 + e) * 4 + w] = mx[m][e];
    }
    __syncthreads();

    float inv[4][4];
    float sum[4][4];
#pragma unroll
    for (int m = 0; m < 4; m++)
#pragma unroll
        for (int e = 0; e < 4; e++) {
            int r = m * 16 + kg * 4 + e;
            float gm = fmaxf(fmaxf(red1[r * 4 + 0], red1[r * 4 + 1]),
                             fmaxf(red1[r * 4 + 2], red1[r * 4 + 3]));
            float s = 0.f;
#pragma unroll
            for (int n = 0; n < 4; n++) {
                float ev = __expf(sacc[m][n][e] - gm);
                sacc[m][n][e] = ev;
                s += ev;
            }
            sum[m][e] = s;
        }
#pragma unroll
    for (int m = 0; m < 4; m++)
#pragma unroll
        for (int e = 0; e < 4; e++) {
            float s = sum[m][e];
#pragma unroll
            for (int off = 1; off < 16; off <<= 1) s += __shfl_xor(s, off);
            sum[m][e] = s;
        }
    if (lr == 0) {
#pragma unroll
        for (int m = 0; m < 4; m++)
#pragma unroll
            for (int e = 0; e < 4; e++)
                red2[(m * 16 + kg * 4 + e) * 4 + w] = sum[m][e];
    }
    __syncthreads();
#pragma unroll
    for (int m = 0; m < 4; m++)
#pragma unroll
        for (int e = 0; e < 4; e++) {
            int r = m * 16 + kg * 4 + e;
            float gs = red2[r * 4 + 0] + red2[r * 4 + 1] +
                       red2[r * 4 + 2] + red2[r * 4 + 3];
            inv[m][e] = 1.f / (1.f + gs);
        }

    // ---- phase 3: P -> LDS (bf16, overwrites Q tile) ----
#pragma unroll
    for (int m = 0; m < 4; m++)
#pragma unroll
        for (int n = 0; n < 4; n++)
#pragma unroll
            for (int e = 0; e < 4; e++) {
                int q = m * 16 + kg * 4 + e;
                int k = w * 64 + n * 16 + lr;
                float pv = sacc[m][n][e] * inv[m][e];
                Ps[q * 256 + (((k >> 3) ^ (q & 7)) * 8) + (k & 7)] = f2b(pv);
            }
    __syncthreads();   // P visible; V tile 0 drained

    // ---- phase 4: O = P V (contraction over k, 8 steps of 32) ----
    f32x4 oacc[4][4];
#pragma unroll
    for (int m = 0; m < 4; m++)
#pragma unroll
        for (int n = 0; n < 4; n++) oacc[m][n] = (f32x4)(0.f);

    for (int kt = 0; kt < 8; kt++) {
        const int cur = kt & 1;
        if (kt < 7) stageV(cur ^ 1, kt + 1);
        short8 af[4], bfr[4];
#pragma unroll
        for (int m = 0; m < 4; m++) {
            int q = m * 16 + lr;
            af[m] = *(const short8*)&Ps[q * 256 + (((kt * 4 + kg) ^ (q & 7)) * 8)];
        }
#pragma unroll
        for (int n = 0; n < 4; n++) {
            int row = w * 64 + n * 16 + lr;
            bfr[n] = *(const short8*)&Ks[cur * 8192 + row * 32 + ((kg ^ ((row >> 1) & 3)) * 8)];
        }
#pragma unroll
        for (int m = 0; m < 4; m++)
#pragma unroll
            for (int n = 0; n < 4; n++)
                oacc[m][n] = __builtin_amdgcn_mfma_f32_16x16x32_bf16(
                    af[m], bfr[n], oacc[m][n], 0, 0, 0);
        __syncthreads();
    }

    // ---- epilogue: O[tok][h*256+d] ----
#pragma unroll
    for (int m = 0; m < 4; m++)
#pragma unroll
        for (int n = 0; n < 4; n++)
#pragma unroll
            for (int e = 0; e < 4; e++) {
                int q = qt * 64 + m * 16 + kg * 4 + e;
                int d = w * 64 + n * 16 + lr;
                O[(size_t)(b * 256 + q) * 2048 + h * 256 + d] = f2b(oacc[m][n][e]);
            }
}

// ---------------------------------------------------------------------------
// Transpose+convert: src f32 [R][C] -> dst bf16 [C][R].
// float4 global loads, [64][65] LDS (2-way max bank alias = free),
// uint2 global stores. blockIdx.z = layer*nsrc + mat.
// ---------------------------------------------------------------------------
__global__ __launch_bounds__(256) void transpose_kernel(
    const float* p0, const float* p1, const float* p2,
    const float* p3, const float* p4, const float* p5,
    int nsrc, long srcLayerStride, int R, int C,
    u16* __restrict__ out, long dstMatStride, long dstLayerStride)
{
    const int mat = blockIdx.z % nsrc, layer = blockIdx.z / nsrc;
    const float* W;
    switch (mat) {
    default: W = p0; break;
    case 1: W = p1; break;
    case 2: W = p2; break;
    case 3: W = p3; break;
    case 4: W = p4; break;
    case 5: W = p5; break;
    }
    W += (size_t)layer * srcLayerStride;
    u16* o = out + (size_t)layer * dstLayerStride + (size_t)mat * dstMatStride;
    __shared__ float t[64][65];
    const int tid = threadIdx.x;
    const int rBase = blockIdx.y * 64, cBase = blockIdx.x * 64;
#pragma unroll
    for (int i = 0; i < 4; i++) {
        int idx = tid + i * 256;
        int rr = idx >> 4, cc4 = (idx & 15) * 4;
        if (rBase + rr < R) {
            float4 v = *(const float4*)&W[(size_t)(rBase + rr) * C + cBase + cc4];
            t[rr][cc4] = v.x; t[rr][cc4 + 1] = v.y;
            t[rr][cc4 + 2] = v.z; t[rr][cc4 + 3] = v.w;
        }
    }
    __syncthreads();
#pragma unroll
    for (int i = 0; i < 4; i++) {
        int idx = tid + i * 256;
        int cc = idx >> 4, rr4 = (idx & 15) * 4;
        if (rBase + rr4 < R) {
            uint2 pk;
            pk.x = (unsigned)f2b(t[rr4][cc]) | ((unsigned)f2b(t[rr4 + 1][cc]) << 16);
            pk.y = (unsigned)f2b(t[rr4 + 2][cc]) | ((unsigned)f2b(t[rr4 + 3][cc]) << 16);
            *(uint2*)&o[(size_t)(cBase + cc) * R + rBase + rr4] = pk;
        }
    }
}

// ---------------------------------------------------------------------------
// LayerNorm rows of 512, f32 in -> bf16 out. One wave per row.
// ---------------------------------------------------------------------------
__global__ __launch_bounds__(256) void ln_kernel(
    const float* __restrict__ X, const float* __restrict__ g,
    const float* __restrict__ b, u16* __restrict__ Y)
{
    const int wave = threadIdx.x >> 6, lane = threadIdx.x & 63;
    const size_t row = (size_t)blockIdx.x * 4 + wave;
    const float* xr = X + row * 512;
    float4 v0 = *reinterpret_cast<const float4*>(xr + lane * 8);
    float4 v1 = *reinterpret_cast<const float4*>(xr + lane * 8 + 4);
    float s = v0.x + v0.y + v0.z + v0.w + v1.x + v1.y + v1.z + v1.w;
    float ss = v0.x * v0.x + v0.y * v0.y + v0.z * v0.z + v0.w * v0.w +
               v1.x * v1.x + v1.y * v1.y + v1.z * v1.z + v1.w * v1.w;
#pragma unroll
    for (int off = 32; off; off >>= 1) {
        s += __shfl_xor(s, off);
        ss += __shfl_xor(ss, off);
    }
    float mu = s * (1.0f / 512.0f);
    float var = ss * (1.0f / 512.0f) - mu * mu;
    float rs = rsqrtf(var + 1e-5f);
    float4 g0 = *reinterpret_cast<const float4*>(g + lane * 8);
    float4 g1 = *reinterpret_cast<const float4*>(g + lane * 8 + 4);
    float4 b0 = *reinterpret_cast<const float4*>(b + lane * 8);
    float4 b1 = *reinterpret_cast<const float4*>(b + lane * 8 + 4);
    float o0 = (v0.x - mu) * rs * g0.x + b0.x;
    float o1 = (v0.y - mu) * rs * g0.y + b0.y;
    float o2 = (v0.z - mu) * rs * g0.z + b0.z;
    float o3 = (v0.w - mu) * rs * g0.w + b0.w;
    float o4 = (v1.x - mu) * rs * g1.x + b1.x;
    float o5 = (v1.y - mu) * rs * g1.y + b1.y;
    float o6 = (v1.z - mu) * rs * g1.z + b1.z;
    float o7 = (v1.w - mu) * rs * g1.w + b1.w;
    uint4 pk;
    pk.x = (unsigned)f2b(o0) | ((unsigned)f2b(o1) << 16);
    pk.y = (unsigned)f2b(o2) | ((unsigned)f2b(o3) << 16);
    pk.z = (unsigned)f2b(o4) | ((unsigned)f2b(o5) << 16);
    pk.w = (unsigned)f2b(o6) | ((unsigned)f2b(o7) << 16);
    *reinterpret_cast<uint4*>(Y + row * 512 + lane * 8) = pk;
}

// ---------------------------------------------------------------------------
// Embedding gather -> bf16 (2 elems/thread): Ag[t][j*300+e] = embed[tok][e]
// ---------------------------------------------------------------------------
__global__ __launch_bounds__(256) void gather_kernel(
    const int* __restrict__ program, const float* __restrict__ embed,
    unsigned* __restrict__ Ag2, int total2)
{
    int idx = blockIdx.x * 256 + threadIdx.x;
    if (idx >= total2) return;
    int t = idx / 1200;
    int rem = idx - t * 1200;
    int j = rem / 150;
    int e2 = rem - j * 150;
    int tok = program[t * 8 + j];
    float2 v = *reinterpret_cast<const float2*>(&embed[(size_t)tok * 300 + e2 * 2]);
    Ag2[idx] = (unsigned)f2b(v.x) | ((unsigned)f2b(v.y) << 16);
}

// f32 -> bf16 convert, 4 elems/thread
__global__ __launch_bounds__(256) void cvt_kernel(
    const float* __restrict__ in, u16* __restrict__ out, int n4)
{
    int i = blockIdx.x * 256 + threadIdx.x;
    if (i >= n4) return;
    float4 v = reinterpret_cast<const float4*>(in)[i];
    uint2 pk;
    pk.x = (unsigned)f2b(v.x) | ((unsigned)f2b(v.y) << 16);
    pk.y = (unsigned)f2b(v.z) | ((unsigned)f2b(v.w) << 16);
    reinterpret_cast<uint2*>(out)[i] = pk;
}

// ---------------------------------------------------------------------------

extern "C" void kernel_launch(void* const* d_in, const int* in_sizes, int n_in,
                              void* d_out, int out_size, void* d_ws, size_t ws_size,
                              hipStream_t stream)
{
    const int*   program = (const int*)d_in[0];
    const int*   adj     = (const int*)d_in[1];
    const float* img     = (const float*)d_in[2];
    const float* embed   = (const float*)d_in[3];
    const float* W_in    = (const float*)d_in[4];
    const float* b_in    = (const float*)d_in[5];
    const float* ln1_g   = (const float*)d_in[6];
    const float* ln1_b   = (const float*)d_in[7];
    const float* ln2_g   = (const float*)d_in[8];
    const float* ln2_b   = (const float*)d_in[9];
    const float* Wq      = (const float*)d_in[10];
    const float* bq      = (const float*)d_in[11];
    const float* Wk      = (const float*)d_in[12];
    const float* bk      = (const float*)d_in[13];
    const float* Wv      = (const float*)d_in[14];
    const float* bv      = (const float*)d_in[15];
    const float* Wo      = (const float*)d_in[16];
    const float* bo      = (const float*)d_in[17];
    const float* fW1     = (const float*)d_in[18];
    const float* fb1     = (const float*)d_in[19];
    const float* fW2     = (const float*)d_in[20];
    const float* fb2     = (const float*)d_in[21];
    const float* cWq     = (const float*)d_in[22];
    const float* cbq     = (const float*)d_in[23];
    const float* cWk     = (const float*)d_in[24];
    const float* cbk     = (const float*)d_in[25];
    const float* cWv     = (const float*)d_in[26];
    const float* cbv     = (const float*)d_in[27];
    const float* cWo     = (const float*)d_in[28];
    const float* cbo     = (const float*)d_in[29];

    char* wsb = (char*)d_ws;
    const size_t MB = 1024 * 1024;
    const long Mi = 1048576;
    const long LSTR = 8 * Mi + Mi / 2;           // 8.5 Mi elements per layer

    float* x    = (float*)(wsb + 0);             // 4096x512 f32      (8 MB)
    u16*   h    = (u16*)(wsb + 8 * MB);          // 4096x512 bf16     (4 MB)
    u16*   xb   = (u16*)(wsb + 12 * MB);         // 4096x512 bf16     (4 MB)
    u16*   imgb = (u16*)(wsb + 16 * MB);         // 4096x512 bf16     (4 MB)
    u16*   WinT = (u16*)(wsb + 20 * MB);         // 512x2400 bf16     (2.4 MB)
    u16*   Kb   = (u16*)(wsb + 24 * MB);         // 4096x2048 bf16    (16 MB)
    u16*   Vt   = (u16*)(wsb + 40 * MB);         // [128][256][256]   (16 MB)
    u16*   O    = (u16*)(wsb + 56 * MB);         // 4096x2048 bf16    (16 MB)
    u16*   Wall = (u16*)(wsb + 72 * MB);         // transposed weights
    u16*   Ag   = Kb;  // gather buffer 19.7 MB (Kb+Vt head, both dead)
    u16*   g    = Kb;  // FFN mid aliases Kb (dead during FFN)

    // big ws: all 6 layers' weights transposed upfront (102 MB at +72)
    const bool bigws = ws_size >= (size_t)175 * MB;

    // prologue
    gather_kernel<<<19200, 256, 0, stream>>>(program, embed, (unsigned*)Ag, 4915200);
    transpose_kernel<<<dim3(8, 38, 1), 256, 0, stream>>>(
        W_in, nullptr, nullptr, nullptr, nullptr, nullptr,
        1, 0, 2400, 512, WinT, 0, 0);
    cvt_kernel<<<2048, 256, 0, stream>>>(img, imgb, 524288);
    if (bigws) {
        transpose_kernel<<<dim3(32, 8, 36), 256, 0, stream>>>(
            Wq, Wk, Wv, cWq, cWk, cWv, 6, Mi, 512, 2048, Wall, Mi, LSTR);
        transpose_kernel<<<dim3(8, 32, 12), 256, 0, stream>>>(
            Wo, cWo, nullptr, nullptr, nullptr, nullptr,
            2, Mi, 2048, 512, Wall + 6 * Mi, Mi, LSTR);
        transpose_kernel<<<dim3(8, 8, 12), 256, 0, stream>>>(
            fW1, fW2, nullptr, nullptr, nullptr, nullptr,
            2, 262144, 512, 512, Wall + 8 * Mi, 262144, LSTR);
    }
    gemm_bf16<64, 64, 32, EPI_F32><<<dim3(8, 64, 1), 256, 0, stream>>>(
        Ag, 0, 2400, WinT, 0, 2400, 4096, 512, 2400,
        b_in, nullptr, nullptr,
        x, nullptr, nullptr, 512);

    for (int l = 0; l < 6; l++) {
        u16* Wl = Wall + (bigws ? (size_t)l * LSTR : 0);
        if (!bigws) {
            transpose_kernel<<<dim3(32, 8, 6), 256, 0, stream>>>(
                Wq + (size_t)l * Mi, Wk + (size_t)l * Mi, Wv + (size_t)l * Mi,
                cWq + (size_t)l * Mi, cWk + (size_t)l * Mi, cWv + (size_t)l * Mi,
                6, 0, 512, 2048, Wl, Mi, 0);
            transpose_kernel<<<dim3(8, 32, 2), 256, 0, stream>>>(
                Wo + (size_t)l * Mi, cWo + (size_t)l * Mi,
                nullptr, nullptr, nullptr, nullptr,
                2, 0, 2048, 512, Wl + 6 * Mi, Mi, 0);
            transpose_kernel<<<dim3(8, 8, 2), 256, 0, stream>>>(
                fW1 + (size_t)l * 262144, fW2 + (size_t)l * 262144,
                nullptr, nullptr, nullptr, nullptr,
                2, 0, 512, 512, Wl + 8 * Mi, 262144, 0);
        }

        // --- self-attention (Q fused into attn; KV-only GEMM) ---
        ln_kernel<<<1024, 256, 0, stream>>>(x, ln1_g + l * 512, ln1_b + l * 512, h);
        gemm_bf16<128, 128, 64, EPI_KV><<<dim3(32, 32, 1), 256, 0, stream>>>(
            h, 0, 512, Wl + 1 * Mi, 0, 512, 4096, 4096, 512,
            bk + l * 2048, bv + l * 2048, nullptr,
            nullptr, Kb, Vt, 2048);
        attn_kernel<true><<<dim3(4, 128), 256, 0, stream>>>(
            h, Wl, bq + l * 2048, Kb, Vt, adj, O);
        gemm_bf16<64, 64, 64, EPI_ATOMIC><<<dim3(8, 64, 4), 256, 0, stream>>>(
            O, 512, 2048, Wl + 6 * Mi, 512, 2048, 4096, 512, 512,
            bo + l * 512, nullptr, nullptr,
            x, nullptr, nullptr, 512);

        // --- FFN ---
        ln_kernel<<<1024, 256, 0, stream>>>(x, ln2_g + l * 512, ln2_b + l * 512, h);
        gemm_bf16<64, 64, 64, EPI_GELU><<<dim3(8, 64, 1), 256, 0, stream>>>(
            h, 0, 512, Wl + 8 * Mi, 0, 512, 4096, 512, 512,
            fb1 + l * 512, nullptr, nullptr,
            nullptr, g, nullptr, 512);
        gemm_bf16<64, 64, 64, EPI_RESID_XB><<<dim3(8, 64, 1), 256, 0, stream>>>(
            g, 0, 512, Wl + 8 * Mi + 262144, 0, 512, 4096, 512, 512,
            fb2 + l * 512, nullptr, x,
            x, xb, nullptr, 512);

        // --- cross-attention (Q fused; query source = xb, no mask) ---
        gemm_bf16<128, 128, 64, EPI_KV><<<dim3(32, 32, 1), 256, 0, stream>>>(
            imgb, 0, 512, Wl + 4 * Mi, 0, 512, 4096, 4096, 512,
            cbk + l * 2048, cbv + l * 2048, nullptr,
            nullptr, Kb, Vt, 2048);
        attn_kernel<false><<<dim3(4, 128), 256, 0, stream>>>(
            xb, Wl + 3 * Mi, cbq + l * 2048, Kb, Vt, nullptr, O);
        gemm_bf16<64, 64, 64, EPI_ATOMIC><<<dim3(8, 64, 4), 256, 0, stream>>>(
            O, 512, 2048, Wl + 7 * Mi, 512, 2048, 4096, 512, 512,
            cbo + l * 512, nullptr, nullptr,
            x, nullptr, nullptr, 512);
    }

    hipMemcpyAsync(d_out, x, (size_t)2097152 * sizeof(float),
                   hipMemcpyDeviceToDevice, stream);
}

// Round 8
// 1350.832 us; speedup vs baseline: 9.2884x; 1.3249x over previous
//
#include <hip/hip_runtime.h>
#include <hip/hip_bf16.h>

typedef __attribute__((ext_vector_type(8))) short short8;
typedef __attribute__((ext_vector_type(4))) float f32x4;
typedef unsigned short u16;

__device__ __forceinline__ u16 f2b(float f) {
    unsigned int u = __builtin_bit_cast(unsigned int, f);
    u = u + 0x7fffu + ((u >> 16) & 1u);
    return (u16)(u >> 16);
}

// epilogue modes (template parameter)
#define EPI_F32      0   // outF = acc + bias0
#define EPI_RESID_XB 3   // outF = acc+bias0+Rsd, outB = bf16(same)
#define EPI_GELU     4   // outB = bf16(gelu(acc + bias0))
#define EPI_KV       7   // 2-way split: K(outB), V-transposed(outV); batched by bz
#define EPI_ATOMIC   9   // atomicAdd(outF, acc) (+bias0 when bz==0), split-K

// ---------------------------------------------------------------------------
// bf16 MFMA GEMM: C = A(M,K) @ Bt(N,K)^T, f32 accumulate, fused epilogue EPI.
// BM x BN tile, BK in {32,64}, 256 threads, 16x16x32 bf16 MFMA.
// 2-phase double-buffered K-loop, global_load_lds width=16, source-side
// XOR swizzle. XCD-aware bijective block swizzle on (x,y) (requires
// gridDim.x*gridDim.y % 8 == 0 -- true for all launches here).
// EPI_KV: bz = batch (layer) using b/bias/out strides; V-half written via
// LDS transpose for coalesced stores (block is uniformly K-half or V-half).
// EPI_ATOMIC: bz = K-slice via aStride/bStride.
// ---------------------------------------------------------------------------
template<int BM, int BN, int BK, int EPI>
__global__ __launch_bounds__(256, 2) void gemm_bf16(
    const u16* __restrict__ A, long aStride, int lda,
    const u16* __restrict__ B, long bStride, int ldb,
    int M, int N, int K,
    const float* __restrict__ bias0, const float* __restrict__ bias1,
    int biasStride,
    const float* __restrict__ Rsd,
    float* __restrict__ outF, u16* __restrict__ outB,
    u16* __restrict__ outV, long outStride, int ldc)
{
    constexpr int WCOLS = BN / 64;           // waves along N
    constexpr int WROWS = 4 / WCOLS;         // waves along M
    constexpr int WM = BM / WROWS;           // rows per wave
    constexpr int MF = WM / 16;
    constexpr int NF = 4;                    // 64 cols per wave
    constexpr int GR = BK / 8;               // 16B units per row
    constexpr int AUNITS = BM * GR;
    constexpr int UPT = (BM + BN) * GR / 256;
    constexpr int BUFE = (BM + BN) * BK;     // u16 per LDS buffer

    __shared__ __align__(16) u16 smem[2 * BUFE];

    const int tid = threadIdx.x;
    const int wave = tid >> 6, lane = tid & 63;
    const int wm = wave / WCOLS, wn = wave % WCOLS;

    // XCD-aware bijective swizzle (chunked): same-y blocks colocate per XCD
    const int nwg = gridDim.x * gridDim.y;
    const int bl = blockIdx.y * gridDim.x + blockIdx.x;
    const int wsw = (bl & 7) * (nwg >> 3) + (bl >> 3);
    const int bxs = wsw % gridDim.x, bys = wsw / gridDim.x;

    const int tm = bys * BM, tn = bxs * BN;
    const int bz = blockIdx.z;

    const size_t aOff = (size_t)bz * (size_t)aStride;
    const size_t bOff = (size_t)bz * (size_t)bStride;

    const int lr = lane & 15, kg = lane >> 4;

    auto stage = [&](int buf, int k0) {
#pragma unroll
        for (int i = 0; i < UPT; i++) {
            int u = tid + i * 256;
            u16* dst = smem + buf * BUFE + u * 8;
            bool isA = u < AUNITS;
            int v = isA ? u : u - AUNITS;
            int row, kloc;
            if constexpr (BK == 64) {
                row = v >> 3;
                int hh = (v >> 2) & 1, g = v & 3;
                kloc = ((hh ^ (row & 1)) << 5) + ((g ^ ((row >> 1) & 3)) << 3);
            } else {
                row = v >> 2;
                int g = v & 3;
                kloc = (g ^ ((row >> 1) & 3)) << 3;
            }
            const u16* src = isA
                ? A + aOff + (size_t)(tm + row) * lda + k0 + kloc
                : B + bOff + (size_t)(tn + row) * ldb + k0 + kloc;
            __builtin_amdgcn_global_load_lds(src, dst, 16, 0, 0);
        }
    };

    auto ldsOff = [&](int row, int kk) -> int {
        if constexpr (BK == 64)
            return row * 64 + (((kk ^ (row & 1)) * 4 + (kg ^ ((row >> 1) & 3))) * 8);
        else
            return row * 32 + ((kg ^ ((row >> 1) & 3)) * 8);
    };

    f32x4 acc[MF][NF];
#pragma unroll
    for (int m = 0; m < MF; m++)
#pragma unroll
        for (int n = 0; n < NF; n++) acc[m][n] = (f32x4)(0.f);

    const int NT = K / BK;
    stage(0, 0);
    __syncthreads();

    for (int t = 0; t < NT; t++) {
        const int cur = t & 1;
        if (t + 1 < NT) stage(cur ^ 1, (t + 1) * BK);

        const u16* As = smem + cur * BUFE;
        const u16* Bs = As + BM * BK;
#pragma unroll
        for (int kk = 0; kk < BK / 32; kk++) {
            short8 af[MF], bfr[NF];
#pragma unroll
            for (int m = 0; m < MF; m++) {
                int row = wm * WM + m * 16 + lr;
                af[m] = *(const short8*)&As[ldsOff(row, kk)];
            }
#pragma unroll
            for (int n = 0; n < NF; n++) {
                int row = wn * 64 + n * 16 + lr;
                bfr[n] = *(const short8*)&Bs[ldsOff(row, kk)];
            }
#pragma unroll
            for (int m = 0; m < MF; m++)
#pragma unroll
                for (int n = 0; n < NF; n++)
                    acc[m][n] = __builtin_amdgcn_mfma_f32_16x16x32_bf16(
                        af[m], bfr[n], acc[m][n], 0, 0, 0);
        }
        __syncthreads();   // drains prefetch (vmcnt 0) + joins waves
    }

    if constexpr (EPI == EPI_KV) {
        if (tn < 2048) {
            // ---- K half: coalesced direct stores ----
#pragma unroll
            for (int m = 0; m < MF; m++)
#pragma unroll
                for (int n = 0; n < NF; n++)
#pragma unroll
                    for (int e = 0; e < 4; e++) {
                        int r = tm + wm * WM + m * 16 + kg * 4 + e;
                        int c = tn + wn * 64 + n * 16 + lr;
                        float t = acc[m][n][e] + bias0[bz * biasStride + c];
                        outB[(size_t)bz * outStride + (size_t)r * 2048 + c] = f2b(t);
                    }
        } else {
            // ---- V half: transpose via LDS, coalesced uint4 stores ----
            const int ccb = tn - 2048;             // multiple of 128
            const int bidx = tm >> 8;              // batch index (BM=128 | 256-row)
            const int hh = ccb >> 8;               // head
            u16* vls = smem;                       // [128 d][136 pad] u16 (34 KB)
#pragma unroll
            for (int m = 0; m < MF; m++)
#pragma unroll
                for (int n = 0; n < NF; n++)
#pragma unroll
                    for (int e = 0; e < 4; e++) {
                        int rl = wm * WM + m * 16 + kg * 4 + e;   // local tok
                        int cl = wn * 64 + n * 16 + lr;           // local d
                        float t = acc[m][n][e] + bias1[bz * biasStride + ccb + cl];
                        vls[cl * 136 + rl] = f2b(t);
                    }
            __syncthreads();
            const int dloc = tid >> 1;
            const int thalf = (tid & 1) * 64;
            const int dglob = (ccb & 255) + dloc;
            u16* dst = outV + (size_t)bz * outStride +
                       (size_t)(bidx * 8 + hh) * 65536 +
                       (size_t)dglob * 256 + (tm & 255) + thalf;
            const u16* srcl = vls + dloc * 136 + thalf;
#pragma unroll
            for (int k = 0; k < 8; k++)
                *(uint4*)(dst + k * 8) = *(const uint4*)(srcl + k * 8);
        }
        return;
    }

    // generic epilogue: D row=(lane>>4)*4+e, col=lane&15
#pragma unroll
    for (int m = 0; m < MF; m++) {
#pragma unroll
        for (int n = 0; n < NF; n++) {
#pragma unroll
            for (int e = 0; e < 4; e++) {
                int r = tm + wm * WM + m * 16 + (lane >> 4) * 4 + e;
                int c = tn + wn * 64 + n * 16 + (lane & 15);
                float v = acc[m][n][e];
                if constexpr (EPI == EPI_F32) {
                    outF[(size_t)r * ldc + c] = v + bias0[c];
                } else if constexpr (EPI == EPI_RESID_XB) {
                    float t = v + bias0[c] + Rsd[(size_t)r * ldc + c];
                    outF[(size_t)r * ldc + c] = t;
                    outB[(size_t)r * ldc + c] = f2b(t);
                } else if constexpr (EPI == EPI_GELU) {
                    float t = v + bias0[c];
                    t = 0.5f * t * (1.f + erff(t * 0.70710678118654752f));
                    outB[(size_t)r * ldc + c] = f2b(t);
                } else if constexpr (EPI == EPI_ATOMIC) {
                    float t = v;
                    if (bz == 0) t += bias0[c];
                    atomicAdd(&outF[(size_t)r * ldc + c], t);
                }
            }
        }
    }
}

// ---------------------------------------------------------------------------
// Fused attention with Q-projection (phases 0-4), XCD swizzle (same-bh
// blocks colocate), s_setprio around MFMA clusters.
// ---------------------------------------------------------------------------
template<bool MASKED>
__global__ __launch_bounds__(256, 2) void attn_kernel(
    const u16* __restrict__ Aq, const u16* __restrict__ WqT,
    const float* __restrict__ bq,
    const u16* __restrict__ K, const u16* __restrict__ Vt,
    const int* __restrict__ adj, u16* __restrict__ O)
{
    __shared__ __align__(16) u16 Ps[64 * 256];       // Q tile then P tile (32 KB)
    __shared__ __align__(16) u16 Ks[2 * 256 * 32];   // B double buffer (32 KB)
    __shared__ __align__(16) u16 Aql[2 * 64 * 32];   // phase-0 A dbuf (8 KB)
    __shared__ float red1[64 * 4];
    __shared__ float red2[64 * 4];

    const int tid = threadIdx.x;
    const int w = tid >> 6, lane = tid & 63;
    const int lr = lane & 15, kg = lane >> 4;

    // swizzle: linear y-major id remapped so 4 qt-blocks of a bh share an XCD
    const int nwg = gridDim.x * gridDim.y;
    const int bl = blockIdx.y * gridDim.x + blockIdx.x;
    const int wsw = (bl & 7) * (nwg >> 3) + (bl >> 3);
    const int qt = wsw % gridDim.x, bh = wsw / gridDim.x;

    const int b = bh >> 3, h = bh & 7;
    const size_t qkBase = (size_t)b * 256 * 2048 + h * 256;

    auto stageA0 = [&](int buf, int k0) {
        int u = tid;                       // 256 units exactly
        int row = u >> 2, g = u & 3;
        int gs = g ^ ((row >> 1) & 3);
        const u16* src = Aq + (size_t)(b * 256 + qt * 64 + row) * 512 + k0 + gs * 8;
        __builtin_amdgcn_global_load_lds(src, Aql + buf * 2048 + u * 8, 16, 0, 0);
    };
    auto stageB0 = [&](int buf, int k0) {
#pragma unroll
        for (int i = 0; i < 4; i++) {
            int u = tid + i * 256;
            int row = u >> 2, g = u & 3;
            int gs = g ^ ((row >> 1) & 3);
            const u16* src = WqT + (size_t)(h * 256 + row) * 512 + k0 + gs * 8;
            __builtin_amdgcn_global_load_lds(src, Ks + buf * 8192 + u * 8, 16, 0, 0);
        }
    };
    auto stageK = [&](int buf, int dk) {
#pragma unroll
        for (int i = 0; i < 4; i++) {
            int u = tid + i * 256;
            int row = u >> 2, g = u & 3;
            int gs = g ^ ((row >> 1) & 3);
            const u16* src = K + qkBase + (size_t)row * 2048 + dk * 32 + gs * 8;
            __builtin_amdgcn_global_load_lds(src, Ks + buf * 8192 + u * 8, 16, 0, 0);
        }
    };
    auto stageV = [&](int buf, int kt) {
#pragma unroll
        for (int i = 0; i < 4; i++) {
            int u = tid + i * 256;
            int row = u >> 2, g = u & 3;   // row = d
            int gs = g ^ ((row >> 1) & 3);
            const u16* src = Vt + (size_t)bh * 65536 + (size_t)row * 256 + kt * 32 + gs * 8;
            __builtin_amdgcn_global_load_lds(src, Ks + buf * 8192 + u * 8, 16, 0, 0);
        }
    };

    // ---- phase 0: Q = Aq @ WqT_head + bq  (K=512, 16 steps of 32) ----
    {
        f32x4 qacc[4][4];
#pragma unroll
        for (int m = 0; m < 4; m++)
#pragma unroll
            for (int n = 0; n < 4; n++) qacc[m][n] = (f32x4)(0.f);

        stageA0(0, 0);
        stageB0(0, 0);
        __syncthreads();
        for (int t = 0; t < 16; t++) {
            const int cur = t & 1;
            if (t < 15) { stageA0(cur ^ 1, (t + 1) * 32); stageB0(cur ^ 1, (t + 1) * 32); }
            short8 af[4], bfr[4];
#pragma unroll
            for (int m = 0; m < 4; m++) {
                int row = m * 16 + lr;
                af[m] = *(const short8*)&Aql[cur * 2048 + row * 32 + ((kg ^ ((row >> 1) & 3)) * 8)];
            }
#pragma unroll
            for (int n = 0; n < 4; n++) {
                int row = w * 64 + n * 16 + lr;
                bfr[n] = *(const short8*)&Ks[cur * 8192 + row * 32 + ((kg ^ ((row >> 1) & 3)) * 8)];
            }
            __builtin_amdgcn_s_setprio(1);
#pragma unroll
            for (int m = 0; m < 4; m++)
#pragma unroll
                for (int n = 0; n < 4; n++)
                    qacc[m][n] = __builtin_amdgcn_mfma_f32_16x16x32_bf16(
                        af[m], bfr[n], qacc[m][n], 0, 0, 0);
            __builtin_amdgcn_s_setprio(0);
            __syncthreads();
        }
        // write Q tile to Ps (bf16, swizzled for phase-1 A reads)
#pragma unroll
        for (int m = 0; m < 4; m++)
#pragma unroll
            for (int n = 0; n < 4; n++)
#pragma unroll
                for (int e = 0; e < 4; e++) {
                    int q = m * 16 + kg * 4 + e;
                    int d = w * 64 + n * 16 + lr;
                    float t = qacc[m][n][e] + bq[h * 256 + d];
                    Ps[q * 256 + (((d >> 3) ^ (q & 7)) * 8) + (d & 7)] = f2b(t);
                }
    }
    __syncthreads();

    f32x4 sacc[4][4];
#pragma unroll
    for (int m = 0; m < 4; m++)
#pragma unroll
        for (int n = 0; n < 4; n++) sacc[m][n] = (f32x4)(0.f);

    // ---- phase 1: S = Q K^T (contraction over d, 8 steps of 32) ----
    stageK(0, 0);
    __syncthreads();
    for (int dk = 0; dk < 8; dk++) {
        const int cur = dk & 1;
        if (dk < 7) stageK(cur ^ 1, dk + 1);
        short8 af[4], bfr[4];
#pragma unroll
        for (int m = 0; m < 4; m++) {
            int row = m * 16 + lr;
            af[m] = *(const short8*)&Ps[row * 256 + (((dk * 4 + kg) ^ (row & 7)) * 8)];
        }
#pragma unroll
        for (int n = 0; n < 4; n++) {
            int row = w * 64 + n * 16 + lr;
            bfr[n] = *(const short8*)&Ks[cur * 8192 + row * 32 + ((kg ^ ((row >> 1) & 3)) * 8)];
        }
        __builtin_amdgcn_s_setprio(1);
#pragma unroll
        for (int m = 0; m < 4; m++)
#pragma unroll
            for (int n = 0; n < 4; n++)
                sacc[m][n] = __builtin_amdgcn_mfma_f32_16x16x32_bf16(
                    af[m], bfr[n], sacc[m][n], 0, 0, 0);
        __builtin_amdgcn_s_setprio(0);
        __syncthreads();
    }

    // prefetch V tile 0 into Ks buf0 (overlaps softmax)
    stageV(0, 0);

    // ---- phase 2: scale + mask + softmax(+1 denom) ----
#pragma unroll
    for (int m = 0; m < 4; m++)
#pragma unroll
        for (int n = 0; n < 4; n++)
#pragma unroll
            for (int e = 0; e < 4; e++) {
                float t = sacc[m][n][e] * 0.0625f;
                if (MASKED) {
                    int q = qt * 64 + m * 16 + kg * 4 + e;
                    int k = w * 64 + n * 16 + lr;
                    int a_ = adj[((size_t)b * 256 + q) * 256 + k];
                    t += (1.f - (float)a_) * -1.0e6f;
                }
                sacc[m][n][e] = t;
            }

    float mx[4][4];
#pragma unroll
    for (int m = 0; m < 4; m++)
#pragma unroll
        for (int e = 0; e < 4; e++) {
            float v = sacc[m][0][e];
#pragma unroll
            for (int n = 1; n < 4; n++) v = fmaxf(v, sacc[m][n][e]);
#pragma unroll
            for (int off = 1; off < 16; off <<= 1) v = fmaxf(v, __shfl_xor(v, off));
            mx[m][e] = v;
        }
    if (lr == 0) {
#pragma unroll
        for (int m = 0; m < 4; m++)
#pragma unroll
            for (int e = 0; e < 4; e++)
                red1[(m * 16 + kg * 4 + e) * 4 + w] = mx[m][e];
    }
    __syncthreads();

    float inv[4][4];
    float sum[4][4];
#pragma unroll
    for (int m = 0; m < 4; m++)
#pragma unroll
        for (int e = 0; e < 4; e++) {
            int r = m * 16 + kg * 4 + e;
            float gm = fmaxf(fmaxf(red1[r * 4 + 0], red1[r * 4 + 1]),
                             fmaxf(red1[r * 4 + 2], red1[r * 4 + 3]));
            float s = 0.f;
#pragma unroll
            for (int n = 0; n < 4; n++) {
                float ev = __expf(sacc[m][n][e] - gm);
                sacc[m][n][e] = ev;
                s += ev;
            }
            sum[m][e] = s;
        }
#pragma unroll
    for (int m = 0; m < 4; m++)
#pragma unroll
        for (int e = 0; e < 4; e++) {
            float s = sum[m][e];
#pragma unroll
            for (int off = 1; off < 16; off <<= 1) s += __shfl_xor(s, off);
            sum[m][e] = s;
        }
    if (lr == 0) {
#pragma unroll
        for (int m = 0; m < 4; m++)
#pragma unroll
            for (int e = 0; e < 4; e++)
                red2[(m * 16 + kg * 4 + e) * 4 + w] = sum[m][e];
    }
    __syncthreads();
#pragma unroll
    for (int m = 0; m < 4; m++)
#pragma unroll
        for (int e = 0; e < 4; e++) {
            int r = m * 16 + kg * 4 + e;
            float gs = red2[r * 4 + 0] + red2[r * 4 + 1] +
                       red2[r * 4 + 2] + red2[r * 4 + 3];
            inv[m][e] = 1.f / (1.f + gs);
        }

    // ---- phase 3: P -> LDS (bf16, overwrites Q tile) ----
#pragma unroll
    for (int m = 0; m < 4; m++)
#pragma unroll
        for (int n = 0; n < 4; n++)
#pragma unroll
            for (int e = 0; e < 4; e++) {
                int q = m * 16 + kg * 4 + e;
                int k = w * 64 + n * 16 + lr;
                float pv = sacc[m][n][e] * inv[m][e];
                Ps[q * 256 + (((k >> 3) ^ (q & 7)) * 8) + (k & 7)] = f2b(pv);
            }
    __syncthreads();   // P visible; V tile 0 drained

    // ---- phase 4: O = P V (contraction over k, 8 steps of 32) ----
    f32x4 oacc[4][4];
#pragma unroll
    for (int m = 0; m < 4; m++)
#pragma unroll
        for (int n = 0; n < 4; n++) oacc[m][n] = (f32x4)(0.f);

    for (int kt = 0; kt < 8; kt++) {
        const int cur = kt & 1;
        if (kt < 7) stageV(cur ^ 1, kt + 1);
        short8 af[4], bfr[4];
#pragma unroll
        for (int m = 0; m < 4; m++) {
            int q = m * 16 + lr;
            af[m] = *(const short8*)&Ps[q * 256 + (((kt * 4 + kg) ^ (q & 7)) * 8)];
        }
#pragma unroll
        for (int n = 0; n < 4; n++) {
            int row = w * 64 + n * 16 + lr;
            bfr[n] = *(const short8*)&Ks[cur * 8192 + row * 32 + ((kg ^ ((row >> 1) & 3)) * 8)];
        }
        __builtin_amdgcn_s_setprio(1);
#pragma unroll
        for (int m = 0; m < 4; m++)
#pragma unroll
            for (int n = 0; n < 4; n++)
                oacc[m][n] = __builtin_amdgcn_mfma_f32_16x16x32_bf16(
                    af[m], bfr[n], oacc[m][n], 0, 0, 0);
        __builtin_amdgcn_s_setprio(0);
        __syncthreads();
    }

    // ---- epilogue: O[tok][h*256+d] ----
#pragma unroll
    for (int m = 0; m < 4; m++)
#pragma unroll
        for (int n = 0; n < 4; n++)
#pragma unroll
            for (int e = 0; e < 4; e++) {
                int q = qt * 64 + m * 16 + kg * 4 + e;
                int d = w * 64 + n * 16 + lr;
                O[(size_t)(b * 256 + q) * 2048 + h * 256 + d] = f2b(oacc[m][n][e]);
            }
}

// ---------------------------------------------------------------------------
// Transpose+convert: src f32 [R][C] -> dst bf16 [C][R].
// float4 global loads, [64][65] LDS (2-way = free), uint2 stores.
// ---------------------------------------------------------------------------
__global__ __launch_bounds__(256) void transpose_kernel(
    const float* p0, const float* p1, const float* p2,
    const float* p3, const float* p4, const float* p5,
    int nsrc, long srcLayerStride, int R, int C,
    u16* __restrict__ out, long dstMatStride, long dstLayerStride)
{
    const int mat = blockIdx.z % nsrc, layer = blockIdx.z / nsrc;
    const float* W;
    switch (mat) {
    default: W = p0; break;
    case 1: W = p1; break;
    case 2: W = p2; break;
    case 3: W = p3; break;
    case 4: W = p4; break;
    case 5: W = p5; break;
    }
    W += (size_t)layer * srcLayerStride;
    u16* o = out + (size_t)layer * dstLayerStride + (size_t)mat * dstMatStride;
    __shared__ float t[64][65];
    const int tid = threadIdx.x;
    const int rBase = blockIdx.y * 64, cBase = blockIdx.x * 64;
#pragma unroll
    for (int i = 0; i < 4; i++) {
        int idx = tid + i * 256;
        int rr = idx >> 4, cc4 = (idx & 15) * 4;
        if (rBase + rr < R) {
            float4 v = *(const float4*)&W[(size_t)(rBase + rr) * C + cBase + cc4];
            t[rr][cc4] = v.x; t[rr][cc4 + 1] = v.y;
            t[rr][cc4 + 2] = v.z; t[rr][cc4 + 3] = v.w;
        }
    }
    __syncthreads();
#pragma unroll
    for (int i = 0; i < 4; i++) {
        int idx = tid + i * 256;
        int cc = idx >> 4, rr4 = (idx & 15) * 4;
        if (rBase + rr4 < R) {
            uint2 pk;
            pk.x = (unsigned)f2b(t[rr4][cc]) | ((unsigned)f2b(t[rr4 + 1][cc]) << 16);
            pk.y = (unsigned)f2b(t[rr4 + 2][cc]) | ((unsigned)f2b(t[rr4 + 3][cc]) << 16);
            *(uint2*)&o[(size_t)(cBase + cc) * R + rBase + rr4] = pk;
        }
    }
}

// ---------------------------------------------------------------------------
// LayerNorm rows of 512, f32 in -> bf16 out. One wave per row.
// ---------------------------------------------------------------------------
__global__ __launch_bounds__(256) void ln_kernel(
    const float* __restrict__ X, const float* __restrict__ g,
    const float* __restrict__ b, u16* __restrict__ Y)
{
    const int wave = threadIdx.x >> 6, lane = threadIdx.x & 63;
    const size_t row = (size_t)blockIdx.x * 4 + wave;
    const float* xr = X + row * 512;
    float4 v0 = *reinterpret_cast<const float4*>(xr + lane * 8);
    float4 v1 = *reinterpret_cast<const float4*>(xr + lane * 8 + 4);
    float s = v0.x + v0.y + v0.z + v0.w + v1.x + v1.y + v1.z + v1.w;
    float ss = v0.x * v0.x + v0.y * v0.y + v0.z * v0.z + v0.w * v0.w +
               v1.x * v1.x + v1.y * v1.y + v1.z * v1.z + v1.w * v1.w;
#pragma unroll
    for (int off = 32; off; off >>= 1) {
        s += __shfl_xor(s, off);
        ss += __shfl_xor(ss, off);
    }
    float mu = s * (1.0f / 512.0f);
    float var = ss * (1.0f / 512.0f) - mu * mu;
    float rs = rsqrtf(var + 1e-5f);
    float4 g0 = *reinterpret_cast<const float4*>(g + lane * 8);
    float4 g1 = *reinterpret_cast<const float4*>(g + lane * 8 + 4);
    float4 b0 = *reinterpret_cast<const float4*>(b + lane * 8);
    float4 b1 = *reinterpret_cast<const float4*>(b + lane * 8 + 4);
    float o0 = (v0.x - mu) * rs * g0.x + b0.x;
    float o1 = (v0.y - mu) * rs * g0.y + b0.y;
    float o2 = (v0.z - mu) * rs * g0.z + b0.z;
    float o3 = (v0.w - mu) * rs * g0.w + b0.w;
    float o4 = (v1.x - mu) * rs * g1.x + b1.x;
    float o5 = (v1.y - mu) * rs * g1.y + b1.y;
    float o6 = (v1.z - mu) * rs * g1.z + b1.z;
    float o7 = (v1.w - mu) * rs * g1.w + b1.w;
    uint4 pk;
    pk.x = (unsigned)f2b(o0) | ((unsigned)f2b(o1) << 16);
    pk.y = (unsigned)f2b(o2) | ((unsigned)f2b(o3) << 16);
    pk.z = (unsigned)f2b(o4) | ((unsigned)f2b(o5) << 16);
    pk.w = (unsigned)f2b(o6) | ((unsigned)f2b(o7) << 16);
    *reinterpret_cast<uint4*>(Y + row * 512 + lane * 8) = pk;
}

// ---------------------------------------------------------------------------
// Embedding gather -> bf16 (2 elems/thread)
// ---------------------------------------------------------------------------
__global__ __launch_bounds__(256) void gather_kernel(
    const int* __restrict__ program, const float* __restrict__ embed,
    unsigned* __restrict__ Ag2, int total2)
{
    int idx = blockIdx.x * 256 + threadIdx.x;
    if (idx >= total2) return;
    int t = idx / 1200;
    int rem = idx - t * 1200;
    int j = rem / 150;
    int e2 = rem - j * 150;
    int tok = program[t * 8 + j];
    float2 v = *reinterpret_cast<const float2*>(&embed[(size_t)tok * 300 + e2 * 2]);
    Ag2[idx] = (unsigned)f2b(v.x) | ((unsigned)f2b(v.y) << 16);
}

// f32 -> bf16 convert, 4 elems/thread
__global__ __launch_bounds__(256) void cvt_kernel(
    const float* __restrict__ in, u16* __restrict__ out, int n4)
{
    int i = blockIdx.x * 256 + threadIdx.x;
    if (i >= n4) return;
    float4 v = reinterpret_cast<const float4*>(in)[i];
    uint2 pk;
    pk.x = (unsigned)f2b(v.x) | ((unsigned)f2b(v.y) << 16);
    pk.y = (unsigned)f2b(v.z) | ((unsigned)f2b(v.w) << 16);
    reinterpret_cast<uint2*>(out)[i] = pk;
}

// ---------------------------------------------------------------------------

extern "C" void kernel_launch(void* const* d_in, const int* in_sizes, int n_in,
                              void* d_out, int out_size, void* d_ws, size_t ws_size,
                              hipStream_t stream)
{
    const int*   program = (const int*)d_in[0];
    const int*   adj     = (const int*)d_in[1];
    const float* img     = (const float*)d_in[2];
    const float* embed   = (const float*)d_in[3];
    const float* W_in    = (const float*)d_in[4];
    const float* b_in    = (const float*)d_in[5];
    const float* ln1_g   = (const float*)d_in[6];
    const float* ln1_b   = (const float*)d_in[7];
    const float* ln2_g   = (const float*)d_in[8];
    const float* ln2_b   = (const float*)d_in[9];
    const float* Wq      = (const float*)d_in[10];
    const float* bq      = (const float*)d_in[11];
    const float* Wk      = (const float*)d_in[12];
    const float* bk      = (const float*)d_in[13];
    const float* Wv      = (const float*)d_in[14];
    const float* bv      = (const float*)d_in[15];
    const float* Wo      = (const float*)d_in[16];
    const float* bo      = (const float*)d_in[17];
    const float* fW1     = (const float*)d_in[18];
    const float* fb1     = (const float*)d_in[19];
    const float* fW2     = (const float*)d_in[20];
    const float* fb2     = (const float*)d_in[21];
    const float* cWq     = (const float*)d_in[22];
    const float* cbq     = (const float*)d_in[23];
    const float* cWk     = (const float*)d_in[24];
    const float* cbk     = (const float*)d_in[25];
    const float* cWv     = (const float*)d_in[26];
    const float* cbv     = (const float*)d_in[27];
    const float* cWo     = (const float*)d_in[28];
    const float* cbo     = (const float*)d_in[29];

    char* wsb = (char*)d_ws;
    const size_t MB = 1024 * 1024;
    const long Mi = 1048576;
    const long LSTR = 8 * Mi + Mi / 2;           // 8.5 Mi elements per layer

    float* x    = (float*)(wsb + 0);             // 4096x512 f32      (8 MB)
    u16*   h    = (u16*)(wsb + 8 * MB);          // 4096x512 bf16     (4 MB)
    u16*   xb   = (u16*)(wsb + 12 * MB);         // 4096x512 bf16     (4 MB)
    u16*   imgb = (u16*)(wsb + 16 * MB);         // 4096x512 bf16     (4 MB)
    u16*   WinT = (u16*)(wsb + 20 * MB);         // 512x2400 bf16     (2.4 MB)
    u16*   Kb   = (u16*)(wsb + 24 * MB);         // 4096x2048 bf16    (16 MB)
    u16*   Vt   = (u16*)(wsb + 40 * MB);         // [128][256][256]   (16 MB)
    u16*   O    = (u16*)(wsb + 56 * MB);         // 4096x2048 bf16    (16 MB)
    u16*   Wall = (u16*)(wsb + 72 * MB);         // transposed weights (102 MB)
    u16*   KcA  = (u16*)(wsb + 176 * MB);        // hoisted cross-K (96 MB)
    u16*   VcA  = (u16*)(wsb + 272 * MB);        // hoisted cross-V (96 MB)
    u16*   Ag   = Kb;  // gather buffer (dead before layer loop)
    u16*   g    = Kb;  // FFN mid aliases Kb (dead during FFN)

    const bool bigws = ws_size >= (size_t)175 * MB;
    const bool hoist = ws_size >= (size_t)369 * MB && bigws;

    // prologue
    gather_kernel<<<19200, 256, 0, stream>>>(program, embed, (unsigned*)Ag, 4915200);
    transpose_kernel<<<dim3(8, 38, 1), 256, 0, stream>>>(
        W_in, nullptr, nullptr, nullptr, nullptr, nullptr,
        1, 0, 2400, 512, WinT, 0, 0);
    cvt_kernel<<<2048, 256, 0, stream>>>(img, imgb, 524288);
    if (bigws) {
        transpose_kernel<<<dim3(32, 8, 36), 256, 0, stream>>>(
            Wq, Wk, Wv, cWq, cWk, cWv, 6, Mi, 512, 2048, Wall, Mi, LSTR);
        transpose_kernel<<<dim3(8, 32, 12), 256, 0, stream>>>(
            Wo, cWo, nullptr, nullptr, nullptr, nullptr,
            2, Mi, 2048, 512, Wall + 6 * Mi, Mi, LSTR);
        transpose_kernel<<<dim3(8, 8, 12), 256, 0, stream>>>(
            fW1, fW2, nullptr, nullptr, nullptr, nullptr,
            2, 262144, 512, 512, Wall + 8 * Mi, 262144, LSTR);
    }
    gemm_bf16<64, 64, 32, EPI_F32><<<dim3(8, 64, 1), 256, 0, stream>>>(
        Ag, 0, 2400, WinT, 0, 2400, 4096, 512, 2400,
        b_in, nullptr, 0, nullptr,
        x, nullptr, nullptr, 0, 512);
    if (hoist) {
        // all 6 layers' cross-KV in one batched dispatch (imgb is static)
        gemm_bf16<128, 128, 64, EPI_KV><<<dim3(32, 32, 6), 256, 0, stream>>>(
            imgb, 0, 512, Wall + 4 * Mi, LSTR, 512, 4096, 4096, 512,
            cbk, cbv, 2048, nullptr,
            nullptr, KcA, VcA, 8 * Mi, 2048);
    }

    for (int l = 0; l < 6; l++) {
        u16* Wl = Wall + (bigws ? (size_t)l * LSTR : 0);
        if (!bigws) {
            transpose_kernel<<<dim3(32, 8, 6), 256, 0, stream>>>(
                Wq + (size_t)l * Mi, Wk + (size_t)l * Mi, Wv + (size_t)l * Mi,
                cWq + (size_t)l * Mi, cWk + (size_t)l * Mi, cWv + (size_t)l * Mi,
                6, 0, 512, 2048, Wl, Mi, 0);
            transpose_kernel<<<dim3(8, 32, 2), 256, 0, stream>>>(
                Wo + (size_t)l * Mi, cWo + (size_t)l * Mi,
                nullptr, nullptr, nullptr, nullptr,
                2, 0, 2048, 512, Wl + 6 * Mi, Mi, 0);
            transpose_kernel<<<dim3(8, 8, 2), 256, 0, stream>>>(
                fW1 + (size_t)l * 262144, fW2 + (size_t)l * 262144,
                nullptr, nullptr, nullptr, nullptr,
                2, 0, 512, 512, Wl + 8 * Mi, 262144, 0);
        }

        // --- self-attention (Q fused into attn; KV-only GEMM) ---
        ln_kernel<<<1024, 256, 0, stream>>>(x, ln1_g + l * 512, ln1_b + l * 512, h);
        gemm_bf16<128, 128, 64, EPI_KV><<<dim3(32, 32, 1), 256, 0, stream>>>(
            h, 0, 512, Wl + 1 * Mi, 0, 512, 4096, 4096, 512,
            bk + l * 2048, bv + l * 2048, 0, nullptr,
            nullptr, Kb, Vt, 0, 2048);
        attn_kernel<true><<<dim3(4, 128), 256, 0, stream>>>(
            h, Wl, bq + l * 2048, Kb, Vt, adj, O);
        gemm_bf16<64, 64, 64, EPI_ATOMIC><<<dim3(8, 64, 2), 256, 0, stream>>>(
            O, 1024, 2048, Wl + 6 * Mi, 1024, 2048, 4096, 512, 1024,
            bo + l * 512, nullptr, 0, nullptr,
            x, nullptr, nullptr, 0, 512);

        // --- FFN ---
        ln_kernel<<<1024, 256, 0, stream>>>(x, ln2_g + l * 512, ln2_b + l * 512, h);
        gemm_bf16<64, 64, 64, EPI_GELU><<<dim3(8, 64, 1), 256, 0, stream>>>(
            h, 0, 512, Wl + 8 * Mi, 0, 512, 4096, 512, 512,
            fb1 + l * 512, nullptr, 0, nullptr,
            nullptr, g, nullptr, 0, 512);
        gemm_bf16<64, 64, 64, EPI_RESID_XB><<<dim3(8, 64, 1), 256, 0, stream>>>(
            g, 0, 512, Wl + 8 * Mi + 262144, 0, 512, 4096, 512, 512,
            fb2 + l * 512, nullptr, 0, x,
            x, xb, nullptr, 0, 512);

        // --- cross-attention (Q fused; query source = xb, no mask) ---
        u16* Kc = hoist ? (KcA + (size_t)l * 8 * Mi) : Kb;
        u16* Vc = hoist ? (VcA + (size_t)l * 8 * Mi) : Vt;
        if (!hoist) {
            gemm_bf16<128, 128, 64, EPI_KV><<<dim3(32, 32, 1), 256, 0, stream>>>(
                imgb, 0, 512, Wl + 4 * Mi, 0, 512, 4096, 4096, 512,
                cbk + l * 2048, cbv + l * 2048, 0, nullptr,
                nullptr, Kb, Vt, 0, 2048);
        }
        attn_kernel<false><<<dim3(4, 128), 256, 0, stream>>>(
            xb, Wl + 3 * Mi, cbq + l * 2048, Kc, Vc, nullptr, O);
        gemm_bf16<64, 64, 64, EPI_ATOMIC><<<dim3(8, 64, 2), 256, 0, stream>>>(
            O, 1024, 2048, Wl + 7 * Mi, 1024, 2048, 4096, 512, 1024,
            cbo + l * 512, nullptr, 0, nullptr,
            x, nullptr, nullptr, 0, 512);
    }

    hipMemcpyAsync(d_out, x, (size_t)2097152 * sizeof(float),
                   hipMemcpyDeviceToDevice, stream);
}